// Round 1
// baseline (5684.642 us; speedup 1.0000x reference)
//
#include <hip/hip_runtime.h>
#include <math.h>

#define SEQL 512
#define DMOD 512
#define NHEAD 8
#define DHEAD 64
#define DFFN 2048
#define NBATCH 4
#define NVARS 7
#define NBV 28          // NBATCH*NVARS
#define NBH 224         // NBV*NHEAD
#define NROWS 14336     // NBV*SEQL
#define NSAMP 35        // U_part = u = 35
#define NPRED 96
#define SBIG 7340032    // NBV*SEQL*DMOD floats

// ---------------- threefry2x32 (matches jax._src.prng) ----------------
__device__ inline void threefry2x32(unsigned k0, unsigned k1,
                                    unsigned x0, unsigned x1,
                                    unsigned &o0, unsigned &o1) {
  unsigned ks2 = k0 ^ k1 ^ 0x1BD11BDAu;
  unsigned ks[3] = {k0, k1, ks2};
  x0 += k0; x1 += k1;
  const unsigned rot[2][4] = {{13u,15u,26u,6u},{17u,29u,16u,24u}};
  #pragma unroll
  for (int i = 0; i < 5; ++i) {
    #pragma unroll
    for (int j = 0; j < 4; ++j) {
      unsigned r = rot[i & 1][j];
      x0 += x1;
      x1 = (x1 << r) | (x1 >> (32u - r));
      x1 ^= x0;
    }
    x0 += ks[(i + 1) % 3];
    x1 += ks[(i + 2) % 3] + (unsigned)(i + 1);
  }
  o0 = x0; o1 = x1;
}

// idx[q][u] = (second-half threefry output) % 512 ; pair i: (x0=i, x1=17920+i)
__global__ void make_idx_kernel(int layer, int* idx) {
  int i = blockIdx.x * 256 + threadIdx.x;
  if (i >= SEQL * NSAMP) return;
  unsigned kl0, kl1, o0, o1;
  threefry2x32(0u, 42u, 0u, (unsigned)layer, kl0, kl1);   // fold_in(key(42), l)
  threefry2x32(kl0, kl1, (unsigned)i, (unsigned)(SEQL * NSAMP + i), o0, o1);
  idx[i] = (int)(o1 & 511u);
}

// ---------------- embedding ----------------
__global__ void embed_kernel(const float* __restrict__ x_enc,
                             const float* __restrict__ w_emb,
                             const float* __restrict__ b_emb,
                             const float* __restrict__ w_pos,
                             float* __restrict__ h) {
  size_t i = (size_t)blockIdx.x * 256 + threadIdx.x;
  if (i >= (size_t)SBIG) return;
  int dm = (int)(i & 511);
  int l  = (int)((i >> 9) & 511);
  int bv = (int)(i >> 18);
  int b = bv / NVARS, v = bv % NVARS;
  h[i] = x_enc[((size_t)b * SEQL + l) * NVARS + v] * w_emb[dm] + b_emb[dm]
         + w_pos[(size_t)l * DMOD + dm];
}

// ---------------- fp32 GEMM: C[M,N] = A[M,K] @ W[N,K]^T + bias, opt gelu ----------------
__global__ __launch_bounds__(256) void gemm_bt(const float* __restrict__ A,
                                               const float* __restrict__ W,
                                               const float* __restrict__ bias,
                                               float* __restrict__ C,
                                               int M, int N, int K, int act) {
  __shared__ float As[16][65];
  __shared__ float Ws[16][65];
  int bm = blockIdx.y * 64, bn = blockIdx.x * 64;
  int tid = threadIdx.x;
  int tx = tid & 15, ty = tid >> 4;
  float acc[4][4] = {};
  for (int k0 = 0; k0 < K; k0 += 16) {
    #pragma unroll
    for (int i = 0; i < 4; ++i) {
      int e = tid + i * 256;
      int r = e >> 4, c = e & 15;
      As[c][r] = A[(size_t)(bm + r) * K + k0 + c];
      Ws[c][r] = W[(size_t)(bn + r) * K + k0 + c];
    }
    __syncthreads();
    #pragma unroll
    for (int kk = 0; kk < 16; ++kk) {
      float a[4], w[4];
      #pragma unroll
      for (int i = 0; i < 4; ++i) a[i] = As[kk][ty * 4 + i];
      #pragma unroll
      for (int j = 0; j < 4; ++j) w[j] = Ws[kk][tx * 4 + j];
      #pragma unroll
      for (int i = 0; i < 4; ++i)
        #pragma unroll
        for (int j = 0; j < 4; ++j) acc[i][j] += a[i] * w[j];
    }
    __syncthreads();
  }
  #pragma unroll
  for (int i = 0; i < 4; ++i) {
    int m = bm + ty * 4 + i;
    #pragma unroll
    for (int j = 0; j < 4; ++j) {
      int n = bn + tx * 4 + j;
      float v = acc[i][j] + bias[n];
      if (act == 1) {
        float x = v;
        float t = tanhf(0.7978845608028654f * (x + 0.044715f * x * x * x));
        v = 0.5f * x * (1.0f + t);
      }
      C[(size_t)m * N + n] = v;
    }
  }
}

// ---------------- M measure: one wave per (bh, q) ----------------
__global__ __launch_bounds__(64) void m_kernel(const float* __restrict__ Q,
                                               const float* __restrict__ K,
                                               const int* __restrict__ idx,
                                               float* __restrict__ Mout) {
  int qrow = blockIdx.x;          // 0..511
  int bh = blockIdx.y;            // 0..223
  int bv = bh >> 3, head = bh & 7;
  int lane = threadIdx.x;         // 0..63
  const float* qv = Q + (size_t)bv * (SEQL * DMOD) + (size_t)qrow * DMOD + head * DHEAD;
  const float* kb = K + (size_t)bv * (SEQL * DMOD) + head * DHEAD;
  float qreg = qv[lane];
  const int* ip = idx + qrow * NSAMP;
  float mx = -INFINITY, sm = 0.f;
  for (int u = 0; u < NSAMP; ++u) {
    int kidx = ip[u];
    float p = qreg * kb[(size_t)kidx * DMOD + lane];
    #pragma unroll
    for (int off = 32; off > 0; off >>= 1) p += __shfl_xor(p, off);
    mx = fmaxf(mx, p);
    sm += p;
  }
  if (lane == 0) Mout[(size_t)bh * SEQL + qrow] = mx - sm * (1.0f / 512.0f);
}

// ---------------- top-k (k=35) per (bh), tie -> smaller index ----------------
__global__ __launch_bounds__(256) void topk_kernel(const float* __restrict__ Mv,
                                                   int* __restrict__ top) {
  int bh = blockIdx.x;
  int tid = threadIdx.x;
  __shared__ float vals[512];
  __shared__ float rv[256];
  __shared__ int ri[256];
  vals[tid]       = Mv[(size_t)bh * SEQL + tid];
  vals[tid + 256] = Mv[(size_t)bh * SEQL + tid + 256];
  __syncthreads();
  for (int t = 0; t < NSAMP; ++t) {
    float v0 = vals[tid], v1 = vals[tid + 256];
    float bvv; int bii;
    if (v0 >= v1) { bvv = v0; bii = tid; } else { bvv = v1; bii = tid + 256; }
    rv[tid] = bvv; ri[tid] = bii;
    __syncthreads();
    for (int s = 128; s > 0; s >>= 1) {
      if (tid < s) {
        float ov = rv[tid + s]; int oi = ri[tid + s];
        if (ov > rv[tid] || (ov == rv[tid] && oi < ri[tid])) { rv[tid] = ov; ri[tid] = oi; }
      }
      __syncthreads();
    }
    if (tid == 0) { top[bh * NSAMP + t] = ri[0]; vals[ri[0]] = -INFINITY; }
    __syncthreads();
  }
}

// ---------------- mean of V over keys, per (bh, d) ----------------
__global__ __launch_bounds__(64) void vmean_kernel(const float* __restrict__ V,
                                                   float* __restrict__ vmean) {
  int bh = blockIdx.x;
  int bv = bh >> 3, head = bh & 7;
  int d = threadIdx.x;
  const float* vb = V + (size_t)bv * (SEQL * DMOD) + head * DHEAD + d;
  float s = 0.f;
  for (int l = 0; l < SEQL; ++l) s += vb[(size_t)l * DMOD];
  vmean[bh * DHEAD + d] = s * (1.0f / 512.0f);
}

// ---------------- ctx = broadcast vmean ----------------
__global__ void ctx_fill_kernel(const float* __restrict__ vmean,
                                float* __restrict__ ctx) {
  size_t i = (size_t)blockIdx.x * 256 + threadIdx.x;
  if (i >= (size_t)SBIG) return;
  int dm = (int)(i & 511);
  int bv = (int)(i >> 18);
  ctx[i] = vmean[bv * DMOD + dm];   // vmean flat layout: [bv*8+h][64] == [bv*512+dm]
}

// ---------------- full attention for selected queries ----------------
__global__ __launch_bounds__(256) void attn_upd_kernel(const float* __restrict__ Q,
                                                       const float* __restrict__ K,
                                                       const float* __restrict__ V,
                                                       const int* __restrict__ top,
                                                       float* __restrict__ ctx) {
  int t = blockIdx.x;    // 0..34
  int bh = blockIdx.y;   // 0..223
  int bv = bh >> 3, head = bh & 7;
  int tid = threadIdx.x;
  int qi = top[bh * NSAMP + t];
  __shared__ float sc[512];
  __shared__ float red[256];
  const float* qv = Q + (size_t)bv * (SEQL * DMOD) + (size_t)qi * DMOD + head * DHEAD;
  const float* kb = K + (size_t)bv * (SEQL * DMOD) + head * DHEAD;
  const float* vb = V + (size_t)bv * (SEQL * DMOD) + head * DHEAD;
  for (int l = tid; l < SEQL; l += 256) {
    const float* kv = kb + (size_t)l * DMOD;
    float s = 0.f;
    #pragma unroll
    for (int d = 0; d < DHEAD; ++d) s += qv[d] * kv[d];
    sc[l] = s * 0.125f;
  }
  __syncthreads();
  red[tid] = fmaxf(sc[tid], sc[tid + 256]);
  __syncthreads();
  for (int s = 128; s > 0; s >>= 1) {
    if (tid < s) red[tid] = fmaxf(red[tid], red[tid + s]);
    __syncthreads();
  }
  float mx = red[0];
  __syncthreads();
  float e0 = expf(sc[tid] - mx), e1 = expf(sc[tid + 256] - mx);
  sc[tid] = e0; sc[tid + 256] = e1;
  red[tid] = e0 + e1;
  __syncthreads();
  for (int s = 128; s > 0; s >>= 1) {
    if (tid < s) red[tid] += red[tid + s];
    __syncthreads();
  }
  float denom = red[0];
  __syncthreads();
  int d = tid & 63, part = tid >> 6;
  float acc = 0.f;
  for (int l = part * 128; l < part * 128 + 128; ++l)
    acc += sc[l] * vb[(size_t)l * DMOD + d];
  red[tid] = acc;
  __syncthreads();
  if (tid < 64) {
    float r = red[tid] + red[tid + 64] + red[tid + 128] + red[tid + 192];
    ctx[(size_t)bv * (SEQL * DMOD) + (size_t)qi * DMOD + head * DHEAD + tid] = r / denom;
  }
}

// ---------------- residual add + layernorm (b may be null) ----------------
__global__ __launch_bounds__(256) void add_ln_kernel(const float* __restrict__ a,
                                                     const float* __restrict__ b,
                                                     const float* __restrict__ g,
                                                     const float* __restrict__ be,
                                                     float* __restrict__ out) {
  int r = blockIdx.x;
  int tid = threadIdx.x;
  __shared__ float red[256];
  size_t base = (size_t)r * DMOD;
  float x0 = a[base + tid];
  float x1 = a[base + tid + 256];
  if (b) { x0 += b[base + tid]; x1 += b[base + tid + 256]; }
  red[tid] = x0 + x1;
  __syncthreads();
  for (int s = 128; s > 0; s >>= 1) {
    if (tid < s) red[tid] += red[tid + s];
    __syncthreads();
  }
  float mu = red[0] * (1.0f / 512.0f);
  __syncthreads();
  float d0 = x0 - mu, d1 = x1 - mu;
  red[tid] = d0 * d0 + d1 * d1;
  __syncthreads();
  for (int s = 128; s > 0; s >>= 1) {
    if (tid < s) red[tid] += red[tid + s];
    __syncthreads();
  }
  float rstd = rsqrtf(red[0] * (1.0f / 512.0f) + 1e-5f);
  out[base + tid]       = d0 * rstd * g[tid] + be[tid];
  out[base + tid + 256] = d1 * rstd * g[tid + 256] + be[tid + 256];
}

// ---------------- head: out[b,p,v] = dot(h[bv], Wh[p]) + bh[p] ----------------
__global__ __launch_bounds__(256) void head_kernel(const float* __restrict__ h,
                                                   const float* __restrict__ Wh,
                                                   const float* __restrict__ bh_,
                                                   float* __restrict__ out) {
  int bv = blockIdx.x;   // 0..27
  int p  = blockIdx.y;   // 0..95
  int tid = threadIdx.x;
  const float* hr = h + (size_t)bv * (SEQL * DMOD);
  const float* wr = Wh + (size_t)p * (SEQL * DMOD);
  float s = 0.f;
  for (int i = tid; i < SEQL * DMOD; i += 256) s += hr[i] * wr[i];
  __shared__ float red[256];
  red[tid] = s;
  __syncthreads();
  for (int st = 128; st > 0; st >>= 1) {
    if (tid < st) red[tid] += red[tid + st];
    __syncthreads();
  }
  if (tid == 0) {
    int b = bv / NVARS, v = bv % NVARS;
    out[(size_t)b * (NPRED * NVARS) + (size_t)p * NVARS + v] = red[0] + bh_[p];
  }
}

extern "C" void kernel_launch(void* const* d_in, const int* in_sizes, int n_in,
                              void* d_out, int out_size, void* d_ws, size_t ws_size,
                              hipStream_t stream) {
  const float* x_enc = (const float*)d_in[0];
  const float* w_emb = (const float*)d_in[1];
  const float* b_emb = (const float*)d_in[2];
  const float* w_pos = (const float*)d_in[3];
  const float* Wq = (const float*)d_in[4];
  const float* bq = (const float*)d_in[5];
  const float* Wk = (const float*)d_in[6];
  const float* bk = (const float*)d_in[7];
  const float* Wv = (const float*)d_in[8];
  const float* bv_ = (const float*)d_in[9];
  const float* Wo = (const float*)d_in[10];
  const float* bo = (const float*)d_in[11];
  const float* W1 = (const float*)d_in[12];
  const float* b1 = (const float*)d_in[13];
  const float* W2 = (const float*)d_in[14];
  const float* b2 = (const float*)d_in[15];
  const float* g1 = (const float*)d_in[16];
  const float* be1 = (const float*)d_in[17];
  const float* g2 = (const float*)d_in[18];
  const float* be2 = (const float*)d_in[19];
  const float* gF = (const float*)d_in[20];
  const float* bF = (const float*)d_in[21];
  const float* Wh = (const float*)d_in[22];
  const float* bh_ = (const float*)d_in[23];
  float* out = (float*)d_out;

  const size_t S = (size_t)SBIG;          // floats in a (28,512,512) buffer
  const size_t SB = S * 4;                // bytes
  char* ws = (char*)d_ws;
  float* h   = (float*)(ws);              // SB
  float* R   = (float*)(ws + SB);         // 4*SB region: Q,K,V,CTX or FFN
  float* Qb  = R;
  float* Kb  = R + S;
  float* Vb  = R + 2 * S;
  float* CTX = R + 3 * S;
  float* FFN = R;                         // 28*512*2048 floats == 4*S
  float* Ob  = (float*)(ws + 5 * SB);     // SB
  int*   idx = (int*)(ws + 6 * SB);                   // 17920 ints
  float* Mv  = (float*)(ws + 6 * SB + 0x20000);       // 114688 floats (448KB)
  int*   top = (int*)(ws + 6 * SB + 0x20000 + 0x80000); // 7840 ints
  float* vmean = (float*)(ws + 6 * SB + 0x20000 + 0x80000 + 0x10000); // 14336 f
  if (ws_size < 6 * SB + 0x20000 + 0x80000 + 0x10000 + 0x10000) return;

  dim3 b256(256);
  int gBig = (int)((S + 255) / 256);

  embed_kernel<<<gBig, b256, 0, stream>>>(x_enc, w_emb, b_emb, w_pos, h);

  for (int l = 0; l < 2; ++l) {
    const float* Wql = Wq + (size_t)l * DMOD * DMOD;
    const float* Wkl = Wk + (size_t)l * DMOD * DMOD;
    const float* Wvl = Wv + (size_t)l * DMOD * DMOD;
    const float* Wol = Wo + (size_t)l * DMOD * DMOD;
    const float* W1l = W1 + (size_t)l * DFFN * DMOD;
    const float* W2l = W2 + (size_t)l * DMOD * DFFN;

    dim3 gq(DMOD / 64, NROWS / 64);
    gemm_bt<<<gq, b256, 0, stream>>>(h, Wql, bq + l * DMOD, Qb, NROWS, DMOD, DMOD, 0);
    gemm_bt<<<gq, b256, 0, stream>>>(h, Wkl, bk + l * DMOD, Kb, NROWS, DMOD, DMOD, 0);
    gemm_bt<<<gq, b256, 0, stream>>>(h, Wvl, bv_ + l * DMOD, Vb, NROWS, DMOD, DMOD, 0);

    make_idx_kernel<<<(SEQL * NSAMP + 255) / 256, b256, 0, stream>>>(l, idx);
    m_kernel<<<dim3(SEQL, NBH), dim3(64), 0, stream>>>(Qb, Kb, idx, Mv);
    topk_kernel<<<NBH, b256, 0, stream>>>(Mv, top);
    vmean_kernel<<<NBH, dim3(64), 0, stream>>>(Vb, vmean);
    ctx_fill_kernel<<<gBig, b256, 0, stream>>>(vmean, CTX);
    attn_upd_kernel<<<dim3(NSAMP, NBH), b256, 0, stream>>>(Qb, Kb, Vb, top, CTX);

    gemm_bt<<<gq, b256, 0, stream>>>(CTX, Wol, bo + l * DMOD, Ob, NROWS, DMOD, DMOD, 0);
    add_ln_kernel<<<NROWS, b256, 0, stream>>>(h, Ob, g1 + l * DMOD, be1 + l * DMOD, h);

    dim3 g1f(DFFN / 64, NROWS / 64);
    gemm_bt<<<g1f, b256, 0, stream>>>(h, W1l, b1 + l * DFFN, FFN, NROWS, DFFN, DMOD, 1);
    dim3 g2f(DMOD / 64, NROWS / 64);
    gemm_bt<<<g2f, b256, 0, stream>>>(FFN, W2l, b2 + l * DMOD, Ob, NROWS, DMOD, DFFN, 0);
    add_ln_kernel<<<NROWS, b256, 0, stream>>>(h, Ob, g2 + l * DMOD, be2 + l * DMOD, h);
  }

  add_ln_kernel<<<NROWS, b256, 0, stream>>>(h, nullptr, gF, bF, h);
  head_kernel<<<dim3(NBV, NPRED), b256, 0, stream>>>(h, Wh, bh_, out);
}

// Round 2
// 2591.480 us; speedup vs baseline: 2.1936x; 2.1936x over previous
//
#include <hip/hip_runtime.h>
#include <math.h>

#define SEQL 512
#define DMOD 512
#define NHEAD 8
#define DHEAD 64
#define DFFN 2048
#define NBATCH 4
#define NVARS 7
#define NBV 28          // NBATCH*NVARS
#define NBH 224         // NBV*NHEAD
#define NROWS 14336     // NBV*SEQL
#define NSAMP 35        // U_part = u = 35
#define NPRED 96
#define SBIG 7340032    // NBV*SEQL*DMOD floats

typedef short bf16x8 __attribute__((ext_vector_type(8)));
typedef float f32x4 __attribute__((ext_vector_type(4)));

__device__ inline unsigned short f2b(float f) {
  unsigned u = __builtin_bit_cast(unsigned, f);
  unsigned r = (u + 0x7FFFu + ((u >> 16) & 1u)) >> 16;
  return (unsigned short)r;
}

// ---------------- threefry2x32 (matches jax._src.prng) ----------------
__device__ inline void threefry2x32(unsigned k0, unsigned k1,
                                    unsigned x0, unsigned x1,
                                    unsigned &o0, unsigned &o1) {
  unsigned ks2 = k0 ^ k1 ^ 0x1BD11BDAu;
  unsigned ks[3] = {k0, k1, ks2};
  x0 += k0; x1 += k1;
  const unsigned rot[2][4] = {{13u,15u,26u,6u},{17u,29u,16u,24u}};
  #pragma unroll
  for (int i = 0; i < 5; ++i) {
    #pragma unroll
    for (int j = 0; j < 4; ++j) {
      unsigned r = rot[i & 1][j];
      x0 += x1;
      x1 = (x1 << r) | (x1 >> (32u - r));
      x1 ^= x0;
    }
    x0 += ks[(i + 1) % 3];
    x1 += ks[(i + 2) % 3] + (unsigned)(i + 1);
  }
  o0 = x0; o1 = x1;
}

__global__ void make_idx_kernel(int layer, int* idx) {
  int i = blockIdx.x * 256 + threadIdx.x;
  if (i >= SEQL * NSAMP) return;
  unsigned kl0, kl1, o0, o1;
  threefry2x32(0u, 42u, 0u, (unsigned)layer, kl0, kl1);
  threefry2x32(kl0, kl1, (unsigned)i, (unsigned)(SEQL * NSAMP + i), o0, o1);
  idx[i] = (int)(o1 & 511u);
}

// ---------------- embedding ----------------
__global__ void embed_kernel(const float* __restrict__ x_enc,
                             const float* __restrict__ w_emb,
                             const float* __restrict__ b_emb,
                             const float* __restrict__ w_pos,
                             float* __restrict__ h) {
  size_t i = (size_t)blockIdx.x * 256 + threadIdx.x;
  if (i >= (size_t)SBIG) return;
  int dm = (int)(i & 511);
  int l  = (int)((i >> 9) & 511);
  int bv = (int)(i >> 18);
  int b = bv / NVARS, v = bv % NVARS;
  h[i] = x_enc[((size_t)b * SEQL + l) * NVARS + v] * w_emb[dm] + b_emb[dm]
         + w_pos[(size_t)l * DMOD + dm];
}

// ---------------- fp32 GEMM (QKV only): C = A @ W^T + bias ----------------
__global__ __launch_bounds__(256) void gemm_bt(const float* __restrict__ A,
                                               const float* __restrict__ W,
                                               const float* __restrict__ bias,
                                               float* __restrict__ C,
                                               int M, int N, int K) {
  __shared__ float As[16][65];
  __shared__ float Ws[16][65];
  int bm = blockIdx.y * 64, bn = blockIdx.x * 64;
  int tid = threadIdx.x;
  int tx = tid & 15, ty = tid >> 4;
  float acc[4][4] = {};
  for (int k0 = 0; k0 < K; k0 += 16) {
    #pragma unroll
    for (int i = 0; i < 4; ++i) {
      int e = tid + i * 256;
      int r = e >> 4, c = e & 15;
      As[c][r] = A[(size_t)(bm + r) * K + k0 + c];
      Ws[c][r] = W[(size_t)(bn + r) * K + k0 + c];
    }
    __syncthreads();
    #pragma unroll
    for (int kk = 0; kk < 16; ++kk) {
      float a[4], w[4];
      #pragma unroll
      for (int i = 0; i < 4; ++i) a[i] = As[kk][ty * 4 + i];
      #pragma unroll
      for (int j = 0; j < 4; ++j) w[j] = Ws[kk][tx * 4 + j];
      #pragma unroll
      for (int i = 0; i < 4; ++i)
        #pragma unroll
        for (int j = 0; j < 4; ++j) acc[i][j] += a[i] * w[j];
    }
    __syncthreads();
  }
  #pragma unroll
  for (int i = 0; i < 4; ++i) {
    int m = bm + ty * 4 + i;
    #pragma unroll
    for (int j = 0; j < 4; ++j) {
      int n = bn + tx * 4 + j;
      C[(size_t)m * N + n] = acc[i][j] + bias[n];
    }
  }
}

// ---------------- bf16 MFMA GEMM: C[M,N] = A[M,K]@W[N,K]^T + bias ----------------
// 128x128 tile, BK=64, 4 waves (2x2), 16x16x32 MFMA, XOR-swizzled LDS.
template<int ACT, int OUTBF>
__global__ __launch_bounds__(256) void gemm_mfma(const unsigned short* __restrict__ A,
                                                 const unsigned short* __restrict__ W,
                                                 const float* __restrict__ bias,
                                                 float* __restrict__ Cf,
                                                 unsigned short* __restrict__ Cb,
                                                 int M, int N, int K) {
  __shared__ __align__(16) unsigned short As[128 * 64];
  __shared__ __align__(16) unsigned short Bs[128 * 64];
  int bm = blockIdx.y * 128, bn = blockIdx.x * 128;
  int tid = threadIdx.x;
  int wave = tid >> 6, lane = tid & 63;
  int wr = wave >> 1, wc = wave & 1;
  int r16 = lane & 15, kq = lane >> 4;

  f32x4 acc[4][4];
  #pragma unroll
  for (int i = 0; i < 4; ++i)
    #pragma unroll
    for (int j = 0; j < 4; ++j) acc[i][j] = (f32x4){0.f, 0.f, 0.f, 0.f};

  for (int kt = 0; kt < K; kt += 64) {
    __syncthreads();
    #pragma unroll
    for (int i = 0; i < 4; ++i) {
      int c = i * 256 + tid;
      int row = c >> 3, kb = c & 7;
      uint4 va = *(const uint4*)(A + (size_t)(bm + row) * K + kt + kb * 8);
      uint4 vb = *(const uint4*)(W + (size_t)(bn + row) * K + kt + kb * 8);
      int sw = ((row << 7) | (kb << 4)) ^ ((row & 7) << 4);
      *(uint4*)((char*)As + sw) = va;
      *(uint4*)((char*)Bs + sw) = vb;
    }
    __syncthreads();
    #pragma unroll
    for (int ks = 0; ks < 2; ++ks) {
      bf16x8 afr[4], bfr[4];
      #pragma unroll
      for (int mi = 0; mi < 4; ++mi) {
        int row = wr * 64 + mi * 16 + r16;
        int addr = ((row << 7) | (ks << 6) | (kq << 4)) ^ ((row & 7) << 4);
        afr[mi] = *(const bf16x8*)((const char*)As + addr);
      }
      #pragma unroll
      for (int ni = 0; ni < 4; ++ni) {
        int row = wc * 64 + ni * 16 + r16;
        int addr = ((row << 7) | (ks << 6) | (kq << 4)) ^ ((row & 7) << 4);
        bfr[ni] = *(const bf16x8*)((const char*)Bs + addr);
      }
      #pragma unroll
      for (int mi = 0; mi < 4; ++mi)
        #pragma unroll
        for (int ni = 0; ni < 4; ++ni)
          acc[mi][ni] = __builtin_amdgcn_mfma_f32_16x16x32_bf16(afr[mi], bfr[ni], acc[mi][ni], 0, 0, 0);
    }
  }
  int crow0 = bm + wr * 64 + (lane >> 4) * 4;
  int ccol0 = bn + wc * 64 + (lane & 15);
  #pragma unroll
  for (int mi = 0; mi < 4; ++mi) {
    #pragma unroll
    for (int ni = 0; ni < 4; ++ni) {
      int col = ccol0 + ni * 16;
      float bv = bias[col];
      #pragma unroll
      for (int r = 0; r < 4; ++r) {
        int row = crow0 + mi * 16 + r;
        float v = acc[mi][ni][r] + bv;
        if (ACT) {
          float x = v;
          float t = tanhf(0.7978845608028654f * (x + 0.044715f * x * x * x));
          v = 0.5f * x * (1.0f + t);
        }
        if (OUTBF) Cb[(size_t)row * N + col] = f2b(v);
        else       Cf[(size_t)row * N + col] = v;
      }
    }
  }
}

// ---------------- fp32 -> bf16 convert ----------------
__global__ void f2b_kernel(const float* __restrict__ src,
                           unsigned short* __restrict__ dst, int n) {
  int i = (blockIdx.x * 256 + threadIdx.x) * 4;
  if (i >= n) return;
  float4 v = *(const float4*)(src + i);
  ushort4 o;
  o.x = f2b(v.x); o.y = f2b(v.y); o.z = f2b(v.z); o.w = f2b(v.w);
  *(ushort4*)(dst + i) = o;
}

// ---------------- M measure ----------------
__global__ __launch_bounds__(64) void m_kernel(const float* __restrict__ Q,
                                               const float* __restrict__ K,
                                               const int* __restrict__ idx,
                                               float* __restrict__ Mout) {
  int qrow = blockIdx.x;
  int bh = blockIdx.y;
  int bv = bh >> 3, head = bh & 7;
  int lane = threadIdx.x;
  const float* qv = Q + (size_t)bv * (SEQL * DMOD) + (size_t)qrow * DMOD + head * DHEAD;
  const float* kb = K + (size_t)bv * (SEQL * DMOD) + head * DHEAD;
  float qreg = qv[lane];
  const int* ip = idx + qrow * NSAMP;
  float mx = -INFINITY, sm = 0.f;
  for (int u = 0; u < NSAMP; ++u) {
    int kidx = ip[u];
    float p = qreg * kb[(size_t)kidx * DMOD + lane];
    #pragma unroll
    for (int off = 32; off > 0; off >>= 1) p += __shfl_xor(p, off);
    mx = fmaxf(mx, p);
    sm += p;
  }
  if (lane == 0) Mout[(size_t)bh * SEQL + qrow] = mx - sm * (1.0f / 512.0f);
}

// ---------------- top-k (k=35) ----------------
__global__ __launch_bounds__(256) void topk_kernel(const float* __restrict__ Mv,
                                                   int* __restrict__ top) {
  int bh = blockIdx.x;
  int tid = threadIdx.x;
  __shared__ float vals[512];
  __shared__ float rv[256];
  __shared__ int ri[256];
  vals[tid]       = Mv[(size_t)bh * SEQL + tid];
  vals[tid + 256] = Mv[(size_t)bh * SEQL + tid + 256];
  __syncthreads();
  for (int t = 0; t < NSAMP; ++t) {
    float v0 = vals[tid], v1 = vals[tid + 256];
    float bvv; int bii;
    if (v0 >= v1) { bvv = v0; bii = tid; } else { bvv = v1; bii = tid + 256; }
    rv[tid] = bvv; ri[tid] = bii;
    __syncthreads();
    for (int s = 128; s > 0; s >>= 1) {
      if (tid < s) {
        float ov = rv[tid + s]; int oi = ri[tid + s];
        if (ov > rv[tid] || (ov == rv[tid] && oi < ri[tid])) { rv[tid] = ov; ri[tid] = oi; }
      }
      __syncthreads();
    }
    if (tid == 0) { top[bh * NSAMP + t] = ri[0]; vals[ri[0]] = -INFINITY; }
    __syncthreads();
  }
}

// ---------------- mean of V ----------------
__global__ __launch_bounds__(64) void vmean_kernel(const float* __restrict__ V,
                                                   float* __restrict__ vmean) {
  int bh = blockIdx.x;
  int bv = bh >> 3, head = bh & 7;
  int d = threadIdx.x;
  const float* vb = V + (size_t)bv * (SEQL * DMOD) + head * DHEAD + d;
  float s = 0.f;
  for (int l = 0; l < SEQL; ++l) s += vb[(size_t)l * DMOD];
  vmean[bh * DHEAD + d] = s * (1.0f / 512.0f);
}

// ---------------- ctx = broadcast vmean (bf16 out) ----------------
__global__ void ctx_fill_kernel(const float* __restrict__ vmean,
                                unsigned short* __restrict__ ctxb) {
  size_t i = (size_t)blockIdx.x * 256 + threadIdx.x;
  if (i >= (size_t)SBIG) return;
  int dm = (int)(i & 511);
  int bv = (int)(i >> 18);
  ctxb[i] = f2b(vmean[bv * DMOD + dm]);
}

// ---------------- full attention for selected queries (bf16 ctx out) ----------------
__global__ __launch_bounds__(256) void attn_upd_kernel(const float* __restrict__ Q,
                                                       const float* __restrict__ K,
                                                       const float* __restrict__ V,
                                                       const int* __restrict__ top,
                                                       unsigned short* __restrict__ ctxb) {
  int t = blockIdx.x;
  int bh = blockIdx.y;
  int bv = bh >> 3, head = bh & 7;
  int tid = threadIdx.x;
  int qi = top[bh * NSAMP + t];
  __shared__ float sc[512];
  __shared__ float red[256];
  const float* qv = Q + (size_t)bv * (SEQL * DMOD) + (size_t)qi * DMOD + head * DHEAD;
  const float* kb = K + (size_t)bv * (SEQL * DMOD) + head * DHEAD;
  const float* vb = V + (size_t)bv * (SEQL * DMOD) + head * DHEAD;
  for (int l = tid; l < SEQL; l += 256) {
    const float* kv = kb + (size_t)l * DMOD;
    float s = 0.f;
    #pragma unroll
    for (int d = 0; d < DHEAD; ++d) s += qv[d] * kv[d];
    sc[l] = s * 0.125f;
  }
  __syncthreads();
  red[tid] = fmaxf(sc[tid], sc[tid + 256]);
  __syncthreads();
  for (int s = 128; s > 0; s >>= 1) {
    if (tid < s) red[tid] = fmaxf(red[tid], red[tid + s]);
    __syncthreads();
  }
  float mx = red[0];
  __syncthreads();
  float e0 = expf(sc[tid] - mx), e1 = expf(sc[tid + 256] - mx);
  sc[tid] = e0; sc[tid + 256] = e1;
  red[tid] = e0 + e1;
  __syncthreads();
  for (int s = 128; s > 0; s >>= 1) {
    if (tid < s) red[tid] += red[tid + s];
    __syncthreads();
  }
  float denom = red[0];
  __syncthreads();
  int d = tid & 63, part = tid >> 6;
  float acc = 0.f;
  for (int l = part * 128; l < part * 128 + 128; ++l)
    acc += sc[l] * vb[(size_t)l * DMOD + d];
  red[tid] = acc;
  __syncthreads();
  if (tid < 64) {
    float r = red[tid] + red[tid + 64] + red[tid + 128] + red[tid + 192];
    ctxb[(size_t)bv * (SEQL * DMOD) + (size_t)qi * DMOD + head * DHEAD + tid] = f2b(r / denom);
  }
}

// ---------------- residual add + layernorm (+ optional bf16 mirror) ----------------
__global__ __launch_bounds__(256) void add_ln_kernel(const float* __restrict__ a,
                                                     const float* __restrict__ b,
                                                     const float* __restrict__ g,
                                                     const float* __restrict__ be,
                                                     float* __restrict__ out,
                                                     unsigned short* __restrict__ outb) {
  int r = blockIdx.x;
  int tid = threadIdx.x;
  __shared__ float red[256];
  size_t base = (size_t)r * DMOD;
  float x0 = a[base + tid];
  float x1 = a[base + tid + 256];
  if (b) { x0 += b[base + tid]; x1 += b[base + tid + 256]; }
  red[tid] = x0 + x1;
  __syncthreads();
  for (int s = 128; s > 0; s >>= 1) {
    if (tid < s) red[tid] += red[tid + s];
    __syncthreads();
  }
  float mu = red[0] * (1.0f / 512.0f);
  __syncthreads();
  float d0 = x0 - mu, d1 = x1 - mu;
  red[tid] = d0 * d0 + d1 * d1;
  __syncthreads();
  for (int s = 128; s > 0; s >>= 1) {
    if (tid < s) red[tid] += red[tid + s];
    __syncthreads();
  }
  float rstd = rsqrtf(red[0] * (1.0f / 512.0f) + 1e-5f);
  float o0 = d0 * rstd * g[tid] + be[tid];
  float o1 = d1 * rstd * g[tid + 256] + be[tid + 256];
  out[base + tid]       = o0;
  out[base + tid + 256] = o1;
  if (outb) {
    outb[base + tid]       = f2b(o0);
    outb[base + tid + 256] = f2b(o1);
  }
}

// ---------------- head: split-K partials ----------------
// grid 512, each block handles 4 chunks of 128 floats; partial[(m*96+n)*512 + blk]
__global__ __launch_bounds__(256) void head_partial(const float* __restrict__ h,
                                                    const float* __restrict__ Wh,
                                                    float* __restrict__ partial) {
  __shared__ float hs[28 * 132];
  __shared__ float wsm[96 * 132];
  int blk = blockIdx.x;
  int tid = threadIdx.x;
  int tx = tid & 31, ty = tid >> 5;   // ty 0..7
  float acc[4][3];
  #pragma unroll
  for (int i = 0; i < 4; ++i)
    #pragma unroll
    for (int j = 0; j < 3; ++j) acc[i][j] = 0.f;
  for (int s = 0; s < 4; ++s) {
    int k0 = (blk * 4 + s) * 128;
    __syncthreads();
    for (int c = tid; c < 28 * 32; c += 256) {
      int m = c >> 5, q = c & 31;
      float4 v = *(const float4*)(h + (size_t)m * (SEQL * DMOD) + k0 + q * 4);
      *(float4*)(hs + m * 132 + q * 4) = v;
    }
    for (int c = tid; c < 96 * 32; c += 256) {
      int n = c >> 5, q = c & 31;
      float4 v = *(const float4*)(Wh + (size_t)n * (SEQL * DMOD) + k0 + q * 4);
      *(float4*)(wsm + n * 132 + q * 4) = v;
    }
    __syncthreads();
    for (int k = 0; k < 128; k += 4) {
      float4 hv[4], wv[3];
      #pragma unroll
      for (int i = 0; i < 4; ++i) hv[i] = *(const float4*)(hs + (ty * 4 + i) * 132 + k);
      #pragma unroll
      for (int j = 0; j < 3; ++j) wv[j] = *(const float4*)(wsm + (tx + j * 32) * 132 + k);
      #pragma unroll
      for (int i = 0; i < 4; ++i)
        #pragma unroll
        for (int j = 0; j < 3; ++j)
          acc[i][j] += hv[i].x * wv[j].x + hv[i].y * wv[j].y
                     + hv[i].z * wv[j].z + hv[i].w * wv[j].w;
    }
  }
  #pragma unroll
  for (int i = 0; i < 4; ++i) {
    int m = ty * 4 + i;
    if (m < 28) {
      #pragma unroll
      for (int j = 0; j < 3; ++j) {
        int n = tx + j * 32;
        partial[(size_t)(m * 96 + n) * 512 + blk] = acc[i][j];
      }
    }
  }
}

__global__ __launch_bounds__(256) void head_reduce(const float* __restrict__ partial,
                                                   const float* __restrict__ bh_,
                                                   float* __restrict__ out) {
  int o = blockIdx.x;            // 0..2687 = m*96+p
  int tid = threadIdx.x;
  float s = partial[(size_t)o * 512 + tid] + partial[(size_t)o * 512 + tid + 256];
  __shared__ float red[256];
  red[tid] = s;
  __syncthreads();
  for (int st = 128; st > 0; st >>= 1) {
    if (tid < st) red[tid] += red[tid + st];
    __syncthreads();
  }
  if (tid == 0) {
    int m = o / 96, p = o % 96;
    int b = m / NVARS, v = m % NVARS;
    out[(size_t)b * (NPRED * NVARS) + (size_t)p * NVARS + v] = red[0] + bh_[p];
  }
}

extern "C" void kernel_launch(void* const* d_in, const int* in_sizes, int n_in,
                              void* d_out, int out_size, void* d_ws, size_t ws_size,
                              hipStream_t stream) {
  const float* x_enc = (const float*)d_in[0];
  const float* w_emb = (const float*)d_in[1];
  const float* b_emb = (const float*)d_in[2];
  const float* w_pos = (const float*)d_in[3];
  const float* Wq = (const float*)d_in[4];
  const float* bq = (const float*)d_in[5];
  const float* Wk = (const float*)d_in[6];
  const float* bk = (const float*)d_in[7];
  const float* Wv = (const float*)d_in[8];
  const float* bv_ = (const float*)d_in[9];
  const float* Wo = (const float*)d_in[10];
  const float* bo = (const float*)d_in[11];
  const float* W1 = (const float*)d_in[12];
  const float* b1 = (const float*)d_in[13];
  const float* W2 = (const float*)d_in[14];
  const float* b2 = (const float*)d_in[15];
  const float* g1 = (const float*)d_in[16];
  const float* be1 = (const float*)d_in[17];
  const float* g2 = (const float*)d_in[18];
  const float* be2 = (const float*)d_in[19];
  const float* gF = (const float*)d_in[20];
  const float* bF = (const float*)d_in[21];
  const float* Wh = (const float*)d_in[22];
  const float* bh_ = (const float*)d_in[23];
  float* out = (float*)d_out;

  const size_t S = (size_t)SBIG;
  const size_t SB = S * 4;
  char* ws = (char*)d_ws;
  float* h   = (float*)(ws);
  float* Qb  = (float*)(ws + SB);
  float* Kb  = (float*)(ws + 2 * SB);
  float* Vb  = (float*)(ws + 3 * SB);
  float* Ob  = (float*)(ws + 4 * SB);
  unsigned short* h_bf = (unsigned short*)(ws + 5 * SB);
  unsigned short* CTXb = (unsigned short*)(ws + 5 * SB + SB / 2);
  int*   idx = (int*)(ws + 6 * SB);
  float* Mv  = (float*)(ws + 6 * SB + 0x20000);
  int*   top = (int*)(ws + 6 * SB + 0x20000 + 0x80000);
  float* vmean = (float*)(ws + 6 * SB + 0x20000 + 0x80000 + 0x10000);
  // aliases (regions dead by the time these are used):
  unsigned short* FFNb = (unsigned short*)Qb;              // 58.7 MB over Qb+Kb
  float* partial = Qb;                                     // 5.5 MB, head phase
  unsigned short* Wo_b = (unsigned short*)Vb;              // after attn reads V
  unsigned short* W1_b = (unsigned short*)((char*)Vb + (1 << 20));
  unsigned short* W2_b = (unsigned short*)((char*)Vb + (4 << 20));
  if (ws_size < 6 * SB + 0x20000 + 0x80000 + 0x10000 + 0x10000) return;

  dim3 b256(256);
  int gBig = (int)((S + 255) / 256);

  embed_kernel<<<gBig, b256, 0, stream>>>(x_enc, w_emb, b_emb, w_pos, h);

  for (int l = 0; l < 2; ++l) {
    const float* Wql = Wq + (size_t)l * DMOD * DMOD;
    const float* Wkl = Wk + (size_t)l * DMOD * DMOD;
    const float* Wvl = Wv + (size_t)l * DMOD * DMOD;
    const float* Wol = Wo + (size_t)l * DMOD * DMOD;
    const float* W1l = W1 + (size_t)l * DFFN * DMOD;
    const float* W2l = W2 + (size_t)l * DMOD * DFFN;

    dim3 gq(DMOD / 64, NROWS / 64);
    gemm_bt<<<gq, b256, 0, stream>>>(h, Wql, bq + l * DMOD, Qb, NROWS, DMOD, DMOD);
    gemm_bt<<<gq, b256, 0, stream>>>(h, Wkl, bk + l * DMOD, Kb, NROWS, DMOD, DMOD);
    gemm_bt<<<gq, b256, 0, stream>>>(h, Wvl, bv_ + l * DMOD, Vb, NROWS, DMOD, DMOD);

    make_idx_kernel<<<(SEQL * NSAMP + 255) / 256, b256, 0, stream>>>(l, idx);
    m_kernel<<<dim3(SEQL, NBH), dim3(64), 0, stream>>>(Qb, Kb, idx, Mv);
    topk_kernel<<<NBH, b256, 0, stream>>>(Mv, top);
    vmean_kernel<<<NBH, dim3(64), 0, stream>>>(Vb, vmean);
    ctx_fill_kernel<<<gBig, b256, 0, stream>>>(vmean, CTXb);
    attn_upd_kernel<<<dim3(NSAMP, NBH), b256, 0, stream>>>(Qb, Kb, Vb, top, CTXb);

    // weight conversions (V region is dead now)
    f2b_kernel<<<(DMOD * DMOD / 4 + 255) / 256, b256, 0, stream>>>(Wol, Wo_b, DMOD * DMOD);
    f2b_kernel<<<(DFFN * DMOD / 4 + 255) / 256, b256, 0, stream>>>(W1l, W1_b, DFFN * DMOD);
    f2b_kernel<<<(DMOD * DFFN / 4 + 255) / 256, b256, 0, stream>>>(W2l, W2_b, DMOD * DFFN);

    dim3 go(DMOD / 128, NROWS / 128);
    gemm_mfma<0, 0><<<go, b256, 0, stream>>>(CTXb, Wo_b, bo + l * DMOD, Ob, (unsigned short*)0, NROWS, DMOD, DMOD);
    add_ln_kernel<<<NROWS, b256, 0, stream>>>(h, Ob, g1 + l * DMOD, be1 + l * DMOD, h, h_bf);

    dim3 gf1(DFFN / 128, NROWS / 128);
    gemm_mfma<1, 1><<<gf1, b256, 0, stream>>>(h_bf, W1_b, b1 + l * DFFN, (float*)0, FFNb, NROWS, DFFN, DMOD);
    dim3 gf2(DMOD / 128, NROWS / 128);
    gemm_mfma<0, 0><<<gf2, b256, 0, stream>>>(FFNb, W2_b, b2 + l * DMOD, Ob, (unsigned short*)0, NROWS, DMOD, DFFN);
    add_ln_kernel<<<NROWS, b256, 0, stream>>>(h, Ob, g2 + l * DMOD, be2 + l * DMOD, h, (unsigned short*)0);
  }

  add_ln_kernel<<<NROWS, b256, 0, stream>>>(h, (const float*)0, gF, bF, h, (unsigned short*)0);
  head_partial<<<512, b256, 0, stream>>>(h, Wh, partial);
  head_reduce<<<NBV * NPRED, b256, 0, stream>>>(partial, bh_, out);
}

// Round 3
// 1819.318 us; speedup vs baseline: 3.1246x; 1.4244x over previous
//
#include <hip/hip_runtime.h>
#include <math.h>

#define SEQL 512
#define DMOD 512
#define NHEAD 8
#define DHEAD 64
#define DFFN 2048
#define NBATCH 4
#define NVARS 7
#define NBV 28          // NBATCH*NVARS
#define NBH 224         // NBV*NHEAD
#define NROWS 14336     // NBV*SEQL
#define NSAMP 35        // U_part = u = 35
#define NPRED 96
#define SBIG 7340032    // NBV*SEQL*DMOD floats
#define QKVS 1536       // fused QKV row stride

typedef short bf16x8 __attribute__((ext_vector_type(8)));
typedef float f32x4 __attribute__((ext_vector_type(4)));

__device__ inline unsigned short f2b(float f) {
  unsigned u = __builtin_bit_cast(unsigned, f);
  unsigned r = (u + 0x7FFFu + ((u >> 16) & 1u)) >> 16;
  return (unsigned short)r;
}
__device__ inline float b2f(unsigned short h) {
  return __builtin_bit_cast(float, (unsigned)h << 16);
}

// ---------------- threefry2x32 (matches jax._src.prng) ----------------
__device__ inline void threefry2x32(unsigned k0, unsigned k1,
                                    unsigned x0, unsigned x1,
                                    unsigned &o0, unsigned &o1) {
  unsigned ks2 = k0 ^ k1 ^ 0x1BD11BDAu;
  unsigned ks[3] = {k0, k1, ks2};
  x0 += k0; x1 += k1;
  const unsigned rot[2][4] = {{13u,15u,26u,6u},{17u,29u,16u,24u}};
  #pragma unroll
  for (int i = 0; i < 5; ++i) {
    #pragma unroll
    for (int j = 0; j < 4; ++j) {
      unsigned r = rot[i & 1][j];
      x0 += x1;
      x1 = (x1 << r) | (x1 >> (32u - r));
      x1 ^= x0;
    }
    x0 += ks[(i + 1) % 3];
    x1 += ks[(i + 2) % 3] + (unsigned)(i + 1);
  }
  o0 = x0; o1 = x1;
}

__global__ void make_idx_kernel(int layer, int* idx) {
  int i = blockIdx.x * 256 + threadIdx.x;
  if (i >= SEQL * NSAMP) return;
  unsigned kl0, kl1, o0, o1;
  threefry2x32(0u, 42u, 0u, (unsigned)layer, kl0, kl1);
  threefry2x32(kl0, kl1, (unsigned)i, (unsigned)(SEQL * NSAMP + i), o0, o1);
  idx[i] = (int)(o1 & 511u);
}

// ---------------- embedding ----------------
__global__ void embed_kernel(const float* __restrict__ x_enc,
                             const float* __restrict__ w_emb,
                             const float* __restrict__ b_emb,
                             const float* __restrict__ w_pos,
                             float* __restrict__ h) {
  size_t i = (size_t)blockIdx.x * 256 + threadIdx.x;
  if (i >= (size_t)SBIG) return;
  int dm = (int)(i & 511);
  int l  = (int)((i >> 9) & 511);
  int bv = (int)(i >> 18);
  int b = bv / NVARS, v = bv % NVARS;
  h[i] = x_enc[((size_t)b * SEQL + l) * NVARS + v] * w_emb[dm] + b_emb[dm]
         + w_pos[(size_t)l * DMOD + dm];
}

// ---------------- fp32 -> (bf16 hi, bf16 lo) split ----------------
__global__ void split_hilo(const float* __restrict__ src,
                           unsigned short* __restrict__ hi,
                           unsigned short* __restrict__ lo, int n) {
  int i = (blockIdx.x * 256 + threadIdx.x) * 4;
  if (i >= n) return;
  float4 v = *(const float4*)(src + i);
  ushort4 h4, l4;
  h4.x = f2b(v.x); l4.x = f2b(v.x - b2f(h4.x));
  h4.y = f2b(v.y); l4.y = f2b(v.y - b2f(h4.y));
  h4.z = f2b(v.z); l4.z = f2b(v.z - b2f(h4.z));
  h4.w = f2b(v.w); l4.w = f2b(v.w - b2f(h4.w));
  *(ushort4*)(hi + i) = h4;
  *(ushort4*)(lo + i) = l4;
}

// ---------------- fp32 -> bf16 convert ----------------
__global__ void f2b_kernel(const float* __restrict__ src,
                           unsigned short* __restrict__ dst, int n) {
  int i = (blockIdx.x * 256 + threadIdx.x) * 4;
  if (i >= n) return;
  float4 v = *(const float4*)(src + i);
  ushort4 o;
  o.x = f2b(v.x); o.y = f2b(v.y); o.z = f2b(v.z); o.w = f2b(v.w);
  *(ushort4*)(dst + i) = o;
}

__global__ void bias_cat(const float* __restrict__ bq, const float* __restrict__ bk,
                         const float* __restrict__ bv, float* __restrict__ bc) {
  int i = blockIdx.x * 256 + threadIdx.x;
  if (i >= 1536) return;
  bc[i] = i < 512 ? bq[i] : (i < 1024 ? bk[i - 512] : bv[i - 1024]);
}

// ---------------- split-bf16 MFMA GEMM (3-pass hi/lo): C = A@W^T + bias ----------------
// fp32-comparable accuracy. 128x128 tile, BK=64, 4 waves, 16x16x32 MFMA.
__global__ __launch_bounds__(256) void gemm_mfma3(const unsigned short* __restrict__ Ah,
                                                  const unsigned short* __restrict__ Al,
                                                  const unsigned short* __restrict__ Bh,
                                                  const unsigned short* __restrict__ Bl,
                                                  const float* __restrict__ bias,
                                                  float* __restrict__ C,
                                                  int M, int N, int K, int ldc) {
  __shared__ __align__(16) unsigned short AsH[128 * 64];
  __shared__ __align__(16) unsigned short AsL[128 * 64];
  __shared__ __align__(16) unsigned short BsH[128 * 64];
  __shared__ __align__(16) unsigned short BsL[128 * 64];
  int bm = blockIdx.y * 128, bn = blockIdx.x * 128;
  int tid = threadIdx.x;
  int wave = tid >> 6, lane = tid & 63;
  int wr = wave >> 1, wc = wave & 1;
  int r16 = lane & 15, kq = lane >> 4;

  f32x4 acc[4][4];
  #pragma unroll
  for (int i = 0; i < 4; ++i)
    #pragma unroll
    for (int j = 0; j < 4; ++j) acc[i][j] = (f32x4){0.f, 0.f, 0.f, 0.f};

  for (int kt = 0; kt < K; kt += 64) {
    __syncthreads();
    #pragma unroll
    for (int i = 0; i < 4; ++i) {
      int c = i * 256 + tid;
      int row = c >> 3, kb = c & 7;
      size_t offA = (size_t)(bm + row) * K + kt + kb * 8;
      size_t offB = (size_t)(bn + row) * K + kt + kb * 8;
      uint4 vah = *(const uint4*)(Ah + offA);
      uint4 val = *(const uint4*)(Al + offA);
      uint4 vbh = *(const uint4*)(Bh + offB);
      uint4 vbl = *(const uint4*)(Bl + offB);
      int sw = ((row << 7) | (kb << 4)) ^ ((row & 7) << 4);
      *(uint4*)((char*)AsH + sw) = vah;
      *(uint4*)((char*)AsL + sw) = val;
      *(uint4*)((char*)BsH + sw) = vbh;
      *(uint4*)((char*)BsL + sw) = vbl;
    }
    __syncthreads();
    #pragma unroll
    for (int ks = 0; ks < 2; ++ks) {
      bf16x8 ah[4], al[4], bh[4], bl[4];
      #pragma unroll
      for (int mi = 0; mi < 4; ++mi) {
        int row = wr * 64 + mi * 16 + r16;
        int addr = ((row << 7) | (ks << 6) | (kq << 4)) ^ ((row & 7) << 4);
        ah[mi] = *(const bf16x8*)((const char*)AsH + addr);
        al[mi] = *(const bf16x8*)((const char*)AsL + addr);
      }
      #pragma unroll
      for (int ni = 0; ni < 4; ++ni) {
        int row = wc * 64 + ni * 16 + r16;
        int addr = ((row << 7) | (ks << 6) | (kq << 4)) ^ ((row & 7) << 4);
        bh[ni] = *(const bf16x8*)((const char*)BsH + addr);
        bl[ni] = *(const bf16x8*)((const char*)BsL + addr);
      }
      #pragma unroll
      for (int mi = 0; mi < 4; ++mi)
        #pragma unroll
        for (int ni = 0; ni < 4; ++ni) {
          acc[mi][ni] = __builtin_amdgcn_mfma_f32_16x16x32_bf16(ah[mi], bh[ni], acc[mi][ni], 0, 0, 0);
          acc[mi][ni] = __builtin_amdgcn_mfma_f32_16x16x32_bf16(ah[mi], bl[ni], acc[mi][ni], 0, 0, 0);
          acc[mi][ni] = __builtin_amdgcn_mfma_f32_16x16x32_bf16(al[mi], bh[ni], acc[mi][ni], 0, 0, 0);
        }
    }
  }
  int crow0 = bm + wr * 64 + (lane >> 4) * 4;
  int ccol0 = bn + wc * 64 + (lane & 15);
  #pragma unroll
  for (int mi = 0; mi < 4; ++mi) {
    #pragma unroll
    for (int ni = 0; ni < 4; ++ni) {
      int col = ccol0 + ni * 16;
      float bvv = bias[col];
      #pragma unroll
      for (int r = 0; r < 4; ++r) {
        int row = crow0 + mi * 16 + r;
        C[(size_t)row * ldc + col] = acc[mi][ni][r] + bvv;
      }
    }
  }
}

// ---------------- bf16 MFMA GEMM (single): C = A@W^T + bias, opt gelu ----------------
template<int ACT, int OUTBF>
__global__ __launch_bounds__(256) void gemm_mfma(const unsigned short* __restrict__ A,
                                                 const unsigned short* __restrict__ W,
                                                 const float* __restrict__ bias,
                                                 float* __restrict__ Cf,
                                                 unsigned short* __restrict__ Cb,
                                                 int M, int N, int K) {
  __shared__ __align__(16) unsigned short As[128 * 64];
  __shared__ __align__(16) unsigned short Bs[128 * 64];
  int bm = blockIdx.y * 128, bn = blockIdx.x * 128;
  int tid = threadIdx.x;
  int wave = tid >> 6, lane = tid & 63;
  int wr = wave >> 1, wc = wave & 1;
  int r16 = lane & 15, kq = lane >> 4;

  f32x4 acc[4][4];
  #pragma unroll
  for (int i = 0; i < 4; ++i)
    #pragma unroll
    for (int j = 0; j < 4; ++j) acc[i][j] = (f32x4){0.f, 0.f, 0.f, 0.f};

  for (int kt = 0; kt < K; kt += 64) {
    __syncthreads();
    #pragma unroll
    for (int i = 0; i < 4; ++i) {
      int c = i * 256 + tid;
      int row = c >> 3, kb = c & 7;
      uint4 va = *(const uint4*)(A + (size_t)(bm + row) * K + kt + kb * 8);
      uint4 vb = *(const uint4*)(W + (size_t)(bn + row) * K + kt + kb * 8);
      int sw = ((row << 7) | (kb << 4)) ^ ((row & 7) << 4);
      *(uint4*)((char*)As + sw) = va;
      *(uint4*)((char*)Bs + sw) = vb;
    }
    __syncthreads();
    #pragma unroll
    for (int ks = 0; ks < 2; ++ks) {
      bf16x8 afr[4], bfr[4];
      #pragma unroll
      for (int mi = 0; mi < 4; ++mi) {
        int row = wr * 64 + mi * 16 + r16;
        int addr = ((row << 7) | (ks << 6) | (kq << 4)) ^ ((row & 7) << 4);
        afr[mi] = *(const bf16x8*)((const char*)As + addr);
      }
      #pragma unroll
      for (int ni = 0; ni < 4; ++ni) {
        int row = wc * 64 + ni * 16 + r16;
        int addr = ((row << 7) | (ks << 6) | (kq << 4)) ^ ((row & 7) << 4);
        bfr[ni] = *(const bf16x8*)((const char*)Bs + addr);
      }
      #pragma unroll
      for (int mi = 0; mi < 4; ++mi)
        #pragma unroll
        for (int ni = 0; ni < 4; ++ni)
          acc[mi][ni] = __builtin_amdgcn_mfma_f32_16x16x32_bf16(afr[mi], bfr[ni], acc[mi][ni], 0, 0, 0);
    }
  }
  int crow0 = bm + wr * 64 + (lane >> 4) * 4;
  int ccol0 = bn + wc * 64 + (lane & 15);
  #pragma unroll
  for (int mi = 0; mi < 4; ++mi) {
    #pragma unroll
    for (int ni = 0; ni < 4; ++ni) {
      int col = ccol0 + ni * 16;
      float bvv = bias[col];
      #pragma unroll
      for (int r = 0; r < 4; ++r) {
        int row = crow0 + mi * 16 + r;
        float v = acc[mi][ni][r] + bvv;
        if (ACT) {
          float x = v;
          float t = tanhf(0.7978845608028654f * (x + 0.044715f * x * x * x));
          v = 0.5f * x * (1.0f + t);
        }
        if (OUTBF) Cb[(size_t)row * N + col] = f2b(v);
        else       Cf[(size_t)row * N + col] = v;
      }
    }
  }
}

// ---------------- M measure: block per (bh), K staged in LDS ----------------
__global__ __launch_bounds__(512) void m2_kernel(const float* __restrict__ QKV,
                                                 const int* __restrict__ idx,
                                                 float* __restrict__ Mout) {
  int bh = blockIdx.x;
  int bv = bh >> 3, head = bh & 7;
  int tid = threadIdx.x;                 // 0..511, one q-row each
  __shared__ float Ks[512 * 65];         // stride 65: bank=(kidx+d)%32
  const float* base = QKV + (size_t)bv * (SEQL * QKVS);
  for (int c = tid; c < 512 * 64; c += 512) {
    int l = c >> 6, d = c & 63;
    Ks[l * 65 + d] = base[(size_t)l * QKVS + 512 + head * 64 + d];
  }
  float q[64];
  const float* qp = base + (size_t)tid * QKVS + head * 64;
  #pragma unroll
  for (int d = 0; d < 64; ++d) q[d] = qp[d];
  __syncthreads();
  const int* ip = idx + tid * NSAMP;
  float mx = -INFINITY, sm = 0.f;
  for (int u = 0; u < NSAMP; ++u) {
    int kidx = ip[u];
    const float* kr = Ks + kidx * 65;
    float s = 0.f;
    #pragma unroll
    for (int d = 0; d < 64; ++d) s += q[d] * kr[d];
    mx = fmaxf(mx, s);
    sm += s;
  }
  Mout[(size_t)bh * SEQL + tid] = mx - sm * (1.0f / 512.0f);
}

// ---------------- top-k (k=35) ----------------
__global__ __launch_bounds__(256) void topk_kernel(const float* __restrict__ Mv,
                                                   int* __restrict__ top) {
  int bh = blockIdx.x;
  int tid = threadIdx.x;
  __shared__ float vals[512];
  __shared__ float rv[256];
  __shared__ int ri[256];
  vals[tid]       = Mv[(size_t)bh * SEQL + tid];
  vals[tid + 256] = Mv[(size_t)bh * SEQL + tid + 256];
  __syncthreads();
  for (int t = 0; t < NSAMP; ++t) {
    float v0 = vals[tid], v1 = vals[tid + 256];
    float bvv; int bii;
    if (v0 >= v1) { bvv = v0; bii = tid; } else { bvv = v1; bii = tid + 256; }
    rv[tid] = bvv; ri[tid] = bii;
    __syncthreads();
    for (int s = 128; s > 0; s >>= 1) {
      if (tid < s) {
        float ov = rv[tid + s]; int oi = ri[tid + s];
        if (ov > rv[tid] || (ov == rv[tid] && oi < ri[tid])) { rv[tid] = ov; ri[tid] = oi; }
      }
      __syncthreads();
    }
    if (tid == 0) { top[bh * NSAMP + t] = ri[0]; vals[ri[0]] = -INFINITY; }
    __syncthreads();
  }
}

// ---------------- mean of V ----------------
__global__ __launch_bounds__(64) void vmean_kernel(const float* __restrict__ QKV,
                                                   float* __restrict__ vmean) {
  int bh = blockIdx.x;
  int bv = bh >> 3, head = bh & 7;
  int d = threadIdx.x;
  const float* vb = QKV + (size_t)bv * (SEQL * QKVS) + 1024 + head * 64 + d;
  float s = 0.f;
  for (int l = 0; l < SEQL; ++l) s += vb[(size_t)l * QKVS];
  vmean[bh * DHEAD + d] = s * (1.0f / 512.0f);
}

// ---------------- ctx = broadcast vmean (bf16 out) ----------------
__global__ void ctx_fill_kernel(const float* __restrict__ vmean,
                                unsigned short* __restrict__ ctxb) {
  size_t i = (size_t)blockIdx.x * 256 + threadIdx.x;
  if (i >= (size_t)SBIG) return;
  int dm = (int)(i & 511);
  int bv = (int)(i >> 18);
  ctxb[i] = f2b(vmean[bv * DMOD + dm]);
}

// ---------------- full attention for selected queries ----------------
__global__ __launch_bounds__(256) void attn_upd_kernel(const float* __restrict__ QKV,
                                                       const int* __restrict__ top,
                                                       unsigned short* __restrict__ ctxb) {
  int t = blockIdx.x;
  int bh = blockIdx.y;
  int bv = bh >> 3, head = bh & 7;
  int tid = threadIdx.x;
  int qi = top[bh * NSAMP + t];
  __shared__ float qs[64];
  __shared__ float sc[512];
  __shared__ float red[256];
  const float* base = QKV + (size_t)bv * (SEQL * QKVS);
  if (tid < 64) qs[tid] = base[(size_t)qi * QKVS + head * 64 + tid];
  __syncthreads();
  for (int l = tid; l < SEQL; l += 256) {
    const float* kv = base + (size_t)l * QKVS + 512 + head * 64;
    float s = 0.f;
    #pragma unroll
    for (int d = 0; d < DHEAD; d += 4) {
      float4 k4 = *(const float4*)(kv + d);
      s += qs[d] * k4.x + qs[d + 1] * k4.y + qs[d + 2] * k4.z + qs[d + 3] * k4.w;
    }
    sc[l] = s * 0.125f;
  }
  __syncthreads();
  red[tid] = fmaxf(sc[tid], sc[tid + 256]);
  __syncthreads();
  for (int s = 128; s > 0; s >>= 1) {
    if (tid < s) red[tid] = fmaxf(red[tid], red[tid + s]);
    __syncthreads();
  }
  float mx = red[0];
  __syncthreads();
  float e0 = expf(sc[tid] - mx), e1 = expf(sc[tid + 256] - mx);
  sc[tid] = e0; sc[tid + 256] = e1;
  red[tid] = e0 + e1;
  __syncthreads();
  for (int s = 128; s > 0; s >>= 1) {
    if (tid < s) red[tid] += red[tid + s];
    __syncthreads();
  }
  float denom = red[0];
  __syncthreads();
  int d = tid & 63, part = tid >> 6;
  float acc = 0.f;
  for (int l = part * 128; l < part * 128 + 128; ++l)
    acc += sc[l] * base[(size_t)l * QKVS + 1024 + head * 64 + d];
  red[tid] = acc;
  __syncthreads();
  if (tid < 64) {
    float r = red[tid] + red[tid + 64] + red[tid + 128] + red[tid + 192];
    ctxb[(size_t)bv * (SEQL * DMOD) + (size_t)qi * DMOD + head * DHEAD + tid] = f2b(r / denom);
  }
}

// ---------------- residual add + layernorm (+ optional bf16 mirror) ----------------
__global__ __launch_bounds__(256) void add_ln_kernel(const float* __restrict__ a,
                                                     const float* __restrict__ b,
                                                     const float* __restrict__ g,
                                                     const float* __restrict__ be,
                                                     float* __restrict__ out,
                                                     unsigned short* __restrict__ outb) {
  int r = blockIdx.x;
  int tid = threadIdx.x;
  __shared__ float red[256];
  size_t base = (size_t)r * DMOD;
  float x0 = a[base + tid];
  float x1 = a[base + tid + 256];
  if (b) { x0 += b[base + tid]; x1 += b[base + tid + 256]; }
  red[tid] = x0 + x1;
  __syncthreads();
  for (int s = 128; s > 0; s >>= 1) {
    if (tid < s) red[tid] += red[tid + s];
    __syncthreads();
  }
  float mu = red[0] * (1.0f / 512.0f);
  __syncthreads();
  float d0 = x0 - mu, d1 = x1 - mu;
  red[tid] = d0 * d0 + d1 * d1;
  __syncthreads();
  for (int s = 128; s > 0; s >>= 1) {
    if (tid < s) red[tid] += red[tid + s];
    __syncthreads();
  }
  float rstd = rsqrtf(red[0] * (1.0f / 512.0f) + 1e-5f);
  float o0 = d0 * rstd * g[tid] + be[tid];
  float o1 = d1 * rstd * g[tid + 256] + be[tid + 256];
  out[base + tid]       = o0;
  out[base + tid + 256] = o1;
  if (outb) {
    outb[base + tid]       = f2b(o0);
    outb[base + tid + 256] = f2b(o1);
  }
}

// ---------------- head: split-K partials ----------------
__global__ __launch_bounds__(256) void head_partial(const float* __restrict__ h,
                                                    const float* __restrict__ Wh,
                                                    float* __restrict__ partial) {
  __shared__ float hs[28 * 132];
  __shared__ float wsm[96 * 132];
  int blk = blockIdx.x;
  int tid = threadIdx.x;
  int tx = tid & 31, ty = tid >> 5;
  float acc[4][3];
  #pragma unroll
  for (int i = 0; i < 4; ++i)
    #pragma unroll
    for (int j = 0; j < 3; ++j) acc[i][j] = 0.f;
  for (int s = 0; s < 4; ++s) {
    int k0 = (blk * 4 + s) * 128;
    __syncthreads();
    for (int c = tid; c < 28 * 32; c += 256) {
      int m = c >> 5, q = c & 31;
      float4 v = *(const float4*)(h + (size_t)m * (SEQL * DMOD) + k0 + q * 4);
      *(float4*)(hs + m * 132 + q * 4) = v;
    }
    for (int c = tid; c < 96 * 32; c += 256) {
      int n = c >> 5, q = c & 31;
      float4 v = *(const float4*)(Wh + (size_t)n * (SEQL * DMOD) + k0 + q * 4);
      *(float4*)(wsm + n * 132 + q * 4) = v;
    }
    __syncthreads();
    for (int k = 0; k < 128; k += 4) {
      float4 hv[4], wv[3];
      #pragma unroll
      for (int i = 0; i < 4; ++i) hv[i] = *(const float4*)(hs + (ty * 4 + i) * 132 + k);
      #pragma unroll
      for (int j = 0; j < 3; ++j) wv[j] = *(const float4*)(wsm + (tx + j * 32) * 132 + k);
      #pragma unroll
      for (int i = 0; i < 4; ++i)
        #pragma unroll
        for (int j = 0; j < 3; ++j)
          acc[i][j] += hv[i].x * wv[j].x + hv[i].y * wv[j].y
                     + hv[i].z * wv[j].z + hv[i].w * wv[j].w;
    }
  }
  #pragma unroll
  for (int i = 0; i < 4; ++i) {
    int m = ty * 4 + i;
    if (m < 28) {
      #pragma unroll
      for (int j = 0; j < 3; ++j) {
        int n = tx + j * 32;
        partial[(size_t)(m * 96 + n) * 512 + blk] = acc[i][j];
      }
    }
  }
}

__global__ __launch_bounds__(256) void head_reduce(const float* __restrict__ partial,
                                                   const float* __restrict__ bh_,
                                                   float* __restrict__ out) {
  int o = blockIdx.x;
  int tid = threadIdx.x;
  float s = partial[(size_t)o * 512 + tid] + partial[(size_t)o * 512 + tid + 256];
  __shared__ float red[256];
  red[tid] = s;
  __syncthreads();
  for (int st = 128; st > 0; st >>= 1) {
    if (tid < st) red[tid] += red[tid + st];
    __syncthreads();
  }
  if (tid == 0) {
    int m = o / 96, p = o % 96;
    int b = m / NVARS, v = m % NVARS;
    out[(size_t)b * (NPRED * NVARS) + (size_t)p * NVARS + v] = red[0] + bh_[p];
  }
}

extern "C" void kernel_launch(void* const* d_in, const int* in_sizes, int n_in,
                              void* d_out, int out_size, void* d_ws, size_t ws_size,
                              hipStream_t stream) {
  const float* x_enc = (const float*)d_in[0];
  const float* w_emb = (const float*)d_in[1];
  const float* b_emb = (const float*)d_in[2];
  const float* w_pos = (const float*)d_in[3];
  const float* Wq = (const float*)d_in[4];
  const float* bq = (const float*)d_in[5];
  const float* Wk = (const float*)d_in[6];
  const float* bk = (const float*)d_in[7];
  const float* Wv = (const float*)d_in[8];
  const float* bv_ = (const float*)d_in[9];
  const float* Wo = (const float*)d_in[10];
  const float* bo = (const float*)d_in[11];
  const float* W1 = (const float*)d_in[12];
  const float* b1 = (const float*)d_in[13];
  const float* W2 = (const float*)d_in[14];
  const float* b2 = (const float*)d_in[15];
  const float* g1 = (const float*)d_in[16];
  const float* be1 = (const float*)d_in[17];
  const float* g2 = (const float*)d_in[18];
  const float* be2 = (const float*)d_in[19];
  const float* gF = (const float*)d_in[20];
  const float* bF = (const float*)d_in[21];
  const float* Wh = (const float*)d_in[22];
  const float* bh_ = (const float*)d_in[23];
  float* out = (float*)d_out;

  const size_t S = (size_t)SBIG;
  const size_t SB = S * 4;                    // 29,360,128 B
  char* ws = (char*)d_ws;
  float* h    = (float*)(ws);                 // [0, SB)
  float* QKV  = (float*)(ws + SB);            // [SB, 4SB): [14336][1536] fp32
  float* Ob   = (float*)(ws + 4 * SB);        // [4SB, 5SB)
  unsigned short* h_hi = (unsigned short*)(ws + 5 * SB);           // SB/2
  unsigned short* h_lo = (unsigned short*)(ws + 5 * SB + SB / 2);  // SB/2
  // phase aliases:
  unsigned short* CTXb = h_hi;                            // after QKV gemm done
  unsigned short* h_bf = h_lo;                            // after ln1
  unsigned short* FFNb = (unsigned short*)QKV;            // 2SB, after attn
  float* partial = QKV;                                   // head phase
  unsigned short* Wo_b = (unsigned short*)((char*)QKV + 2 * SB);            // 0.5MB
  unsigned short* W1_b = (unsigned short*)((char*)QKV + 2 * SB + (1 << 20)); // 2MB
  unsigned short* W2_b = (unsigned short*)((char*)QKV + 2 * SB + (4 << 20)); // 2MB
  unsigned short* Wqkv_hi = (unsigned short*)Ob;                       // 1.5MB
  unsigned short* Wqkv_lo = (unsigned short*)((char*)Ob + 0x180000);   // 1.5MB
  int*   idx = (int*)(ws + 6 * SB);                        // 70KB
  float* Mv  = (float*)(ws + 6 * SB + 0x20000);            // 448KB
  int*   top = (int*)(ws + 6 * SB + 0xA0000);              // 31KB
  float* vmean = (float*)(ws + 6 * SB + 0xB0000);          // 56KB
  float* bias_c = (float*)(ws + 6 * SB + 0xB0000 + 0xE800); // 6KB
  if (ws_size < 6 * SB + 0xC0000) return;

  dim3 b256(256);
  int gBig = (int)((S + 255) / 256);

  embed_kernel<<<gBig, b256, 0, stream>>>(x_enc, w_emb, b_emb, w_pos, h);

  for (int l = 0; l < 2; ++l) {
    const float* Wql = Wq + (size_t)l * DMOD * DMOD;
    const float* Wkl = Wk + (size_t)l * DMOD * DMOD;
    const float* Wvl = Wv + (size_t)l * DMOD * DMOD;
    const float* Wol = Wo + (size_t)l * DMOD * DMOD;
    const float* W1l = W1 + (size_t)l * DFFN * DMOD;
    const float* W2l = W2 + (size_t)l * DMOD * DFFN;

    // hi/lo splits for exact-enough QKV
    split_hilo<<<(int)(S / 4 + 255) / 256, b256, 0, stream>>>(h, h_hi, h_lo, (int)S);
    split_hilo<<<(DMOD * DMOD / 4 + 255) / 256, b256, 0, stream>>>(Wql, Wqkv_hi, Wqkv_lo, DMOD * DMOD);
    split_hilo<<<(DMOD * DMOD / 4 + 255) / 256, b256, 0, stream>>>(Wkl, Wqkv_hi + DMOD * DMOD, Wqkv_lo + DMOD * DMOD, DMOD * DMOD);
    split_hilo<<<(DMOD * DMOD / 4 + 255) / 256, b256, 0, stream>>>(Wvl, Wqkv_hi + 2 * DMOD * DMOD, Wqkv_lo + 2 * DMOD * DMOD, DMOD * DMOD);
    bias_cat<<<6, b256, 0, stream>>>(bq + l * DMOD, bk + l * DMOD, bv_ + l * DMOD, bias_c);

    // fused QKV projection, fp32-accurate via 3-pass hi/lo MFMA
    dim3 gqkv(QKVS / 128, NROWS / 128);
    gemm_mfma3<<<gqkv, b256, 0, stream>>>(h_hi, h_lo, Wqkv_hi, Wqkv_lo, bias_c,
                                          QKV, NROWS, QKVS, DMOD, QKVS);

    make_idx_kernel<<<(SEQL * NSAMP + 255) / 256, b256, 0, stream>>>(l, idx);
    m2_kernel<<<NBH, dim3(512), 0, stream>>>(QKV, idx, Mv);
    topk_kernel<<<NBH, b256, 0, stream>>>(Mv, top);
    vmean_kernel<<<NBH, dim3(64), 0, stream>>>(QKV, vmean);
    ctx_fill_kernel<<<gBig, b256, 0, stream>>>(vmean, CTXb);
    attn_upd_kernel<<<dim3(NSAMP, NBH), b256, 0, stream>>>(QKV, top, CTXb);

    // weight bf16 conversions into dead QKV tail
    f2b_kernel<<<(DMOD * DMOD / 4 + 255) / 256, b256, 0, stream>>>(Wol, Wo_b, DMOD * DMOD);
    f2b_kernel<<<(DFFN * DMOD / 4 + 255) / 256, b256, 0, stream>>>(W1l, W1_b, DFFN * DMOD);
    f2b_kernel<<<(DMOD * DFFN / 4 + 255) / 256, b256, 0, stream>>>(W2l, W2_b, DMOD * DFFN);

    dim3 go(DMOD / 128, NROWS / 128);
    gemm_mfma<0, 0><<<go, b256, 0, stream>>>(CTXb, Wo_b, bo + l * DMOD, Ob, (unsigned short*)0, NROWS, DMOD, DMOD);
    add_ln_kernel<<<NROWS, b256, 0, stream>>>(h, Ob, g1 + l * DMOD, be1 + l * DMOD, h, h_bf);

    dim3 gf1(DFFN / 128, NROWS / 128);
    gemm_mfma<1, 1><<<gf1, b256, 0, stream>>>(h_bf, W1_b, b1 + l * DFFN, (float*)0, FFNb, NROWS, DFFN, DMOD);
    dim3 gf2(DMOD / 128, NROWS / 128);
    gemm_mfma<0, 0><<<gf2, b256, 0, stream>>>(FFNb, W2_b, b2 + l * DMOD, Ob, (unsigned short*)0, NROWS, DMOD, DFFN);
    add_ln_kernel<<<NROWS, b256, 0, stream>>>(h, Ob, g2 + l * DMOD, be2 + l * DMOD, h, (unsigned short*)0);
  }

  add_ln_kernel<<<NROWS, b256, 0, stream>>>(h, (const float*)0, gF, bF, h, (unsigned short*)0);
  head_partial<<<512, b256, 0, stream>>>(h, Wh, partial);
  head_reduce<<<NBV * NPRED, b256, 0, stream>>>(partial, bh_, out);
}

// Round 4
// 977.440 us; speedup vs baseline: 5.8158x; 1.8613x over previous
//
#include <hip/hip_runtime.h>
#include <math.h>

#define SEQL 512
#define DMOD 512
#define NHEAD 8
#define DHEAD 64
#define DFFN 2048
#define NBATCH 4
#define NVARS 7
#define NBV 28          // NBATCH*NVARS
#define NBH 224         // NBV*NHEAD
#define NROWS 14336     // NBV*SEQL
#define NSAMP 35        // U_part = u = 35
#define NPRED 96
#define SBIG 7340032    // NBV*SEQL*DMOD floats
#define QKVS 1536       // fused QKV row stride

typedef short bf16x8 __attribute__((ext_vector_type(8)));
typedef float f32x4 __attribute__((ext_vector_type(4)));

__device__ inline unsigned short f2b(float f) {
  unsigned u = __builtin_bit_cast(unsigned, f);
  unsigned r = (u + 0x7FFFu + ((u >> 16) & 1u)) >> 16;
  return (unsigned short)r;
}
__device__ inline float b2f(unsigned short h) {
  return __builtin_bit_cast(float, (unsigned)h << 16);
}

// ---------------- threefry2x32 (matches jax._src.prng) ----------------
__device__ inline void threefry2x32(unsigned k0, unsigned k1,
                                    unsigned x0, unsigned x1,
                                    unsigned &o0, unsigned &o1) {
  unsigned ks2 = k0 ^ k1 ^ 0x1BD11BDAu;
  unsigned ks[3] = {k0, k1, ks2};
  x0 += k0; x1 += k1;
  const unsigned rot[2][4] = {{13u,15u,26u,6u},{17u,29u,16u,24u}};
  #pragma unroll
  for (int i = 0; i < 5; ++i) {
    #pragma unroll
    for (int j = 0; j < 4; ++j) {
      unsigned r = rot[i & 1][j];
      x0 += x1;
      x1 = (x1 << r) | (x1 >> (32u - r));
      x1 ^= x0;
    }
    x0 += ks[(i + 1) % 3];
    x1 += ks[(i + 2) % 3] + (unsigned)(i + 1);
  }
  o0 = x0; o1 = x1;
}

__global__ void make_idx_kernel(int layer, int* idx) {
  int i = blockIdx.x * 256 + threadIdx.x;
  if (i >= SEQL * NSAMP) return;
  unsigned kl0, kl1, o0, o1;
  threefry2x32(0u, 42u, 0u, (unsigned)layer, kl0, kl1);
  threefry2x32(kl0, kl1, (unsigned)i, (unsigned)(SEQL * NSAMP + i), o0, o1);
  idx[i] = (int)(o1 & 511u);
}

// ---------------- embedding ----------------
__global__ void embed_kernel(const float* __restrict__ x_enc,
                             const float* __restrict__ w_emb,
                             const float* __restrict__ b_emb,
                             const float* __restrict__ w_pos,
                             float* __restrict__ h) {
  size_t i = (size_t)blockIdx.x * 256 + threadIdx.x;
  if (i >= (size_t)SBIG) return;
  int dm = (int)(i & 511);
  int l  = (int)((i >> 9) & 511);
  int bv = (int)(i >> 18);
  int b = bv / NVARS, v = bv % NVARS;
  h[i] = x_enc[((size_t)b * SEQL + l) * NVARS + v] * w_emb[dm] + b_emb[dm]
         + w_pos[(size_t)l * DMOD + dm];
}

// ---------------- fp32 -> (bf16 hi, bf16 lo) split ----------------
__global__ void split_hilo(const float* __restrict__ src,
                           unsigned short* __restrict__ hi,
                           unsigned short* __restrict__ lo, int n) {
  int i = (blockIdx.x * 256 + threadIdx.x) * 4;
  if (i >= n) return;
  float4 v = *(const float4*)(src + i);
  ushort4 h4, l4;
  h4.x = f2b(v.x); l4.x = f2b(v.x - b2f(h4.x));
  h4.y = f2b(v.y); l4.y = f2b(v.y - b2f(h4.y));
  h4.z = f2b(v.z); l4.z = f2b(v.z - b2f(h4.z));
  h4.w = f2b(v.w); l4.w = f2b(v.w - b2f(h4.w));
  *(ushort4*)(hi + i) = h4;
  *(ushort4*)(lo + i) = l4;
}

// ---------------- fp32 -> bf16 convert ----------------
__global__ void f2b_kernel(const float* __restrict__ src,
                           unsigned short* __restrict__ dst, int n) {
  int i = (blockIdx.x * 256 + threadIdx.x) * 4;
  if (i >= n) return;
  float4 v = *(const float4*)(src + i);
  ushort4 o;
  o.x = f2b(v.x); o.y = f2b(v.y); o.z = f2b(v.z); o.w = f2b(v.w);
  *(ushort4*)(dst + i) = o;
}

__global__ void bias_cat(const float* __restrict__ bq, const float* __restrict__ bk,
                         const float* __restrict__ bv, float* __restrict__ bc) {
  int i = blockIdx.x * 256 + threadIdx.x;
  if (i >= 1536) return;
  bc[i] = i < 512 ? bq[i] : (i < 1024 ? bk[i - 512] : bv[i - 1024]);
}

// ---------------- split-bf16 MFMA GEMM (3-pass hi/lo): C = A@W^T + bias ----------------
__global__ __launch_bounds__(256) void gemm_mfma3(const unsigned short* __restrict__ Ah,
                                                  const unsigned short* __restrict__ Al,
                                                  const unsigned short* __restrict__ Bh,
                                                  const unsigned short* __restrict__ Bl,
                                                  const float* __restrict__ bias,
                                                  float* __restrict__ C,
                                                  int M, int N, int K, int ldc) {
  __shared__ __align__(16) unsigned short AsH[128 * 64];
  __shared__ __align__(16) unsigned short AsL[128 * 64];
  __shared__ __align__(16) unsigned short BsH[128 * 64];
  __shared__ __align__(16) unsigned short BsL[128 * 64];
  int bm = blockIdx.y * 128, bn = blockIdx.x * 128;
  int tid = threadIdx.x;
  int wave = tid >> 6, lane = tid & 63;
  int wr = wave >> 1, wc = wave & 1;
  int r16 = lane & 15, kq = lane >> 4;

  f32x4 acc[4][4];
  #pragma unroll
  for (int i = 0; i < 4; ++i)
    #pragma unroll
    for (int j = 0; j < 4; ++j) acc[i][j] = (f32x4){0.f, 0.f, 0.f, 0.f};

  for (int kt = 0; kt < K; kt += 64) {
    __syncthreads();
    #pragma unroll
    for (int i = 0; i < 4; ++i) {
      int c = i * 256 + tid;
      int row = c >> 3, kb = c & 7;
      size_t offA = (size_t)(bm + row) * K + kt + kb * 8;
      size_t offB = (size_t)(bn + row) * K + kt + kb * 8;
      uint4 vah = *(const uint4*)(Ah + offA);
      uint4 val = *(const uint4*)(Al + offA);
      uint4 vbh = *(const uint4*)(Bh + offB);
      uint4 vbl = *(const uint4*)(Bl + offB);
      int sw = ((row << 7) | (kb << 4)) ^ ((row & 7) << 4);
      *(uint4*)((char*)AsH + sw) = vah;
      *(uint4*)((char*)AsL + sw) = val;
      *(uint4*)((char*)BsH + sw) = vbh;
      *(uint4*)((char*)BsL + sw) = vbl;
    }
    __syncthreads();
    #pragma unroll
    for (int ks = 0; ks < 2; ++ks) {
      bf16x8 ah[4], al[4], bh[4], bl[4];
      #pragma unroll
      for (int mi = 0; mi < 4; ++mi) {
        int row = wr * 64 + mi * 16 + r16;
        int addr = ((row << 7) | (ks << 6) | (kq << 4)) ^ ((row & 7) << 4);
        ah[mi] = *(const bf16x8*)((const char*)AsH + addr);
        al[mi] = *(const bf16x8*)((const char*)AsL + addr);
      }
      #pragma unroll
      for (int ni = 0; ni < 4; ++ni) {
        int row = wc * 64 + ni * 16 + r16;
        int addr = ((row << 7) | (ks << 6) | (kq << 4)) ^ ((row & 7) << 4);
        bh[ni] = *(const bf16x8*)((const char*)BsH + addr);
        bl[ni] = *(const bf16x8*)((const char*)BsL + addr);
      }
      #pragma unroll
      for (int mi = 0; mi < 4; ++mi)
        #pragma unroll
        for (int ni = 0; ni < 4; ++ni) {
          acc[mi][ni] = __builtin_amdgcn_mfma_f32_16x16x32_bf16(ah[mi], bh[ni], acc[mi][ni], 0, 0, 0);
          acc[mi][ni] = __builtin_amdgcn_mfma_f32_16x16x32_bf16(ah[mi], bl[ni], acc[mi][ni], 0, 0, 0);
          acc[mi][ni] = __builtin_amdgcn_mfma_f32_16x16x32_bf16(al[mi], bh[ni], acc[mi][ni], 0, 0, 0);
        }
    }
  }
  int crow0 = bm + wr * 64 + (lane >> 4) * 4;
  int ccol0 = bn + wc * 64 + (lane & 15);
  #pragma unroll
  for (int mi = 0; mi < 4; ++mi) {
    #pragma unroll
    for (int ni = 0; ni < 4; ++ni) {
      int col = ccol0 + ni * 16;
      float bvv = bias[col];
      #pragma unroll
      for (int r = 0; r < 4; ++r) {
        int row = crow0 + mi * 16 + r;
        C[(size_t)row * ldc + col] = acc[mi][ni][r] + bvv;
      }
    }
  }
}

// ---------------- bf16 MFMA GEMM (single): C = A@W^T + bias, opt gelu ----------------
template<int ACT, int OUTBF>
__global__ __launch_bounds__(256) void gemm_mfma(const unsigned short* __restrict__ A,
                                                 const unsigned short* __restrict__ W,
                                                 const float* __restrict__ bias,
                                                 float* __restrict__ Cf,
                                                 unsigned short* __restrict__ Cb,
                                                 int M, int N, int K) {
  __shared__ __align__(16) unsigned short As[128 * 64];
  __shared__ __align__(16) unsigned short Bs[128 * 64];
  int bm = blockIdx.y * 128, bn = blockIdx.x * 128;
  int tid = threadIdx.x;
  int wave = tid >> 6, lane = tid & 63;
  int wr = wave >> 1, wc = wave & 1;
  int r16 = lane & 15, kq = lane >> 4;

  f32x4 acc[4][4];
  #pragma unroll
  for (int i = 0; i < 4; ++i)
    #pragma unroll
    for (int j = 0; j < 4; ++j) acc[i][j] = (f32x4){0.f, 0.f, 0.f, 0.f};

  for (int kt = 0; kt < K; kt += 64) {
    __syncthreads();
    #pragma unroll
    for (int i = 0; i < 4; ++i) {
      int c = i * 256 + tid;
      int row = c >> 3, kb = c & 7;
      uint4 va = *(const uint4*)(A + (size_t)(bm + row) * K + kt + kb * 8);
      uint4 vb = *(const uint4*)(W + (size_t)(bn + row) * K + kt + kb * 8);
      int sw = ((row << 7) | (kb << 4)) ^ ((row & 7) << 4);
      *(uint4*)((char*)As + sw) = va;
      *(uint4*)((char*)Bs + sw) = vb;
    }
    __syncthreads();
    #pragma unroll
    for (int ks = 0; ks < 2; ++ks) {
      bf16x8 afr[4], bfr[4];
      #pragma unroll
      for (int mi = 0; mi < 4; ++mi) {
        int row = wr * 64 + mi * 16 + r16;
        int addr = ((row << 7) | (ks << 6) | (kq << 4)) ^ ((row & 7) << 4);
        afr[mi] = *(const bf16x8*)((const char*)As + addr);
      }
      #pragma unroll
      for (int ni = 0; ni < 4; ++ni) {
        int row = wc * 64 + ni * 16 + r16;
        int addr = ((row << 7) | (ks << 6) | (kq << 4)) ^ ((row & 7) << 4);
        bfr[ni] = *(const bf16x8*)((const char*)Bs + addr);
      }
      #pragma unroll
      for (int mi = 0; mi < 4; ++mi)
        #pragma unroll
        for (int ni = 0; ni < 4; ++ni)
          acc[mi][ni] = __builtin_amdgcn_mfma_f32_16x16x32_bf16(afr[mi], bfr[ni], acc[mi][ni], 0, 0, 0);
    }
  }
  int crow0 = bm + wr * 64 + (lane >> 4) * 4;
  int ccol0 = bn + wc * 64 + (lane & 15);
  #pragma unroll
  for (int mi = 0; mi < 4; ++mi) {
    #pragma unroll
    for (int ni = 0; ni < 4; ++ni) {
      int col = ccol0 + ni * 16;
      float bvv = bias[col];
      #pragma unroll
      for (int r = 0; r < 4; ++r) {
        int row = crow0 + mi * 16 + r;
        float v = acc[mi][ni][r] + bvv;
        if (ACT) {
          float x = v;
          float t = tanhf(0.7978845608028654f * (x + 0.044715f * x * x * x));
          v = 0.5f * x * (1.0f + t);
        }
        if (OUTBF) Cb[(size_t)row * N + col] = f2b(v);
        else       Cf[(size_t)row * N + col] = v;
      }
    }
  }
}

// ---------------- M measure: block per (bh), K staged in LDS ----------------
__global__ __launch_bounds__(512) void m2_kernel(const float* __restrict__ QKV,
                                                 const int* __restrict__ idx,
                                                 float* __restrict__ Mout) {
  int bh = blockIdx.x;
  int bv = bh >> 3, head = bh & 7;
  int tid = threadIdx.x;                 // 0..511, one q-row each
  __shared__ float Ks[512 * 65];         // stride 65: bank=(kidx+d)%32
  const float* base = QKV + (size_t)bv * (SEQL * QKVS);
  for (int c = tid; c < 512 * 64; c += 512) {
    int l = c >> 6, d = c & 63;
    Ks[l * 65 + d] = base[(size_t)l * QKVS + 512 + head * 64 + d];
  }
  float q[64];
  const float* qp = base + (size_t)tid * QKVS + head * 64;
  #pragma unroll
  for (int d = 0; d < 64; ++d) q[d] = qp[d];
  __syncthreads();
  const int* ip = idx + tid * NSAMP;
  float mx = -INFINITY, sm = 0.f;
  for (int u = 0; u < NSAMP; ++u) {
    int kidx = ip[u];
    const float* kr = Ks + kidx * 65;
    float s = 0.f;
    #pragma unroll
    for (int d = 0; d < 64; ++d) s += q[d] * kr[d];
    mx = fmaxf(mx, s);
    sm += s;
  }
  Mout[(size_t)bh * SEQL + tid] = mx - sm * (1.0f / 512.0f);
}

// ---------------- top-k (k=35) ----------------
__global__ __launch_bounds__(256) void topk_kernel(const float* __restrict__ Mv,
                                                   int* __restrict__ top) {
  int bh = blockIdx.x;
  int tid = threadIdx.x;
  __shared__ float vals[512];
  __shared__ float rv[256];
  __shared__ int ri[256];
  vals[tid]       = Mv[(size_t)bh * SEQL + tid];
  vals[tid + 256] = Mv[(size_t)bh * SEQL + tid + 256];
  __syncthreads();
  for (int t = 0; t < NSAMP; ++t) {
    float v0 = vals[tid], v1 = vals[tid + 256];
    float bvv; int bii;
    if (v0 >= v1) { bvv = v0; bii = tid; } else { bvv = v1; bii = tid + 256; }
    rv[tid] = bvv; ri[tid] = bii;
    __syncthreads();
    for (int s = 128; s > 0; s >>= 1) {
      if (tid < s) {
        float ov = rv[tid + s]; int oi = ri[tid + s];
        if (ov > rv[tid] || (ov == rv[tid] && oi < ri[tid])) { rv[tid] = ov; ri[tid] = oi; }
      }
      __syncthreads();
    }
    if (tid == 0) { top[bh * NSAMP + t] = ri[0]; vals[ri[0]] = -INFINITY; }
    __syncthreads();
  }
}

// ---------------- mean of V ----------------
__global__ __launch_bounds__(64) void vmean_kernel(const float* __restrict__ QKV,
                                                   float* __restrict__ vmean) {
  int bh = blockIdx.x;
  int bv = bh >> 3, head = bh & 7;
  int d = threadIdx.x;
  const float* vb = QKV + (size_t)bv * (SEQL * QKVS) + 1024 + head * 64 + d;
  float s = 0.f;
  for (int l = 0; l < SEQL; ++l) s += vb[(size_t)l * QKVS];
  vmean[bh * DHEAD + d] = s * (1.0f / 512.0f);
}

// ---------------- ctx = broadcast vmean (bf16 out) ----------------
__global__ void ctx_fill_kernel(const float* __restrict__ vmean,
                                unsigned short* __restrict__ ctxb) {
  size_t i = (size_t)blockIdx.x * 256 + threadIdx.x;
  if (i >= (size_t)SBIG) return;
  int dm = (int)(i & 511);
  int bv = (int)(i >> 18);
  ctxb[i] = f2b(vmean[bv * DMOD + dm]);
}

// ---------------- MFMA attention for selected queries: block per (bh) ----------------
// LDS: KV (K then V^T, 64KB) + P (48x512 bf16, 48KB) + Qs (48x64 bf16, 6KB)
__global__ __launch_bounds__(256) void attn2_kernel(const float* __restrict__ QKV,
                                                    const int* __restrict__ top,
                                                    unsigned short* __restrict__ ctxb) {
  __shared__ __align__(16) unsigned short KV[512 * 64];
  __shared__ __align__(16) unsigned short P[48 * 512];
  __shared__ __align__(16) unsigned short Qs[48 * 64];
  __shared__ int topi[NSAMP];
  int bh = blockIdx.x;
  int bv = bh >> 3, head = bh & 7;
  int tid = threadIdx.x;
  int wv = tid >> 6, lane = tid & 63;
  int r16 = lane & 15, kq = lane >> 4;
  const float* base = QKV + (size_t)bv * (SEQL * QKVS);

  if (tid < NSAMP) topi[tid] = top[bh * NSAMP + tid];
  __syncthreads();

  // stage Q_sel (scale folded) as bf16, row stride 128B, XOR swizzle
  for (int c = tid; c < NSAMP * 16; c += 256) {
    int u = c >> 4, dq = c & 15;
    float4 q4 = *(const float4*)(base + (size_t)topi[u] * QKVS + head * 64 + dq * 4);
    ushort4 o;
    o.x = f2b(q4.x * 0.125f); o.y = f2b(q4.y * 0.125f);
    o.z = f2b(q4.z * 0.125f); o.w = f2b(q4.w * 0.125f);
    int byte = ((u << 7) | (dq << 3)) ^ ((u & 7) << 4);
    *(ushort4*)((char*)Qs + byte) = o;
  }
  // stage K (512x64) bf16 swizzled
  for (int c = tid; c < 512 * 16; c += 256) {
    int l = c >> 4, dq = c & 15;
    float4 k4 = *(const float4*)(base + (size_t)l * QKVS + 512 + head * 64 + dq * 4);
    ushort4 o;
    o.x = f2b(k4.x); o.y = f2b(k4.y); o.z = f2b(k4.z); o.w = f2b(k4.w);
    int byte = ((l << 7) | (dq << 3)) ^ ((l & 7) << 4);
    *(ushort4*)((char*)KV + byte) = o;
  }
  __syncthreads();

  // QK^T: scores[48][512]; wave wv owns n-tiles wv*8..wv*8+7
  {
    f32x4 acc[3][8];
    #pragma unroll
    for (int m = 0; m < 3; ++m)
      #pragma unroll
      for (int j = 0; j < 8; ++j) acc[m][j] = (f32x4){0.f, 0.f, 0.f, 0.f};
    bf16x8 afr[3][2];
    #pragma unroll
    for (int m = 0; m < 3; ++m)
      #pragma unroll
      for (int ks = 0; ks < 2; ++ks) {
        int row = m * 16 + r16;
        int addr = ((row << 7) | (ks << 6) | (kq << 4)) ^ ((row & 7) << 4);
        afr[m][ks] = *(const bf16x8*)((const char*)Qs + addr);
      }
    #pragma unroll
    for (int j = 0; j < 8; ++j) {
      int nrow = (wv * 8 + j) * 16 + r16;
      #pragma unroll
      for (int ks = 0; ks < 2; ++ks) {
        int addr = ((nrow << 7) | (ks << 6) | (kq << 4)) ^ ((nrow & 7) << 4);
        bf16x8 bfr = *(const bf16x8*)((const char*)KV + addr);
        #pragma unroll
        for (int m = 0; m < 3; ++m)
          acc[m][j] = __builtin_amdgcn_mfma_f32_16x16x32_bf16(afr[m][ks], bfr, acc[m][j], 0, 0, 0);
      }
    }
    // write scores to P (bf16, swizzled rows of 1024B)
    #pragma unroll
    for (int m = 0; m < 3; ++m)
      #pragma unroll
      for (int j = 0; j < 8; ++j) {
        int l = (wv * 8 + j) * 16 + r16;
        #pragma unroll
        for (int r = 0; r < 4; ++r) {
          int u = m * 16 + kq * 4 + r;
          int byte = ((u << 10) | (l << 1)) ^ ((u & 7) << 4);
          *(unsigned short*)((char*)P + byte) = f2b(acc[m][j][r]);
        }
      }
  }
  __syncthreads();

  // stage V^T (64 rows of 512) into KV region (K is dead)
  for (int c = tid; c < 512 * 16; c += 256) {
    int l = c >> 4, dq = c & 15;
    float4 v4 = *(const float4*)(base + (size_t)l * QKVS + 1024 + head * 64 + dq * 4);
    float vv[4] = {v4.x, v4.y, v4.z, v4.w};
    #pragma unroll
    for (int j = 0; j < 4; ++j) {
      int d = dq * 4 + j;
      int byte = ((d << 10) | (l << 1)) ^ ((d & 7) << 4);
      *(unsigned short*)((char*)KV + byte) = f2b(vv[j]);
    }
  }
  // softmax on P rows (wave-parallel, one b128 per lane per row)
  for (int u = wv; u < NSAMP; u += 4) {
    int byte = ((u << 10) | (lane << 4)) ^ ((u & 7) << 4);
    bf16x8 sv = *(const bf16x8*)((const char*)P + byte);
    float s[8];
    #pragma unroll
    for (int j = 0; j < 8; ++j) s[j] = b2f((unsigned short)sv[j]);
    float mx = s[0];
    #pragma unroll
    for (int j = 1; j < 8; ++j) mx = fmaxf(mx, s[j]);
    #pragma unroll
    for (int off = 32; off > 0; off >>= 1) mx = fmaxf(mx, __shfl_xor(mx, off));
    float e[8], sm = 0.f;
    #pragma unroll
    for (int j = 0; j < 8; ++j) { e[j] = __expf(s[j] - mx); sm += e[j]; }
    #pragma unroll
    for (int off = 32; off > 0; off >>= 1) sm += __shfl_xor(sm, off);
    float inv = 1.0f / sm;
    bf16x8 pv;
    #pragma unroll
    for (int j = 0; j < 8; ++j) pv[j] = (short)f2b(e[j] * inv);
    *(bf16x8*)((char*)P + byte) = pv;
  }
  __syncthreads();

  // PV: ctx[48][64] = P[48][512] @ V[512][64]; wave wv owns n-tile wv (d block)
  {
    f32x4 acc2[3];
    #pragma unroll
    for (int m = 0; m < 3; ++m) acc2[m] = (f32x4){0.f, 0.f, 0.f, 0.f};
    for (int kst = 0; kst < 16; ++kst) {
      int vrow = wv * 16 + r16;
      int baddr = ((vrow << 10) | (kst << 6) | (kq << 4)) ^ ((vrow & 7) << 4);
      bf16x8 bfr = *(const bf16x8*)((const char*)KV + baddr);
      #pragma unroll
      for (int m = 0; m < 3; ++m) {
        int prow = m * 16 + r16;
        int aaddr = ((prow << 10) | (kst << 6) | (kq << 4)) ^ ((prow & 7) << 4);
        bf16x8 afr2 = *(const bf16x8*)((const char*)P + aaddr);
        acc2[m] = __builtin_amdgcn_mfma_f32_16x16x32_bf16(afr2, bfr, acc2[m], 0, 0, 0);
      }
    }
    int d = wv * 16 + r16;
    #pragma unroll
    for (int m = 0; m < 3; ++m)
      #pragma unroll
      for (int r = 0; r < 4; ++r) {
        int u = m * 16 + kq * 4 + r;
        if (u < NSAMP) {
          size_t off = (size_t)bv * (SEQL * DMOD) + (size_t)topi[u] * DMOD + head * 64 + d;
          ctxb[off] = f2b(acc2[m][r]);
        }
      }
  }
}

// ---------------- residual add + layernorm (+ optional bf16 mirror) ----------------
__global__ __launch_bounds__(256) void add_ln_kernel(const float* __restrict__ a,
                                                     const float* __restrict__ b,
                                                     const float* __restrict__ g,
                                                     const float* __restrict__ be,
                                                     float* __restrict__ out,
                                                     unsigned short* __restrict__ outb) {
  int r = blockIdx.x;
  int tid = threadIdx.x;
  __shared__ float red[256];
  size_t base = (size_t)r * DMOD;
  float x0 = a[base + tid];
  float x1 = a[base + tid + 256];
  if (b) { x0 += b[base + tid]; x1 += b[base + tid + 256]; }
  red[tid] = x0 + x1;
  __syncthreads();
  for (int s = 128; s > 0; s >>= 1) {
    if (tid < s) red[tid] += red[tid + s];
    __syncthreads();
  }
  float mu = red[0] * (1.0f / 512.0f);
  __syncthreads();
  float d0 = x0 - mu, d1 = x1 - mu;
  red[tid] = d0 * d0 + d1 * d1;
  __syncthreads();
  for (int s = 128; s > 0; s >>= 1) {
    if (tid < s) red[tid] += red[tid + s];
    __syncthreads();
  }
  float rstd = rsqrtf(red[0] * (1.0f / 512.0f) + 1e-5f);
  float o0 = d0 * rstd * g[tid] + be[tid];
  float o1 = d1 * rstd * g[tid + 256] + be[tid + 256];
  out[base + tid]       = o0;
  out[base + tid + 256] = o1;
  if (outb) {
    outb[base + tid]       = f2b(o0);
    outb[base + tid + 256] = f2b(o1);
  }
}

// ---------------- head: split-K partials ----------------
__global__ __launch_bounds__(256) void head_partial(const float* __restrict__ h,
                                                    const float* __restrict__ Wh,
                                                    float* __restrict__ partial) {
  __shared__ float hs[28 * 132];
  __shared__ float wsm[96 * 132];
  int blk = blockIdx.x;
  int tid = threadIdx.x;
  int tx = tid & 31, ty = tid >> 5;
  float acc[4][3];
  #pragma unroll
  for (int i = 0; i < 4; ++i)
    #pragma unroll
    for (int j = 0; j < 3; ++j) acc[i][j] = 0.f;
  for (int s = 0; s < 4; ++s) {
    int k0 = (blk * 4 + s) * 128;
    __syncthreads();
    for (int c = tid; c < 28 * 32; c += 256) {
      int m = c >> 5, q = c & 31;
      float4 v = *(const float4*)(h + (size_t)m * (SEQL * DMOD) + k0 + q * 4);
      *(float4*)(hs + m * 132 + q * 4) = v;
    }
    for (int c = tid; c < 96 * 32; c += 256) {
      int n = c >> 5, q = c & 31;
      float4 v = *(const float4*)(Wh + (size_t)n * (SEQL * DMOD) + k0 + q * 4);
      *(float4*)(wsm + n * 132 + q * 4) = v;
    }
    __syncthreads();
    for (int k = 0; k < 128; k += 4) {
      float4 hv[4], wv[3];
      #pragma unroll
      for (int i = 0; i < 4; ++i) hv[i] = *(const float4*)(hs + (ty * 4 + i) * 132 + k);
      #pragma unroll
      for (int j = 0; j < 3; ++j) wv[j] = *(const float4*)(wsm + (tx + j * 32) * 132 + k);
      #pragma unroll
      for (int i = 0; i < 4; ++i)
        #pragma unroll
        for (int j = 0; j < 3; ++j)
          acc[i][j] += hv[i].x * wv[j].x + hv[i].y * wv[j].y
                     + hv[i].z * wv[j].z + hv[i].w * wv[j].w;
    }
  }
  #pragma unroll
  for (int i = 0; i < 4; ++i) {
    int m = ty * 4 + i;
    if (m < 28) {
      #pragma unroll
      for (int j = 0; j < 3; ++j) {
        int n = tx + j * 32;
        partial[(size_t)(m * 96 + n) * 512 + blk] = acc[i][j];
      }
    }
  }
}

__global__ __launch_bounds__(256) void head_reduce(const float* __restrict__ partial,
                                                   const float* __restrict__ bh_,
                                                   float* __restrict__ out) {
  int o = blockIdx.x;
  int tid = threadIdx.x;
  float s = partial[(size_t)o * 512 + tid] + partial[(size_t)o * 512 + tid + 256];
  __shared__ float red[256];
  red[tid] = s;
  __syncthreads();
  for (int st = 128; st > 0; st >>= 1) {
    if (tid < st) red[tid] += red[tid + st];
    __syncthreads();
  }
  if (tid == 0) {
    int m = o / 96, p = o % 96;
    int b = m / NVARS, v = m % NVARS;
    out[(size_t)b * (NPRED * NVARS) + (size_t)p * NVARS + v] = red[0] + bh_[p];
  }
}

extern "C" void kernel_launch(void* const* d_in, const int* in_sizes, int n_in,
                              void* d_out, int out_size, void* d_ws, size_t ws_size,
                              hipStream_t stream) {
  const float* x_enc = (const float*)d_in[0];
  const float* w_emb = (const float*)d_in[1];
  const float* b_emb = (const float*)d_in[2];
  const float* w_pos = (const float*)d_in[3];
  const float* Wq = (const float*)d_in[4];
  const float* bq = (const float*)d_in[5];
  const float* Wk = (const float*)d_in[6];
  const float* bk = (const float*)d_in[7];
  const float* Wv = (const float*)d_in[8];
  const float* bv_ = (const float*)d_in[9];
  const float* Wo = (const float*)d_in[10];
  const float* bo = (const float*)d_in[11];
  const float* W1 = (const float*)d_in[12];
  const float* b1 = (const float*)d_in[13];
  const float* W2 = (const float*)d_in[14];
  const float* b2 = (const float*)d_in[15];
  const float* g1 = (const float*)d_in[16];
  const float* be1 = (const float*)d_in[17];
  const float* g2 = (const float*)d_in[18];
  const float* be2 = (const float*)d_in[19];
  const float* gF = (const float*)d_in[20];
  const float* bF = (const float*)d_in[21];
  const float* Wh = (const float*)d_in[22];
  const float* bh_ = (const float*)d_in[23];
  float* out = (float*)d_out;

  const size_t S = (size_t)SBIG;
  const size_t SB = S * 4;                    // 29,360,128 B
  char* ws = (char*)d_ws;
  float* h    = (float*)(ws);                 // [0, SB)
  float* QKV  = (float*)(ws + SB);            // [SB, 4SB): [14336][1536] fp32
  float* Ob   = (float*)(ws + 4 * SB);        // [4SB, 5SB)
  unsigned short* h_hi = (unsigned short*)(ws + 5 * SB);           // SB/2
  unsigned short* h_lo = (unsigned short*)(ws + 5 * SB + SB / 2);  // SB/2
  // phase aliases:
  unsigned short* CTXb = h_hi;                            // after QKV gemm done
  unsigned short* h_bf = h_lo;                            // after ln1
  unsigned short* FFNb = (unsigned short*)QKV;            // 2SB, after attn
  float* partial = QKV;                                   // head phase
  unsigned short* Wo_b = (unsigned short*)((char*)QKV + 2 * SB);            // 0.5MB
  unsigned short* W1_b = (unsigned short*)((char*)QKV + 2 * SB + (1 << 20)); // 2MB
  unsigned short* W2_b = (unsigned short*)((char*)QKV + 2 * SB + (4 << 20)); // 2MB
  unsigned short* Wqkv_hi = (unsigned short*)Ob;                       // 1.5MB
  unsigned short* Wqkv_lo = (unsigned short*)((char*)Ob + 0x180000);   // 1.5MB
  int*   idx = (int*)(ws + 6 * SB);                        // 70KB
  float* Mv  = (float*)(ws + 6 * SB + 0x20000);            // 448KB
  int*   top = (int*)(ws + 6 * SB + 0xA0000);              // 31KB
  float* vmean = (float*)(ws + 6 * SB + 0xB0000);          // 56KB
  float* bias_c = (float*)(ws + 6 * SB + 0xB0000 + 0xE800); // 6KB
  if (ws_size < 6 * SB + 0xC0000) return;

  dim3 b256(256);
  int gBig = (int)((S + 255) / 256);

  embed_kernel<<<gBig, b256, 0, stream>>>(x_enc, w_emb, b_emb, w_pos, h);

  for (int l = 0; l < 2; ++l) {
    const float* Wql = Wq + (size_t)l * DMOD * DMOD;
    const float* Wkl = Wk + (size_t)l * DMOD * DMOD;
    const float* Wvl = Wv + (size_t)l * DMOD * DMOD;
    const float* Wol = Wo + (size_t)l * DMOD * DMOD;
    const float* W1l = W1 + (size_t)l * DFFN * DMOD;
    const float* W2l = W2 + (size_t)l * DMOD * DFFN;

    // hi/lo splits for exact-enough QKV
    split_hilo<<<(int)(S / 4 + 255) / 256, b256, 0, stream>>>(h, h_hi, h_lo, (int)S);
    split_hilo<<<(DMOD * DMOD / 4 + 255) / 256, b256, 0, stream>>>(Wql, Wqkv_hi, Wqkv_lo, DMOD * DMOD);
    split_hilo<<<(DMOD * DMOD / 4 + 255) / 256, b256, 0, stream>>>(Wkl, Wqkv_hi + DMOD * DMOD, Wqkv_lo + DMOD * DMOD, DMOD * DMOD);
    split_hilo<<<(DMOD * DMOD / 4 + 255) / 256, b256, 0, stream>>>(Wvl, Wqkv_hi + 2 * DMOD * DMOD, Wqkv_lo + 2 * DMOD * DMOD, DMOD * DMOD);
    bias_cat<<<6, b256, 0, stream>>>(bq + l * DMOD, bk + l * DMOD, bv_ + l * DMOD, bias_c);

    // fused QKV projection, fp32-accurate via 3-pass hi/lo MFMA
    dim3 gqkv(QKVS / 128, NROWS / 128);
    gemm_mfma3<<<gqkv, b256, 0, stream>>>(h_hi, h_lo, Wqkv_hi, Wqkv_lo, bias_c,
                                          QKV, NROWS, QKVS, DMOD, QKVS);

    make_idx_kernel<<<(SEQL * NSAMP + 255) / 256, b256, 0, stream>>>(l, idx);
    m2_kernel<<<NBH, dim3(512), 0, stream>>>(QKV, idx, Mv);
    topk_kernel<<<NBH, b256, 0, stream>>>(Mv, top);
    vmean_kernel<<<NBH, dim3(64), 0, stream>>>(QKV, vmean);
    ctx_fill_kernel<<<gBig, b256, 0, stream>>>(vmean, CTXb);
    attn2_kernel<<<NBH, b256, 0, stream>>>(QKV, top, CTXb);

    // weight bf16 conversions into dead QKV tail
    f2b_kernel<<<(DMOD * DMOD / 4 + 255) / 256, b256, 0, stream>>>(Wol, Wo_b, DMOD * DMOD);
    f2b_kernel<<<(DFFN * DMOD / 4 + 255) / 256, b256, 0, stream>>>(W1l, W1_b, DFFN * DMOD);
    f2b_kernel<<<(DMOD * DFFN / 4 + 255) / 256, b256, 0, stream>>>(W2l, W2_b, DMOD * DFFN);

    dim3 go(DMOD / 128, NROWS / 128);
    gemm_mfma<0, 0><<<go, b256, 0, stream>>>(CTXb, Wo_b, bo + l * DMOD, Ob, (unsigned short*)0, NROWS, DMOD, DMOD);
    add_ln_kernel<<<NROWS, b256, 0, stream>>>(h, Ob, g1 + l * DMOD, be1 + l * DMOD, h, h_bf);

    dim3 gf1(DFFN / 128, NROWS / 128);
    gemm_mfma<1, 1><<<gf1, b256, 0, stream>>>(h_bf, W1_b, b1 + l * DFFN, (float*)0, FFNb, NROWS, DFFN, DMOD);
    dim3 gf2(DMOD / 128, NROWS / 128);
    gemm_mfma<0, 0><<<gf2, b256, 0, stream>>>(FFNb, W2_b, b2 + l * DMOD, Ob, (unsigned short*)0, NROWS, DMOD, DFFN);
    add_ln_kernel<<<NROWS, b256, 0, stream>>>(h, Ob, g2 + l * DMOD, be2 + l * DMOD, h, (unsigned short*)0);
  }

  add_ln_kernel<<<NROWS, b256, 0, stream>>>(h, (const float*)0, gF, bF, h, (unsigned short*)0);
  head_partial<<<512, b256, 0, stream>>>(h, Wh, partial);
  head_reduce<<<NBV * NPRED, b256, 0, stream>>>(partial, bh_, out);
}

// Round 5
// 888.614 us; speedup vs baseline: 6.3972x; 1.1000x over previous
//
#include <hip/hip_runtime.h>
#include <math.h>

#define SEQL 512
#define DMOD 512
#define NHEAD 8
#define DHEAD 64
#define DFFN 2048
#define NBATCH 4
#define NVARS 7
#define NBV 28          // NBATCH*NVARS
#define NBH 224         // NBV*NHEAD
#define NROWS 14336     // NBV*SEQL
#define NSAMP 35        // U_part = u = 35
#define NPRED 96
#define SBIG 7340032    // NBV*SEQL*DMOD floats
#define QKS 1024        // fused QK row stride

typedef short bf16x8 __attribute__((ext_vector_type(8)));
typedef float f32x4 __attribute__((ext_vector_type(4)));

__device__ inline unsigned short f2b(float f) {
  unsigned u = __builtin_bit_cast(unsigned, f);
  unsigned r = (u + 0x7FFFu + ((u >> 16) & 1u)) >> 16;
  return (unsigned short)r;
}
__device__ inline float b2f(unsigned short h) {
  return __builtin_bit_cast(float, (unsigned)h << 16);
}

// ---------------- threefry2x32 (matches jax._src.prng) ----------------
__device__ inline void threefry2x32(unsigned k0, unsigned k1,
                                    unsigned x0, unsigned x1,
                                    unsigned &o0, unsigned &o1) {
  unsigned ks2 = k0 ^ k1 ^ 0x1BD11BDAu;
  unsigned ks[3] = {k0, k1, ks2};
  x0 += k0; x1 += k1;
  const unsigned rot[2][4] = {{13u,15u,26u,6u},{17u,29u,16u,24u}};
  #pragma unroll
  for (int i = 0; i < 5; ++i) {
    #pragma unroll
    for (int j = 0; j < 4; ++j) {
      unsigned r = rot[i & 1][j];
      x0 += x1;
      x1 = (x1 << r) | (x1 >> (32u - r));
      x1 ^= x0;
    }
    x0 += ks[(i + 1) % 3];
    x1 += ks[(i + 2) % 3] + (unsigned)(i + 1);
  }
  o0 = x0; o1 = x1;
}

__global__ void make_idx_kernel(int layer, int* idx) {
  int i = blockIdx.x * 256 + threadIdx.x;
  if (i >= SEQL * NSAMP) return;
  unsigned kl0, kl1, o0, o1;
  threefry2x32(0u, 42u, 0u, (unsigned)layer, kl0, kl1);
  threefry2x32(kl0, kl1, (unsigned)i, (unsigned)(SEQL * NSAMP + i), o0, o1);
  idx[i] = (int)(o1 & 511u);
}

// ---------------- embedding (fused hi/lo split) ----------------
__global__ void embed_kernel(const float* __restrict__ x_enc,
                             const float* __restrict__ w_emb,
                             const float* __restrict__ b_emb,
                             const float* __restrict__ w_pos,
                             float* __restrict__ h,
                             unsigned short* __restrict__ h_hi,
                             unsigned short* __restrict__ h_lo) {
  size_t i = (size_t)blockIdx.x * 256 + threadIdx.x;
  if (i >= (size_t)SBIG) return;
  int dm = (int)(i & 511);
  int l  = (int)((i >> 9) & 511);
  int bv = (int)(i >> 18);
  int b = bv / NVARS, v = bv % NVARS;
  float val = x_enc[((size_t)b * SEQL + l) * NVARS + v] * w_emb[dm] + b_emb[dm]
              + w_pos[(size_t)l * DMOD + dm];
  h[i] = val;
  unsigned short hi = f2b(val);
  h_hi[i] = hi;
  h_lo[i] = f2b(val - b2f(hi));
}

// ---------------- fp32 -> (bf16 hi, bf16 lo) split (weights) ----------------
__global__ void split_hilo(const float* __restrict__ src,
                           unsigned short* __restrict__ hi,
                           unsigned short* __restrict__ lo, int n) {
  int i = (blockIdx.x * 256 + threadIdx.x) * 4;
  if (i >= n) return;
  float4 v = *(const float4*)(src + i);
  ushort4 h4, l4;
  h4.x = f2b(v.x); l4.x = f2b(v.x - b2f(h4.x));
  h4.y = f2b(v.y); l4.y = f2b(v.y - b2f(h4.y));
  h4.z = f2b(v.z); l4.z = f2b(v.z - b2f(h4.z));
  h4.w = f2b(v.w); l4.w = f2b(v.w - b2f(h4.w));
  *(ushort4*)(hi + i) = h4;
  *(ushort4*)(lo + i) = l4;
}

// ---------------- fp32 -> bf16 convert ----------------
__global__ void f2b_kernel(const float* __restrict__ src,
                           unsigned short* __restrict__ dst, int n) {
  int i = (blockIdx.x * 256 + threadIdx.x) * 4;
  if (i >= n) return;
  float4 v = *(const float4*)(src + i);
  ushort4 o;
  o.x = f2b(v.x); o.y = f2b(v.y); o.z = f2b(v.z); o.w = f2b(v.w);
  *(ushort4*)(dst + i) = o;
}

__global__ void bias_cat2(const float* __restrict__ bq, const float* __restrict__ bk,
                          float* __restrict__ bc) {
  int i = blockIdx.x * 256 + threadIdx.x;
  if (i >= 1024) return;
  bc[i] = i < 512 ? bq[i] : bk[i - 512];
}

// ---------------- split-bf16 MFMA GEMM (3-pass hi/lo): C = A@W^T + bias ----------------
__global__ __launch_bounds__(256) void gemm_mfma3(const unsigned short* __restrict__ Ah,
                                                  const unsigned short* __restrict__ Al,
                                                  const unsigned short* __restrict__ Bh,
                                                  const unsigned short* __restrict__ Bl,
                                                  const float* __restrict__ bias,
                                                  float* __restrict__ C,
                                                  int M, int N, int K, int ldc) {
  __shared__ __align__(16) unsigned short AsH[128 * 64];
  __shared__ __align__(16) unsigned short AsL[128 * 64];
  __shared__ __align__(16) unsigned short BsH[128 * 64];
  __shared__ __align__(16) unsigned short BsL[128 * 64];
  // bijective XCD swizzle (nwg % 8 == 0 for all our grids)
  int nwg = gridDim.x * gridDim.y;
  int flat = blockIdx.y * gridDim.x + blockIdx.x;
  int swz = (flat & 7) * (nwg >> 3) + (flat >> 3);
  int bxs = swz % gridDim.x, bys = swz / gridDim.x;
  int bm = bys * 128, bn = bxs * 128;
  int tid = threadIdx.x;
  int wave = tid >> 6, lane = tid & 63;
  int wr = wave >> 1, wc = wave & 1;
  int r16 = lane & 15, kq = lane >> 4;

  f32x4 acc[4][4];
  #pragma unroll
  for (int i = 0; i < 4; ++i)
    #pragma unroll
    for (int j = 0; j < 4; ++j) acc[i][j] = (f32x4){0.f, 0.f, 0.f, 0.f};

  for (int kt = 0; kt < K; kt += 64) {
    __syncthreads();
    #pragma unroll
    for (int i = 0; i < 4; ++i) {
      int c = i * 256 + tid;
      int row = c >> 3, kb = c & 7;
      size_t offA = (size_t)(bm + row) * K + kt + kb * 8;
      size_t offB = (size_t)(bn + row) * K + kt + kb * 8;
      uint4 vah = *(const uint4*)(Ah + offA);
      uint4 val = *(const uint4*)(Al + offA);
      uint4 vbh = *(const uint4*)(Bh + offB);
      uint4 vbl = *(const uint4*)(Bl + offB);
      int sw = ((row << 7) | (kb << 4)) ^ ((row & 7) << 4);
      *(uint4*)((char*)AsH + sw) = vah;
      *(uint4*)((char*)AsL + sw) = val;
      *(uint4*)((char*)BsH + sw) = vbh;
      *(uint4*)((char*)BsL + sw) = vbl;
    }
    __syncthreads();
    #pragma unroll
    for (int ks = 0; ks < 2; ++ks) {
      bf16x8 ah[4], al[4], bh[4], bl[4];
      #pragma unroll
      for (int mi = 0; mi < 4; ++mi) {
        int row = wr * 64 + mi * 16 + r16;
        int addr = ((row << 7) | (ks << 6) | (kq << 4)) ^ ((row & 7) << 4);
        ah[mi] = *(const bf16x8*)((const char*)AsH + addr);
        al[mi] = *(const bf16x8*)((const char*)AsL + addr);
      }
      #pragma unroll
      for (int ni = 0; ni < 4; ++ni) {
        int row = wc * 64 + ni * 16 + r16;
        int addr = ((row << 7) | (ks << 6) | (kq << 4)) ^ ((row & 7) << 4);
        bh[ni] = *(const bf16x8*)((const char*)BsH + addr);
        bl[ni] = *(const bf16x8*)((const char*)BsL + addr);
      }
      #pragma unroll
      for (int mi = 0; mi < 4; ++mi)
        #pragma unroll
        for (int ni = 0; ni < 4; ++ni) {
          acc[mi][ni] = __builtin_amdgcn_mfma_f32_16x16x32_bf16(ah[mi], bh[ni], acc[mi][ni], 0, 0, 0);
          acc[mi][ni] = __builtin_amdgcn_mfma_f32_16x16x32_bf16(ah[mi], bl[ni], acc[mi][ni], 0, 0, 0);
          acc[mi][ni] = __builtin_amdgcn_mfma_f32_16x16x32_bf16(al[mi], bh[ni], acc[mi][ni], 0, 0, 0);
        }
    }
  }
  int crow0 = bm + wr * 64 + (lane >> 4) * 4;
  int ccol0 = bn + wc * 64 + (lane & 15);
  #pragma unroll
  for (int mi = 0; mi < 4; ++mi) {
    #pragma unroll
    for (int ni = 0; ni < 4; ++ni) {
      int col = ccol0 + ni * 16;
      float bvv = bias[col];
      #pragma unroll
      for (int r = 0; r < 4; ++r) {
        int row = crow0 + mi * 16 + r;
        C[(size_t)row * ldc + col] = acc[mi][ni][r] + bvv;
      }
    }
  }
}

// ---------------- bf16 MFMA GEMM (single): C = A@W^T + bias, opt gelu ----------------
template<int ACT, int OUTBF>
__global__ __launch_bounds__(256) void gemm_mfma(const unsigned short* __restrict__ A,
                                                 const unsigned short* __restrict__ W,
                                                 const float* __restrict__ bias,
                                                 float* __restrict__ Cf,
                                                 unsigned short* __restrict__ Cb,
                                                 int M, int N, int K) {
  __shared__ __align__(16) unsigned short As[128 * 64];
  __shared__ __align__(16) unsigned short Bs[128 * 64];
  int nwg = gridDim.x * gridDim.y;
  int flat = blockIdx.y * gridDim.x + blockIdx.x;
  int swz = (flat & 7) * (nwg >> 3) + (flat >> 3);
  int bxs = swz % gridDim.x, bys = swz / gridDim.x;
  int bm = bys * 128, bn = bxs * 128;
  int tid = threadIdx.x;
  int wave = tid >> 6, lane = tid & 63;
  int wr = wave >> 1, wc = wave & 1;
  int r16 = lane & 15, kq = lane >> 4;

  f32x4 acc[4][4];
  #pragma unroll
  for (int i = 0; i < 4; ++i)
    #pragma unroll
    for (int j = 0; j < 4; ++j) acc[i][j] = (f32x4){0.f, 0.f, 0.f, 0.f};

  for (int kt = 0; kt < K; kt += 64) {
    __syncthreads();
    #pragma unroll
    for (int i = 0; i < 4; ++i) {
      int c = i * 256 + tid;
      int row = c >> 3, kb = c & 7;
      uint4 va = *(const uint4*)(A + (size_t)(bm + row) * K + kt + kb * 8);
      uint4 vb = *(const uint4*)(W + (size_t)(bn + row) * K + kt + kb * 8);
      int sw = ((row << 7) | (kb << 4)) ^ ((row & 7) << 4);
      *(uint4*)((char*)As + sw) = va;
      *(uint4*)((char*)Bs + sw) = vb;
    }
    __syncthreads();
    #pragma unroll
    for (int ks = 0; ks < 2; ++ks) {
      bf16x8 afr[4], bfr[4];
      #pragma unroll
      for (int mi = 0; mi < 4; ++mi) {
        int row = wr * 64 + mi * 16 + r16;
        int addr = ((row << 7) | (ks << 6) | (kq << 4)) ^ ((row & 7) << 4);
        afr[mi] = *(const bf16x8*)((const char*)As + addr);
      }
      #pragma unroll
      for (int ni = 0; ni < 4; ++ni) {
        int row = wc * 64 + ni * 16 + r16;
        int addr = ((row << 7) | (ks << 6) | (kq << 4)) ^ ((row & 7) << 4);
        bfr[ni] = *(const bf16x8*)((const char*)Bs + addr);
      }
      #pragma unroll
      for (int mi = 0; mi < 4; ++mi)
        #pragma unroll
        for (int ni = 0; ni < 4; ++ni)
          acc[mi][ni] = __builtin_amdgcn_mfma_f32_16x16x32_bf16(afr[mi], bfr[ni], acc[mi][ni], 0, 0, 0);
    }
  }
  int crow0 = bm + wr * 64 + (lane >> 4) * 4;
  int ccol0 = bn + wc * 64 + (lane & 15);
  #pragma unroll
  for (int mi = 0; mi < 4; ++mi) {
    #pragma unroll
    for (int ni = 0; ni < 4; ++ni) {
      int col = ccol0 + ni * 16;
      float bvv = bias[col];
      #pragma unroll
      for (int r = 0; r < 4; ++r) {
        int row = crow0 + mi * 16 + r;
        float v = acc[mi][ni][r] + bvv;
        if (ACT) {
          float x = v;
          float t = tanhf(0.7978845608028654f * (x + 0.044715f * x * x * x));
          v = 0.5f * x * (1.0f + t);
        }
        if (OUTBF) Cb[(size_t)row * N + col] = f2b(v);
        else       Cf[(size_t)row * N + col] = v;
      }
    }
  }
}

// ---------------- M measure: block per (bh), K staged in LDS ----------------
__global__ __launch_bounds__(512) void m2_kernel(const float* __restrict__ QK,
                                                 const int* __restrict__ idx,
                                                 float* __restrict__ Mout) {
  int bh = blockIdx.x;
  int bv = bh >> 3, head = bh & 7;
  int tid = threadIdx.x;                 // 0..511, one q-row each
  __shared__ float Ks[512 * 65];
  const float* base = QK + (size_t)bv * (SEQL * QKS);
  for (int c = tid; c < 512 * 64; c += 512) {
    int l = c >> 6, d = c & 63;
    Ks[l * 65 + d] = base[(size_t)l * QKS + 512 + head * 64 + d];
  }
  float q[64];
  const float* qp = base + (size_t)tid * QKS + head * 64;
  #pragma unroll
  for (int d = 0; d < 64; ++d) q[d] = qp[d];
  __syncthreads();
  const int* ip = idx + tid * NSAMP;
  float mx = -INFINITY, sm = 0.f;
  for (int u = 0; u < NSAMP; ++u) {
    int kidx = ip[u];
    const float* kr = Ks + kidx * 65;
    float s = 0.f;
    #pragma unroll
    for (int d = 0; d < 64; ++d) s += q[d] * kr[d];
    mx = fmaxf(mx, s);
    sm += s;
  }
  Mout[(size_t)bh * SEQL + tid] = mx - sm * (1.0f / 512.0f);
}

// ---------------- top-k (k=35) ----------------
__global__ __launch_bounds__(256) void topk_kernel(const float* __restrict__ Mv,
                                                   int* __restrict__ top) {
  int bh = blockIdx.x;
  int tid = threadIdx.x;
  __shared__ float vals[512];
  __shared__ float rv[256];
  __shared__ int ri[256];
  vals[tid]       = Mv[(size_t)bh * SEQL + tid];
  vals[tid + 256] = Mv[(size_t)bh * SEQL + tid + 256];
  __syncthreads();
  for (int t = 0; t < NSAMP; ++t) {
    float v0 = vals[tid], v1 = vals[tid + 256];
    float bvv; int bii;
    if (v0 >= v1) { bvv = v0; bii = tid; } else { bvv = v1; bii = tid + 256; }
    rv[tid] = bvv; ri[tid] = bii;
    __syncthreads();
    for (int s = 128; s > 0; s >>= 1) {
      if (tid < s) {
        float ov = rv[tid + s]; int oi = ri[tid + s];
        if (ov > rv[tid] || (ov == rv[tid] && oi < ri[tid])) { rv[tid] = ov; ri[tid] = oi; }
      }
      __syncthreads();
    }
    if (tid == 0) { top[bh * NSAMP + t] = ri[0]; vals[ri[0]] = -INFINITY; }
    __syncthreads();
  }
}

// ---------------- mean of V (bf16 V) ----------------
__global__ __launch_bounds__(64) void vmean_kernel(const unsigned short* __restrict__ Vb,
                                                   float* __restrict__ vmean) {
  int bh = blockIdx.x;
  int bv = bh >> 3, head = bh & 7;
  int d = threadIdx.x;
  const unsigned short* vb = Vb + (size_t)bv * (SEQL * DMOD) + head * 64 + d;
  float s = 0.f;
  for (int l = 0; l < SEQL; ++l) s += b2f(vb[(size_t)l * DMOD]);
  vmean[bh * DHEAD + d] = s * (1.0f / 512.0f);
}

// ---------------- ctx = broadcast vmean (bf16 out) ----------------
__global__ void ctx_fill_kernel(const float* __restrict__ vmean,
                                unsigned short* __restrict__ ctxb) {
  size_t i = (size_t)blockIdx.x * 256 + threadIdx.x;
  if (i >= (size_t)SBIG) return;
  int dm = (int)(i & 511);
  int bv = (int)(i >> 18);
  ctxb[i] = f2b(vmean[bv * DMOD + dm]);
}

// ---------------- MFMA attention for selected queries: block per (bh) ----------------
__global__ __launch_bounds__(256) void attn2_kernel(const float* __restrict__ QK,
                                                    const unsigned short* __restrict__ Vb,
                                                    const int* __restrict__ top,
                                                    unsigned short* __restrict__ ctxb) {
  __shared__ __align__(16) unsigned short KV[512 * 64];
  __shared__ __align__(16) unsigned short P[48 * 512];
  __shared__ __align__(16) unsigned short Qs[48 * 64];
  __shared__ int topi[NSAMP];
  int bh = blockIdx.x;
  int bv = bh >> 3, head = bh & 7;
  int tid = threadIdx.x;
  int wv = tid >> 6, lane = tid & 63;
  int r16 = lane & 15, kq = lane >> 4;
  const float* base = QK + (size_t)bv * (SEQL * QKS);
  const unsigned short* vbase = Vb + (size_t)bv * (SEQL * DMOD) + head * 64;

  if (tid < NSAMP) topi[tid] = top[bh * NSAMP + tid];
  __syncthreads();

  // stage Q_sel (scale folded) as bf16, row stride 128B, XOR swizzle
  for (int c = tid; c < NSAMP * 16; c += 256) {
    int u = c >> 4, dq = c & 15;
    float4 q4 = *(const float4*)(base + (size_t)topi[u] * QKS + head * 64 + dq * 4);
    ushort4 o;
    o.x = f2b(q4.x * 0.125f); o.y = f2b(q4.y * 0.125f);
    o.z = f2b(q4.z * 0.125f); o.w = f2b(q4.w * 0.125f);
    int byte = ((u << 7) | (dq << 3)) ^ ((u & 7) << 4);
    *(ushort4*)((char*)Qs + byte) = o;
  }
  // stage K (512x64) bf16 swizzled
  for (int c = tid; c < 512 * 16; c += 256) {
    int l = c >> 4, dq = c & 15;
    float4 k4 = *(const float4*)(base + (size_t)l * QKS + 512 + head * 64 + dq * 4);
    ushort4 o;
    o.x = f2b(k4.x); o.y = f2b(k4.y); o.z = f2b(k4.z); o.w = f2b(k4.w);
    int byte = ((l << 7) | (dq << 3)) ^ ((l & 7) << 4);
    *(ushort4*)((char*)KV + byte) = o;
  }
  __syncthreads();

  // QK^T: scores[48][512]
  {
    f32x4 acc[3][8];
    #pragma unroll
    for (int m = 0; m < 3; ++m)
      #pragma unroll
      for (int j = 0; j < 8; ++j) acc[m][j] = (f32x4){0.f, 0.f, 0.f, 0.f};
    bf16x8 afr[3][2];
    #pragma unroll
    for (int m = 0; m < 3; ++m)
      #pragma unroll
      for (int ks = 0; ks < 2; ++ks) {
        int row = m * 16 + r16;
        int addr = ((row << 7) | (ks << 6) | (kq << 4)) ^ ((row & 7) << 4);
        afr[m][ks] = *(const bf16x8*)((const char*)Qs + addr);
      }
    #pragma unroll
    for (int j = 0; j < 8; ++j) {
      int nrow = (wv * 8 + j) * 16 + r16;
      #pragma unroll
      for (int ks = 0; ks < 2; ++ks) {
        int addr = ((nrow << 7) | (ks << 6) | (kq << 4)) ^ ((nrow & 7) << 4);
        bf16x8 bfr = *(const bf16x8*)((const char*)KV + addr);
        #pragma unroll
        for (int m = 0; m < 3; ++m)
          acc[m][j] = __builtin_amdgcn_mfma_f32_16x16x32_bf16(afr[m][ks], bfr, acc[m][j], 0, 0, 0);
      }
    }
    #pragma unroll
    for (int m = 0; m < 3; ++m)
      #pragma unroll
      for (int j = 0; j < 8; ++j) {
        int l = (wv * 8 + j) * 16 + r16;
        #pragma unroll
        for (int r = 0; r < 4; ++r) {
          int u = m * 16 + kq * 4 + r;
          int byte = ((u << 10) | (l << 1)) ^ ((u & 7) << 4);
          *(unsigned short*)((char*)P + byte) = f2b(acc[m][j][r]);
        }
      }
  }
  __syncthreads();

  // stage V^T (64 rows of 512) into KV region (K dead) from bf16 V
  for (int c = tid; c < 512 * 8; c += 256) {
    int l = c >> 3, dq = c & 7;
    bf16x8 v8 = *(const bf16x8*)(vbase + (size_t)l * DMOD + dq * 8);
    #pragma unroll
    for (int j = 0; j < 8; ++j) {
      int d = dq * 8 + j;
      int byte = ((d << 10) | (l << 1)) ^ ((d & 7) << 4);
      *(unsigned short*)((char*)KV + byte) = (unsigned short)v8[j];
    }
  }
  // softmax on P rows
  for (int u = wv; u < NSAMP; u += 4) {
    int byte = ((u << 10) | (lane << 4)) ^ ((u & 7) << 4);
    bf16x8 sv = *(const bf16x8*)((const char*)P + byte);
    float s[8];
    #pragma unroll
    for (int j = 0; j < 8; ++j) s[j] = b2f((unsigned short)sv[j]);
    float mx = s[0];
    #pragma unroll
    for (int j = 1; j < 8; ++j) mx = fmaxf(mx, s[j]);
    #pragma unroll
    for (int off = 32; off > 0; off >>= 1) mx = fmaxf(mx, __shfl_xor(mx, off));
    float e[8], sm = 0.f;
    #pragma unroll
    for (int j = 0; j < 8; ++j) { e[j] = __expf(s[j] - mx); sm += e[j]; }
    #pragma unroll
    for (int off = 32; off > 0; off >>= 1) sm += __shfl_xor(sm, off);
    float inv = 1.0f / sm;
    bf16x8 pv;
    #pragma unroll
    for (int j = 0; j < 8; ++j) pv[j] = (short)f2b(e[j] * inv);
    *(bf16x8*)((char*)P + byte) = pv;
  }
  __syncthreads();

  // PV: ctx[48][64] = P @ V
  {
    f32x4 acc2[3];
    #pragma unroll
    for (int m = 0; m < 3; ++m) acc2[m] = (f32x4){0.f, 0.f, 0.f, 0.f};
    for (int kst = 0; kst < 16; ++kst) {
      int vrow = wv * 16 + r16;
      int baddr = ((vrow << 10) | (kst << 6) | (kq << 4)) ^ ((vrow & 7) << 4);
      bf16x8 bfr = *(const bf16x8*)((const char*)KV + baddr);
      #pragma unroll
      for (int m = 0; m < 3; ++m) {
        int prow = m * 16 + r16;
        int aaddr = ((prow << 10) | (kst << 6) | (kq << 4)) ^ ((prow & 7) << 4);
        bf16x8 afr2 = *(const bf16x8*)((const char*)P + aaddr);
        acc2[m] = __builtin_amdgcn_mfma_f32_16x16x32_bf16(afr2, bfr, acc2[m], 0, 0, 0);
      }
    }
    int d = wv * 16 + r16;
    #pragma unroll
    for (int m = 0; m < 3; ++m)
      #pragma unroll
      for (int r = 0; r < 4; ++r) {
        int u = m * 16 + kq * 4 + r;
        if (u < NSAMP) {
          size_t off = (size_t)bv * (SEQL * DMOD) + (size_t)topi[u] * DMOD + head * 64 + d;
          ctxb[off] = f2b(acc2[m][r]);
        }
      }
  }
}

// ---------------- residual add + layernorm ----------------
// BMODE: 0 = no residual-in, 2 = bf16 residual-in
// OUT: 0 none, 1 bf16 mirror, 2 hi/lo split outputs
template<int BMODE, int OUT>
__global__ __launch_bounds__(256) void add_ln(const float* __restrict__ a,
                                              const unsigned short* __restrict__ b,
                                              const float* __restrict__ g,
                                              const float* __restrict__ be,
                                              float* __restrict__ out,
                                              unsigned short* __restrict__ outb,
                                              unsigned short* __restrict__ outh,
                                              unsigned short* __restrict__ outl) {
  int r = blockIdx.x;
  int tid = threadIdx.x;
  __shared__ float red[256];
  size_t base = (size_t)r * DMOD;
  float x0 = a[base + tid];
  float x1 = a[base + tid + 256];
  if (BMODE == 2) { x0 += b2f(b[base + tid]); x1 += b2f(b[base + tid + 256]); }
  red[tid] = x0 + x1;
  __syncthreads();
  for (int s = 128; s > 0; s >>= 1) {
    if (tid < s) red[tid] += red[tid + s];
    __syncthreads();
  }
  float mu = red[0] * (1.0f / 512.0f);
  __syncthreads();
  float d0 = x0 - mu, d1 = x1 - mu;
  red[tid] = d0 * d0 + d1 * d1;
  __syncthreads();
  for (int s = 128; s > 0; s >>= 1) {
    if (tid < s) red[tid] += red[tid + s];
    __syncthreads();
  }
  float rstd = rsqrtf(red[0] * (1.0f / 512.0f) + 1e-5f);
  float o0 = d0 * rstd * g[tid] + be[tid];
  float o1 = d1 * rstd * g[tid + 256] + be[tid + 256];
  out[base + tid]       = o0;
  out[base + tid + 256] = o1;
  if (OUT == 1) {
    outb[base + tid]       = f2b(o0);
    outb[base + tid + 256] = f2b(o1);
  }
  if (OUT == 2) {
    unsigned short hi0 = f2b(o0), hi1 = f2b(o1);
    outh[base + tid]       = hi0;
    outh[base + tid + 256] = hi1;
    outl[base + tid]       = f2b(o0 - b2f(hi0));
    outl[base + tid + 256] = f2b(o1 - b2f(hi1));
  }
}

// ---------------- head: split-K partials (coalesced [blk][2688] layout) ----------------
__global__ __launch_bounds__(256) void head_partial(const float* __restrict__ h,
                                                    const float* __restrict__ Wh,
                                                    float* __restrict__ partial) {
  __shared__ float hs[28 * 132];
  __shared__ float wsm[96 * 132];
  int blk = blockIdx.x;            // 0..1023
  int tid = threadIdx.x;
  int tx = tid & 31, ty = tid >> 5;
  float acc[4][3];
  #pragma unroll
  for (int i = 0; i < 4; ++i)
    #pragma unroll
    for (int j = 0; j < 3; ++j) acc[i][j] = 0.f;
  for (int s = 0; s < 2; ++s) {
    int k0 = (blk * 2 + s) * 128;
    __syncthreads();
    for (int c = tid; c < 28 * 32; c += 256) {
      int m = c >> 5, q = c & 31;
      float4 v = *(const float4*)(h + (size_t)m * (SEQL * DMOD) + k0 + q * 4);
      *(float4*)(hs + m * 132 + q * 4) = v;
    }
    for (int c = tid; c < 96 * 32; c += 256) {
      int n = c >> 5, q = c & 31;
      float4 v = *(const float4*)(Wh + (size_t)n * (SEQL * DMOD) + k0 + q * 4);
      *(float4*)(wsm + n * 132 + q * 4) = v;
    }
    __syncthreads();
    for (int k = 0; k < 128; k += 4) {
      float4 hv[4], wv[3];
      #pragma unroll
      for (int i = 0; i < 4; ++i) hv[i] = *(const float4*)(hs + (ty * 4 + i) * 132 + k);
      #pragma unroll
      for (int j = 0; j < 3; ++j) wv[j] = *(const float4*)(wsm + (tx + j * 32) * 132 + k);
      #pragma unroll
      for (int i = 0; i < 4; ++i)
        #pragma unroll
        for (int j = 0; j < 3; ++j)
          acc[i][j] += hv[i].x * wv[j].x + hv[i].y * wv[j].y
                     + hv[i].z * wv[j].z + hv[i].w * wv[j].w;
    }
  }
  #pragma unroll
  for (int i = 0; i < 4; ++i) {
    int m = ty * 4 + i;
    if (m < 28) {
      #pragma unroll
      for (int j = 0; j < 3; ++j) {
        int n = tx + j * 32;
        partial[(size_t)blk * 2688 + m * 96 + n] = acc[i][j];
      }
    }
  }
}

__global__ __launch_bounds__(256) void head_reduce(const float* __restrict__ partial,
                                                   const float* __restrict__ bh_,
                                                   float* __restrict__ out) {
  int o = blockIdx.x;              // 0..2687 = m*96+p
  int tid = threadIdx.x;
  float s = 0.f;
  for (int b = tid; b < 1024; b += 256) s += partial[(size_t)b * 2688 + o];
  __shared__ float red[256];
  red[tid] = s;
  __syncthreads();
  for (int st = 128; st > 0; st >>= 1) {
    if (tid < st) red[tid] += red[tid + st];
    __syncthreads();
  }
  if (tid == 0) {
    int m = o / 96, p = o % 96;
    int b = m / NVARS, v = m % NVARS;
    out[(size_t)b * (NPRED * NVARS) + (size_t)p * NVARS + v] = red[0] + bh_[p];
  }
}

extern "C" void kernel_launch(void* const* d_in, const int* in_sizes, int n_in,
                              void* d_out, int out_size, void* d_ws, size_t ws_size,
                              hipStream_t stream) {
  const float* x_enc = (const float*)d_in[0];
  const float* w_emb = (const float*)d_in[1];
  const float* b_emb = (const float*)d_in[2];
  const float* w_pos = (const float*)d_in[3];
  const float* Wq = (const float*)d_in[4];
  const float* bq = (const float*)d_in[5];
  const float* Wk = (const float*)d_in[6];
  const float* bk = (const float*)d_in[7];
  const float* Wv = (const float*)d_in[8];
  const float* bv_ = (const float*)d_in[9];
  const float* Wo = (const float*)d_in[10];
  const float* bo = (const float*)d_in[11];
  const float* W1 = (const float*)d_in[12];
  const float* b1 = (const float*)d_in[13];
  const float* W2 = (const float*)d_in[14];
  const float* b2 = (const float*)d_in[15];
  const float* g1 = (const float*)d_in[16];
  const float* be1 = (const float*)d_in[17];
  const float* g2 = (const float*)d_in[18];
  const float* be2 = (const float*)d_in[19];
  const float* gF = (const float*)d_in[20];
  const float* bF = (const float*)d_in[21];
  const float* Wh = (const float*)d_in[22];
  const float* bh_ = (const float*)d_in[23];
  float* out = (float*)d_out;

  const size_t S = (size_t)SBIG;
  const size_t SB = S * 4;                    // 29,360,128 B
  char* ws = (char*)d_ws;
  float* h    = (float*)(ws);                 // [0, SB)
  float* QKb  = (float*)(ws + SB);            // [SB, 3SB): [14336][1024] fp32
  unsigned short* Vb   = (unsigned short*)(ws + 3 * SB);            // 14.7 MB
  unsigned short* Ob_b = (unsigned short*)(ws + 3 * SB + SB / 2);   // 14.7 MB
  // weight scratch region [4SB, 5SB)
  unsigned short* Wqkv_hi = (unsigned short*)(ws + 4 * SB);                 // 1 MB
  unsigned short* Wqkv_lo = (unsigned short*)(ws + 4 * SB + 0x100000);      // 1 MB
  unsigned short* Wv_b = (unsigned short*)(ws + 4 * SB + 0x200000);         // 0.5 MB
  unsigned short* Wo_b = (unsigned short*)(ws + 4 * SB + 0x280000);         // 0.5 MB
  unsigned short* W1_b = (unsigned short*)(ws + 4 * SB + 0x300000);         // 2 MB
  unsigned short* W2_b = (unsigned short*)(ws + 4 * SB + 0x500000);         // 2 MB
  float* bias_qk = (float*)(ws + 4 * SB + 0x700000);                        // 4 KB
  unsigned short* h_hi = (unsigned short*)(ws + 5 * SB);           // SB/2
  unsigned short* h_lo = (unsigned short*)(ws + 5 * SB + SB / 2);  // SB/2
  // phase aliases:
  unsigned short* CTXb = h_hi;                 // after QK+V gemms consumed h_hi
  unsigned short* h_bf = h_lo;                 // after QK gemm consumed h_lo
  unsigned short* FFNb = (unsigned short*)QKb; // after attn consumed QK
  float* partial = QKb;                        // head phase
  int*   idx = (int*)(ws + 6 * SB);                        // 70KB
  float* Mv  = (float*)(ws + 6 * SB + 0x20000);            // 448KB
  int*   top = (int*)(ws + 6 * SB + 0xA0000);              // 31KB
  float* vmean = (float*)(ws + 6 * SB + 0xB0000);          // 56KB
  if (ws_size < 6 * SB + 0xC0000) return;

  dim3 b256(256);
  int gBig = (int)((S + 255) / 256);

  embed_kernel<<<gBig, b256, 0, stream>>>(x_enc, w_emb, b_emb, w_pos, h, h_hi, h_lo);

  for (int l = 0; l < 2; ++l) {
    const float* Wql = Wq + (size_t)l * DMOD * DMOD;
    const float* Wkl = Wk + (size_t)l * DMOD * DMOD;
    const float* Wvl = Wv + (size_t)l * DMOD * DMOD;
    const float* Wol = Wo + (size_t)l * DMOD * DMOD;
    const float* W1l = W1 + (size_t)l * DFFN * DMOD;
    const float* W2l = W2 + (size_t)l * DMOD * DFFN;

    // weight prep
    split_hilo<<<(DMOD * DMOD / 4 + 255) / 256, b256, 0, stream>>>(Wql, Wqkv_hi, Wqkv_lo, DMOD * DMOD);
    split_hilo<<<(DMOD * DMOD / 4 + 255) / 256, b256, 0, stream>>>(Wkl, Wqkv_hi + DMOD * DMOD, Wqkv_lo + DMOD * DMOD, DMOD * DMOD);
    f2b_kernel<<<(DMOD * DMOD / 4 + 255) / 256, b256, 0, stream>>>(Wvl, Wv_b, DMOD * DMOD);
    f2b_kernel<<<(DMOD * DMOD / 4 + 255) / 256, b256, 0, stream>>>(Wol, Wo_b, DMOD * DMOD);
    f2b_kernel<<<(DFFN * DMOD / 4 + 255) / 256, b256, 0, stream>>>(W1l, W1_b, DFFN * DMOD);
    f2b_kernel<<<(DMOD * DFFN / 4 + 255) / 256, b256, 0, stream>>>(W2l, W2_b, DMOD * DFFN);
    bias_cat2<<<4, b256, 0, stream>>>(bq + l * DMOD, bk + l * DMOD, bias_qk);

    // QK projection (fp32-accurate, selection-exact) and V projection (bf16)
    dim3 gqk(QKS / 128, NROWS / 128);
    gemm_mfma3<<<gqk, b256, 0, stream>>>(h_hi, h_lo, Wqkv_hi, Wqkv_lo, bias_qk,
                                         QKb, NROWS, QKS, DMOD, QKS);
    dim3 gv(DMOD / 128, NROWS / 128);
    gemm_mfma<0, 1><<<gv, b256, 0, stream>>>(h_hi, Wv_b, bv_ + l * DMOD,
                                             (float*)0, Vb, NROWS, DMOD, DMOD);

    make_idx_kernel<<<(SEQL * NSAMP + 255) / 256, b256, 0, stream>>>(l, idx);
    m2_kernel<<<NBH, dim3(512), 0, stream>>>(QKb, idx, Mv);
    topk_kernel<<<NBH, b256, 0, stream>>>(Mv, top);
    vmean_kernel<<<NBH, dim3(64), 0, stream>>>(Vb, vmean);
    ctx_fill_kernel<<<gBig, b256, 0, stream>>>(vmean, CTXb);
    attn2_kernel<<<NBH, b256, 0, stream>>>(QKb, Vb, top, CTXb);

    dim3 go(DMOD / 128, NROWS / 128);
    gemm_mfma<0, 1><<<go, b256, 0, stream>>>(CTXb, Wo_b, bo + l * DMOD,
                                             (float*)0, Ob_b, NROWS, DMOD, DMOD);
    add_ln<2, 1><<<NROWS, b256, 0, stream>>>(h, Ob_b, g1 + l * DMOD, be1 + l * DMOD,
                                             h, h_bf, (unsigned short*)0, (unsigned short*)0);

    dim3 gf1(DFFN / 128, NROWS / 128);
    gemm_mfma<1, 1><<<gf1, b256, 0, stream>>>(h_bf, W1_b, b1 + l * DFFN,
                                              (float*)0, FFNb, NROWS, DFFN, DMOD);
    dim3 gf2(DMOD / 128, NROWS / 128);
    gemm_mfma<0, 1><<<gf2, b256, 0, stream>>>(FFNb, W2_b, b2 + l * DMOD,
                                              (float*)0, Ob_b, NROWS, DMOD, DFFN);
    if (l == 0) {
      add_ln<2, 2><<<NROWS, b256, 0, stream>>>(h, Ob_b, g2 + l * DMOD, be2 + l * DMOD,
                                               h, (unsigned short*)0, h_hi, h_lo);
    } else {
      add_ln<2, 0><<<NROWS, b256, 0, stream>>>(h, Ob_b, g2 + l * DMOD, be2 + l * DMOD,
                                               h, (unsigned short*)0, (unsigned short*)0, (unsigned short*)0);
    }
  }

  add_ln<0, 0><<<NROWS, b256, 0, stream>>>(h, (const unsigned short*)0, gF, bF,
                                           h, (unsigned short*)0, (unsigned short*)0, (unsigned short*)0);
  head_partial<<<1024, b256, 0, stream>>>(h, Wh, partial);
  head_reduce<<<NBV * NPRED, b256, 0, stream>>>(partial, bh_, out);
}

// Round 6
// 822.301 us; speedup vs baseline: 6.9131x; 1.0806x over previous
//
#include <hip/hip_runtime.h>
#include <math.h>

#define SEQL 512
#define DMOD 512
#define NHEAD 8
#define DHEAD 64
#define DFFN 2048
#define NBATCH 4
#define NVARS 7
#define NBV 28          // NBATCH*NVARS
#define NBH 224         // NBV*NHEAD
#define NROWS 14336     // NBV*SEQL
#define NSAMP 35        // U_part = u = 35
#define NPRED 96
#define SBIG 7340032    // NBV*SEQL*DMOD floats
#define QKS 1024        // fused QK row stride

typedef short bf16x8 __attribute__((ext_vector_type(8)));
typedef float f32x4 __attribute__((ext_vector_type(4)));

__device__ inline unsigned short f2b(float f) {
  unsigned u = __builtin_bit_cast(unsigned, f);
  unsigned r = (u + 0x7FFFu + ((u >> 16) & 1u)) >> 16;
  return (unsigned short)r;
}
__device__ inline float b2f(unsigned short h) {
  return __builtin_bit_cast(float, (unsigned)h << 16);
}

// ---------------- threefry2x32 (matches jax._src.prng) ----------------
__device__ inline void threefry2x32(unsigned k0, unsigned k1,
                                    unsigned x0, unsigned x1,
                                    unsigned &o0, unsigned &o1) {
  unsigned ks2 = k0 ^ k1 ^ 0x1BD11BDAu;
  unsigned ks[3] = {k0, k1, ks2};
  x0 += k0; x1 += k1;
  const unsigned rot[2][4] = {{13u,15u,26u,6u},{17u,29u,16u,24u}};
  #pragma unroll
  for (int i = 0; i < 5; ++i) {
    #pragma unroll
    for (int j = 0; j < 4; ++j) {
      unsigned r = rot[i & 1][j];
      x0 += x1;
      x1 = (x1 << r) | (x1 >> (32u - r));
      x1 ^= x0;
    }
    x0 += ks[(i + 1) % 3];
    x1 += ks[(i + 2) % 3] + (unsigned)(i + 1);
  }
  o0 = x0; o1 = x1;
}

__global__ void make_idx_kernel(int layer, int* idx) {
  int i = blockIdx.x * 256 + threadIdx.x;
  if (i >= SEQL * NSAMP) return;
  unsigned kl0, kl1, o0, o1;
  threefry2x32(0u, 42u, 0u, (unsigned)layer, kl0, kl1);
  threefry2x32(kl0, kl1, (unsigned)i, (unsigned)(SEQL * NSAMP + i), o0, o1);
  idx[i] = (int)(o1 & 511u);
}

// ---------------- embedding (vectorized, fused hi/lo split) ----------------
__global__ void embed_kernel(const float* __restrict__ x_enc,
                             const float* __restrict__ w_emb,
                             const float* __restrict__ b_emb,
                             const float* __restrict__ w_pos,
                             float* __restrict__ h,
                             unsigned short* __restrict__ h_hi,
                             unsigned short* __restrict__ h_lo) {
  size_t i = (size_t)blockIdx.x * 256 + threadIdx.x;
  if (i >= (size_t)(SBIG / 4)) return;
  size_t e = i * 4;
  int dm = (int)(e & 511);
  int l  = (int)((e >> 9) & 511);
  int bv = (int)(e >> 18);
  int b = bv / NVARS, v = bv % NVARS;
  float xs = x_enc[((size_t)b * SEQL + l) * NVARS + v];
  float4 we = *(const float4*)(w_emb + dm);
  float4 bb = *(const float4*)(b_emb + dm);
  float4 wp = *(const float4*)(w_pos + (size_t)l * DMOD + dm);
  float4 val;
  val.x = xs * we.x + bb.x + wp.x;
  val.y = xs * we.y + bb.y + wp.y;
  val.z = xs * we.z + bb.z + wp.z;
  val.w = xs * we.w + bb.w + wp.w;
  *(float4*)(h + e) = val;
  ushort4 hi4, lo4;
  hi4.x = f2b(val.x); lo4.x = f2b(val.x - b2f(hi4.x));
  hi4.y = f2b(val.y); lo4.y = f2b(val.y - b2f(hi4.y));
  hi4.z = f2b(val.z); lo4.z = f2b(val.z - b2f(hi4.z));
  hi4.w = f2b(val.w); lo4.w = f2b(val.w - b2f(hi4.w));
  *(ushort4*)(h_hi + e) = hi4;
  *(ushort4*)(h_lo + e) = lo4;
}

// ---------------- fused per-layer weight prep (one dispatch) ----------------
// regions: Wq hilo | Wk hilo | Wv f2b | Wo f2b | W1 f2b | W2 f2b
__global__ void prep_weights(const float* __restrict__ Wq, const float* __restrict__ Wk,
                             const float* __restrict__ Wv, const float* __restrict__ Wo,
                             const float* __restrict__ W1, const float* __restrict__ W2,
                             unsigned short* __restrict__ Wqk_hi, unsigned short* __restrict__ Wqk_lo,
                             unsigned short* __restrict__ Wv_b, unsigned short* __restrict__ Wo_b,
                             unsigned short* __restrict__ W1_b, unsigned short* __restrict__ W2_b) {
  const int Q4 = 65536;   // 262144/4
  int g = blockIdx.x * 256 + threadIdx.x;
  if (g < 2 * Q4) {
    const float* src = g < Q4 ? Wq : Wk;
    unsigned short* hi = Wqk_hi + (g < Q4 ? 0 : DMOD * DMOD);
    unsigned short* lo = Wqk_lo + (g < Q4 ? 0 : DMOD * DMOD);
    int off = (g < Q4 ? g : g - Q4) * 4;
    float4 v = *(const float4*)(src + off);
    ushort4 h4, l4;
    h4.x = f2b(v.x); l4.x = f2b(v.x - b2f(h4.x));
    h4.y = f2b(v.y); l4.y = f2b(v.y - b2f(h4.y));
    h4.z = f2b(v.z); l4.z = f2b(v.z - b2f(h4.z));
    h4.w = f2b(v.w); l4.w = f2b(v.w - b2f(h4.w));
    *(ushort4*)(hi + off) = h4;
    *(ushort4*)(lo + off) = l4;
    return;
  }
  const float* src;
  unsigned short* dst;
  int off;
  if (g < 3 * Q4)      { src = Wv; dst = Wv_b; off = (g - 2 * Q4) * 4; }
  else if (g < 4 * Q4) { src = Wo; dst = Wo_b; off = (g - 3 * Q4) * 4; }
  else if (g < 4 * Q4 + 262144) { src = W1; dst = W1_b; off = (g - 4 * Q4) * 4; }
  else                 { src = W2; dst = W2_b; off = (g - 4 * Q4 - 262144) * 4; }
  float4 v = *(const float4*)(src + off);
  ushort4 o;
  o.x = f2b(v.x); o.y = f2b(v.y); o.z = f2b(v.z); o.w = f2b(v.w);
  *(ushort4*)(dst + off) = o;
}

// ---------------- split-bf16 MFMA GEMM (3-pass hi/lo): C = A@W^T + [bq|bk] ----------------
__global__ __launch_bounds__(256) void gemm_mfma3(const unsigned short* __restrict__ Ah,
                                                  const unsigned short* __restrict__ Al,
                                                  const unsigned short* __restrict__ Bh,
                                                  const unsigned short* __restrict__ Bl,
                                                  const float* __restrict__ bq,
                                                  const float* __restrict__ bk,
                                                  float* __restrict__ C,
                                                  int M, int N, int K, int ldc) {
  __shared__ __align__(16) unsigned short AsH[128 * 64];
  __shared__ __align__(16) unsigned short AsL[128 * 64];
  __shared__ __align__(16) unsigned short BsH[128 * 64];
  __shared__ __align__(16) unsigned short BsL[128 * 64];
  int nwg = gridDim.x * gridDim.y;
  int flat = blockIdx.y * gridDim.x + blockIdx.x;
  int swz = (flat & 7) * (nwg >> 3) + (flat >> 3);
  int bxs = swz % gridDim.x, bys = swz / gridDim.x;
  int bm = bys * 128, bn = bxs * 128;
  int tid = threadIdx.x;
  int wave = tid >> 6, lane = tid & 63;
  int wr = wave >> 1, wc = wave & 1;
  int r16 = lane & 15, kq = lane >> 4;

  f32x4 acc[4][4];
  #pragma unroll
  for (int i = 0; i < 4; ++i)
    #pragma unroll
    for (int j = 0; j < 4; ++j) acc[i][j] = (f32x4){0.f, 0.f, 0.f, 0.f};

  for (int kt = 0; kt < K; kt += 64) {
    __syncthreads();
    #pragma unroll
    for (int i = 0; i < 4; ++i) {
      int c = i * 256 + tid;
      int row = c >> 3, kb = c & 7;
      size_t offA = (size_t)(bm + row) * K + kt + kb * 8;
      size_t offB = (size_t)(bn + row) * K + kt + kb * 8;
      uint4 vah = *(const uint4*)(Ah + offA);
      uint4 val = *(const uint4*)(Al + offA);
      uint4 vbh = *(const uint4*)(Bh + offB);
      uint4 vbl = *(const uint4*)(Bl + offB);
      int sw = ((row << 7) | (kb << 4)) ^ ((row & 7) << 4);
      *(uint4*)((char*)AsH + sw) = vah;
      *(uint4*)((char*)AsL + sw) = val;
      *(uint4*)((char*)BsH + sw) = vbh;
      *(uint4*)((char*)BsL + sw) = vbl;
    }
    __syncthreads();
    #pragma unroll
    for (int ks = 0; ks < 2; ++ks) {
      bf16x8 ah[4], al[4], bh[4], bl[4];
      #pragma unroll
      for (int mi = 0; mi < 4; ++mi) {
        int row = wr * 64 + mi * 16 + r16;
        int addr = ((row << 7) | (ks << 6) | (kq << 4)) ^ ((row & 7) << 4);
        ah[mi] = *(const bf16x8*)((const char*)AsH + addr);
        al[mi] = *(const bf16x8*)((const char*)AsL + addr);
      }
      #pragma unroll
      for (int ni = 0; ni < 4; ++ni) {
        int row = wc * 64 + ni * 16 + r16;
        int addr = ((row << 7) | (ks << 6) | (kq << 4)) ^ ((row & 7) << 4);
        bh[ni] = *(const bf16x8*)((const char*)BsH + addr);
        bl[ni] = *(const bf16x8*)((const char*)BsL + addr);
      }
      #pragma unroll
      for (int mi = 0; mi < 4; ++mi)
        #pragma unroll
        for (int ni = 0; ni < 4; ++ni) {
          acc[mi][ni] = __builtin_amdgcn_mfma_f32_16x16x32_bf16(ah[mi], bh[ni], acc[mi][ni], 0, 0, 0);
          acc[mi][ni] = __builtin_amdgcn_mfma_f32_16x16x32_bf16(ah[mi], bl[ni], acc[mi][ni], 0, 0, 0);
          acc[mi][ni] = __builtin_amdgcn_mfma_f32_16x16x32_bf16(al[mi], bh[ni], acc[mi][ni], 0, 0, 0);
        }
    }
  }
  int crow0 = bm + wr * 64 + (lane >> 4) * 4;
  int ccol0 = bn + wc * 64 + (lane & 15);
  #pragma unroll
  for (int mi = 0; mi < 4; ++mi) {
    #pragma unroll
    for (int ni = 0; ni < 4; ++ni) {
      int col = ccol0 + ni * 16;
      float bvv = col < 512 ? bq[col] : bk[col - 512];
      #pragma unroll
      for (int r = 0; r < 4; ++r) {
        int row = crow0 + mi * 16 + r;
        C[(size_t)row * ldc + col] = acc[mi][ni][r] + bvv;
      }
    }
  }
}

// ---------------- bf16 MFMA GEMM (single): C = A@W^T + bias, opt gelu ----------------
template<int ACT, int OUTBF>
__global__ __launch_bounds__(256) void gemm_mfma(const unsigned short* __restrict__ A,
                                                 const unsigned short* __restrict__ W,
                                                 const float* __restrict__ bias,
                                                 float* __restrict__ Cf,
                                                 unsigned short* __restrict__ Cb,
                                                 int M, int N, int K) {
  __shared__ __align__(16) unsigned short As[128 * 64];
  __shared__ __align__(16) unsigned short Bs[128 * 64];
  int nwg = gridDim.x * gridDim.y;
  int flat = blockIdx.y * gridDim.x + blockIdx.x;
  int swz = (flat & 7) * (nwg >> 3) + (flat >> 3);
  int bxs = swz % gridDim.x, bys = swz / gridDim.x;
  int bm = bys * 128, bn = bxs * 128;
  int tid = threadIdx.x;
  int wave = tid >> 6, lane = tid & 63;
  int wr = wave >> 1, wc = wave & 1;
  int r16 = lane & 15, kq = lane >> 4;

  f32x4 acc[4][4];
  #pragma unroll
  for (int i = 0; i < 4; ++i)
    #pragma unroll
    for (int j = 0; j < 4; ++j) acc[i][j] = (f32x4){0.f, 0.f, 0.f, 0.f};

  for (int kt = 0; kt < K; kt += 64) {
    __syncthreads();
    #pragma unroll
    for (int i = 0; i < 4; ++i) {
      int c = i * 256 + tid;
      int row = c >> 3, kb = c & 7;
      uint4 va = *(const uint4*)(A + (size_t)(bm + row) * K + kt + kb * 8);
      uint4 vb = *(const uint4*)(W + (size_t)(bn + row) * K + kt + kb * 8);
      int sw = ((row << 7) | (kb << 4)) ^ ((row & 7) << 4);
      *(uint4*)((char*)As + sw) = va;
      *(uint4*)((char*)Bs + sw) = vb;
    }
    __syncthreads();
    #pragma unroll
    for (int ks = 0; ks < 2; ++ks) {
      bf16x8 afr[4], bfr[4];
      #pragma unroll
      for (int mi = 0; mi < 4; ++mi) {
        int row = wr * 64 + mi * 16 + r16;
        int addr = ((row << 7) | (ks << 6) | (kq << 4)) ^ ((row & 7) << 4);
        afr[mi] = *(const bf16x8*)((const char*)As + addr);
      }
      #pragma unroll
      for (int ni = 0; ni < 4; ++ni) {
        int row = wc * 64 + ni * 16 + r16;
        int addr = ((row << 7) | (ks << 6) | (kq << 4)) ^ ((row & 7) << 4);
        bfr[ni] = *(const bf16x8*)((const char*)Bs + addr);
      }
      #pragma unroll
      for (int mi = 0; mi < 4; ++mi)
        #pragma unroll
        for (int ni = 0; ni < 4; ++ni)
          acc[mi][ni] = __builtin_amdgcn_mfma_f32_16x16x32_bf16(afr[mi], bfr[ni], acc[mi][ni], 0, 0, 0);
    }
  }
  int crow0 = bm + wr * 64 + (lane >> 4) * 4;
  int ccol0 = bn + wc * 64 + (lane & 15);
  #pragma unroll
  for (int mi = 0; mi < 4; ++mi) {
    #pragma unroll
    for (int ni = 0; ni < 4; ++ni) {
      int col = ccol0 + ni * 16;
      float bvv = bias[col];
      #pragma unroll
      for (int r = 0; r < 4; ++r) {
        int row = crow0 + mi * 16 + r;
        float v = acc[mi][ni][r] + bvv;
        if (ACT) {
          float x = v;
          float t = tanhf(0.7978845608028654f * (x + 0.044715f * x * x * x));
          v = 0.5f * x * (1.0f + t);
        }
        if (OUTBF) Cb[(size_t)row * N + col] = f2b(v);
        else       Cf[(size_t)row * N + col] = v;
      }
    }
  }
}

// ---------------- M measure: block per (bh), K staged in LDS ----------------
__global__ __launch_bounds__(512) void m2_kernel(const float* __restrict__ QK,
                                                 const int* __restrict__ idx,
                                                 float* __restrict__ Mout) {
  int bh = blockIdx.x;
  int bv = bh >> 3, head = bh & 7;
  int tid = threadIdx.x;                 // 0..511, one q-row each
  __shared__ float Ks[512 * 65];
  const float* base = QK + (size_t)bv * (SEQL * QKS);
  for (int c = tid; c < 512 * 16; c += 512) {
    int l = c >> 4, d4 = (c & 15) * 4;
    float4 v = *(const float4*)(base + (size_t)l * QKS + 512 + head * 64 + d4);
    Ks[l * 65 + d4 + 0] = v.x;
    Ks[l * 65 + d4 + 1] = v.y;
    Ks[l * 65 + d4 + 2] = v.z;
    Ks[l * 65 + d4 + 3] = v.w;
  }
  float q[64];
  const float* qp = base + (size_t)tid * QKS + head * 64;
  #pragma unroll
  for (int d4 = 0; d4 < 64; d4 += 4) {
    float4 qv = *(const float4*)(qp + d4);
    q[d4 + 0] = qv.x; q[d4 + 1] = qv.y; q[d4 + 2] = qv.z; q[d4 + 3] = qv.w;
  }
  __syncthreads();
  const int* ip = idx + tid * NSAMP;
  float mx = -INFINITY, sm = 0.f;
  for (int u = 0; u < NSAMP; ++u) {
    int kidx = ip[u];
    const float* kr = Ks + kidx * 65;
    float s = 0.f;
    #pragma unroll
    for (int d = 0; d < 64; ++d) s += q[d] * kr[d];
    mx = fmaxf(mx, s);
    sm += s;
  }
  Mout[(size_t)bh * SEQL + tid] = mx - sm * (1.0f / 512.0f);
}

// ---------------- top-k (k=35) ----------------
__global__ __launch_bounds__(256) void topk_kernel(const float* __restrict__ Mv,
                                                   int* __restrict__ top) {
  int bh = blockIdx.x;
  int tid = threadIdx.x;
  __shared__ float vals[512];
  __shared__ float rv[256];
  __shared__ int ri[256];
  vals[tid]       = Mv[(size_t)bh * SEQL + tid];
  vals[tid + 256] = Mv[(size_t)bh * SEQL + tid + 256];
  __syncthreads();
  for (int t = 0; t < NSAMP; ++t) {
    float v0 = vals[tid], v1 = vals[tid + 256];
    float bvv; int bii;
    if (v0 >= v1) { bvv = v0; bii = tid; } else { bvv = v1; bii = tid + 256; }
    rv[tid] = bvv; ri[tid] = bii;
    __syncthreads();
    for (int s = 128; s > 0; s >>= 1) {
      if (tid < s) {
        float ov = rv[tid + s]; int oi = ri[tid + s];
        if (ov > rv[tid] || (ov == rv[tid] && oi < ri[tid])) { rv[tid] = ov; ri[tid] = oi; }
      }
      __syncthreads();
    }
    if (tid == 0) { top[bh * NSAMP + t] = ri[0]; vals[ri[0]] = -INFINITY; }
    __syncthreads();
  }
}

// ---------------- mean of V (bf16 V) ----------------
__global__ __launch_bounds__(64) void vmean_kernel(const unsigned short* __restrict__ Vb,
                                                   float* __restrict__ vmean) {
  int bh = blockIdx.x;
  int bv = bh >> 3, head = bh & 7;
  int d = threadIdx.x;
  const unsigned short* vb = Vb + (size_t)bv * (SEQL * DMOD) + head * 64 + d;
  float s = 0.f;
  for (int l = 0; l < SEQL; ++l) s += b2f(vb[(size_t)l * DMOD]);
  vmean[bh * DHEAD + d] = s * (1.0f / 512.0f);
}

// ---------------- ctx = broadcast vmean (bf16 out, vectorized) ----------------
__global__ void ctx_fill_kernel(const float* __restrict__ vmean,
                                unsigned short* __restrict__ ctxb) {
  size_t i = (size_t)blockIdx.x * 256 + threadIdx.x;
  if (i >= (size_t)(SBIG / 4)) return;
  size_t e = i * 4;
  int dm = (int)(e & 511);
  int bv = (int)(e >> 18);
  float4 vm = *(const float4*)(vmean + bv * DMOD + dm);
  ushort4 o;
  o.x = f2b(vm.x); o.y = f2b(vm.y); o.z = f2b(vm.z); o.w = f2b(vm.w);
  *(ushort4*)(ctxb + e) = o;
}

// ---------------- MFMA attention for selected queries: block per (bh) ----------------
__global__ __launch_bounds__(256) void attn2_kernel(const float* __restrict__ QK,
                                                    const unsigned short* __restrict__ Vb,
                                                    const int* __restrict__ top,
                                                    unsigned short* __restrict__ ctxb) {
  __shared__ __align__(16) unsigned short KV[512 * 64];
  __shared__ __align__(16) unsigned short P[48 * 512];
  __shared__ __align__(16) unsigned short Qs[48 * 64];
  __shared__ int topi[NSAMP];
  int bh = blockIdx.x;
  int bv = bh >> 3, head = bh & 7;
  int tid = threadIdx.x;
  int wv = tid >> 6, lane = tid & 63;
  int r16 = lane & 15, kq = lane >> 4;
  const float* base = QK + (size_t)bv * (SEQL * QKS);
  const unsigned short* vbase = Vb + (size_t)bv * (SEQL * DMOD) + head * 64;

  if (tid < NSAMP) topi[tid] = top[bh * NSAMP + tid];
  __syncthreads();

  for (int c = tid; c < NSAMP * 16; c += 256) {
    int u = c >> 4, dq = c & 15;
    float4 q4 = *(const float4*)(base + (size_t)topi[u] * QKS + head * 64 + dq * 4);
    ushort4 o;
    o.x = f2b(q4.x * 0.125f); o.y = f2b(q4.y * 0.125f);
    o.z = f2b(q4.z * 0.125f); o.w = f2b(q4.w * 0.125f);
    int byte = ((u << 7) | (dq << 3)) ^ ((u & 7) << 4);
    *(ushort4*)((char*)Qs + byte) = o;
  }
  for (int c = tid; c < 512 * 16; c += 256) {
    int l = c >> 4, dq = c & 15;
    float4 k4 = *(const float4*)(base + (size_t)l * QKS + 512 + head * 64 + dq * 4);
    ushort4 o;
    o.x = f2b(k4.x); o.y = f2b(k4.y); o.z = f2b(k4.z); o.w = f2b(k4.w);
    int byte = ((l << 7) | (dq << 3)) ^ ((l & 7) << 4);
    *(ushort4*)((char*)KV + byte) = o;
  }
  __syncthreads();

  // QK^T: scores[48][512]
  {
    f32x4 acc[3][8];
    #pragma unroll
    for (int m = 0; m < 3; ++m)
      #pragma unroll
      for (int j = 0; j < 8; ++j) acc[m][j] = (f32x4){0.f, 0.f, 0.f, 0.f};
    bf16x8 afr[3][2];
    #pragma unroll
    for (int m = 0; m < 3; ++m)
      #pragma unroll
      for (int ks = 0; ks < 2; ++ks) {
        int row = m * 16 + r16;
        int addr = ((row << 7) | (ks << 6) | (kq << 4)) ^ ((row & 7) << 4);
        afr[m][ks] = *(const bf16x8*)((const char*)Qs + addr);
      }
    #pragma unroll
    for (int j = 0; j < 8; ++j) {
      int nrow = (wv * 8 + j) * 16 + r16;
      #pragma unroll
      for (int ks = 0; ks < 2; ++ks) {
        int addr = ((nrow << 7) | (ks << 6) | (kq << 4)) ^ ((nrow & 7) << 4);
        bf16x8 bfr = *(const bf16x8*)((const char*)KV + addr);
        #pragma unroll
        for (int m = 0; m < 3; ++m)
          acc[m][j] = __builtin_amdgcn_mfma_f32_16x16x32_bf16(afr[m][ks], bfr, acc[m][j], 0, 0, 0);
      }
    }
    #pragma unroll
    for (int m = 0; m < 3; ++m)
      #pragma unroll
      for (int j = 0; j < 8; ++j) {
        int l = (wv * 8 + j) * 16 + r16;
        #pragma unroll
        for (int r = 0; r < 4; ++r) {
          int u = m * 16 + kq * 4 + r;
          int byte = ((u << 10) | (l << 1)) ^ ((u & 7) << 4);
          *(unsigned short*)((char*)P + byte) = f2b(acc[m][j][r]);
        }
      }
  }
  __syncthreads();

  // stage V^T into KV region (K dead) from bf16 V
  for (int c = tid; c < 512 * 8; c += 256) {
    int l = c >> 3, dq = c & 7;
    bf16x8 v8 = *(const bf16x8*)(vbase + (size_t)l * DMOD + dq * 8);
    #pragma unroll
    for (int j = 0; j < 8; ++j) {
      int d = dq * 8 + j;
      int byte = ((d << 10) | (l << 1)) ^ ((d & 7) << 4);
      *(unsigned short*)((char*)KV + byte) = (unsigned short)v8[j];
    }
  }
  // softmax on P rows
  for (int u = wv; u < NSAMP; u += 4) {
    int byte = ((u << 10) | (lane << 4)) ^ ((u & 7) << 4);
    bf16x8 sv = *(const bf16x8*)((const char*)P + byte);
    float s[8];
    #pragma unroll
    for (int j = 0; j < 8; ++j) s[j] = b2f((unsigned short)sv[j]);
    float mx = s[0];
    #pragma unroll
    for (int j = 1; j < 8; ++j) mx = fmaxf(mx, s[j]);
    #pragma unroll
    for (int off = 32; off > 0; off >>= 1) mx = fmaxf(mx, __shfl_xor(mx, off));
    float e[8], sm = 0.f;
    #pragma unroll
    for (int j = 0; j < 8; ++j) { e[j] = __expf(s[j] - mx); sm += e[j]; }
    #pragma unroll
    for (int off = 32; off > 0; off >>= 1) sm += __shfl_xor(sm, off);
    float inv = 1.0f / sm;
    bf16x8 pv;
    #pragma unroll
    for (int j = 0; j < 8; ++j) pv[j] = (short)f2b(e[j] * inv);
    *(bf16x8*)((char*)P + byte) = pv;
  }
  __syncthreads();

  // PV: ctx[48][64] = P @ V
  {
    f32x4 acc2[3];
    #pragma unroll
    for (int m = 0; m < 3; ++m) acc2[m] = (f32x4){0.f, 0.f, 0.f, 0.f};
    for (int kst = 0; kst < 16; ++kst) {
      int vrow = wv * 16 + r16;
      int baddr = ((vrow << 10) | (kst << 6) | (kq << 4)) ^ ((vrow & 7) << 4);
      bf16x8 bfr = *(const bf16x8*)((const char*)KV + baddr);
      #pragma unroll
      for (int m = 0; m < 3; ++m) {
        int prow = m * 16 + r16;
        int aaddr = ((prow << 10) | (kst << 6) | (kq << 4)) ^ ((prow & 7) << 4);
        bf16x8 afr2 = *(const bf16x8*)((const char*)P + aaddr);
        acc2[m] = __builtin_amdgcn_mfma_f32_16x16x32_bf16(afr2, bfr, acc2[m], 0, 0, 0);
      }
    }
    int d = wv * 16 + r16;
    #pragma unroll
    for (int m = 0; m < 3; ++m)
      #pragma unroll
      for (int r = 0; r < 4; ++r) {
        int u = m * 16 + kq * 4 + r;
        if (u < NSAMP) {
          size_t off = (size_t)bv * (SEQL * DMOD) + (size_t)topi[u] * DMOD + head * 64 + d;
          ctxb[off] = f2b(acc2[m][r]);
        }
      }
  }
}

// ---------------- residual add + layernorm (vectorized: 2 rows/block) ----------------
// BMODE: 0 = no residual-in, 2 = bf16 residual-in
// OUT: 0 none, 1 bf16 mirror, 2 hi/lo split outputs
template<int BMODE, int OUT>
__global__ __launch_bounds__(256) void add_ln(const float* __restrict__ a,
                                              const unsigned short* __restrict__ b,
                                              const float* __restrict__ g,
                                              const float* __restrict__ be,
                                              float* __restrict__ out,
                                              unsigned short* __restrict__ outb,
                                              unsigned short* __restrict__ outh,
                                              unsigned short* __restrict__ outl) {
  int row = blockIdx.x * 2 + (threadIdx.x >> 7);
  int t = threadIdx.x & 127;
  int wave = threadIdx.x >> 6;
  int lane = threadIdx.x & 63;
  size_t base = (size_t)row * DMOD + t * 4;
  float4 x = *(const float4*)(a + base);
  if (BMODE == 2) {
    ushort4 r4 = *(const ushort4*)(b + base);
    x.x += b2f(r4.x); x.y += b2f(r4.y); x.z += b2f(r4.z); x.w += b2f(r4.w);
  }
  float s1 = x.x + x.y + x.z + x.w;
  float s2 = x.x * x.x + x.y * x.y + x.z * x.z + x.w * x.w;
  #pragma unroll
  for (int off = 32; off > 0; off >>= 1) {
    s1 += __shfl_xor(s1, off);
    s2 += __shfl_xor(s2, off);
  }
  __shared__ float sh[8];
  if (lane == 0) { sh[wave * 2] = s1; sh[wave * 2 + 1] = s2; }
  __syncthreads();
  int mate = wave ^ 1;
  s1 += sh[mate * 2];
  s2 += sh[mate * 2 + 1];
  float mu = s1 * (1.0f / 512.0f);
  float var = s2 * (1.0f / 512.0f) - mu * mu;
  float rstd = rsqrtf(var + 1e-5f);
  float4 gg = *(const float4*)(g + t * 4);
  float4 bb = *(const float4*)(be + t * 4);
  float4 o;
  o.x = (x.x - mu) * rstd * gg.x + bb.x;
  o.y = (x.y - mu) * rstd * gg.y + bb.y;
  o.z = (x.z - mu) * rstd * gg.z + bb.z;
  o.w = (x.w - mu) * rstd * gg.w + bb.w;
  *(float4*)(out + base) = o;
  if (OUT == 1) {
    ushort4 ob;
    ob.x = f2b(o.x); ob.y = f2b(o.y); ob.z = f2b(o.z); ob.w = f2b(o.w);
    *(ushort4*)(outb + base) = ob;
  }
  if (OUT == 2) {
    ushort4 hi4, lo4;
    hi4.x = f2b(o.x); lo4.x = f2b(o.x - b2f(hi4.x));
    hi4.y = f2b(o.y); lo4.y = f2b(o.y - b2f(hi4.y));
    hi4.z = f2b(o.z); lo4.z = f2b(o.z - b2f(hi4.z));
    hi4.w = f2b(o.w); lo4.w = f2b(o.w - b2f(hi4.w));
    *(ushort4*)(outh + base) = hi4;
    *(ushort4*)(outl + base) = lo4;
  }
}

// ---------------- head via MFMA: partial[blk*4+w][2688], K-chunk 512/block ----------------
// A = h_bf [28][262144] bf16 (padded to 32 rows), B = Wh fp32 converted on the fly.
__global__ __launch_bounds__(256) void head_partial_mfma(const unsigned short* __restrict__ hbf,
                                                         const float* __restrict__ Wh,
                                                         float* __restrict__ partial) {
  __shared__ __align__(16) unsigned short Hs[32 * 512];   // 32 KB
  __shared__ __align__(16) unsigned short Ws[96 * 512];   // 96 KB
  int blk = blockIdx.x;            // 0..511
  int k0 = blk * 512;
  int tid = threadIdx.x;
  int wv = tid >> 6, lane = tid & 63;
  int r16 = lane & 15, kq = lane >> 4;

  for (int c = tid; c < 32 * 64; c += 256) {
    int row = c >> 6, col8 = c & 63;
    int src = row < 28 ? row : 0;
    bf16x8 v = *(const bf16x8*)(hbf + (size_t)src * 262144 + k0 + col8 * 8);
    int byte = ((row << 10) | (col8 << 4)) ^ ((row & 7) << 4);
    *(bf16x8*)((char*)Hs + byte) = v;
  }
  for (int c = tid; c < 96 * 64; c += 256) {
    int row = c >> 6, col8 = c & 63;
    const float* src = Wh + (size_t)row * 262144 + k0 + col8 * 8;
    float4 va = *(const float4*)(src);
    float4 vb = *(const float4*)(src + 4);
    bf16x8 o8;
    o8[0] = (short)f2b(va.x); o8[1] = (short)f2b(va.y);
    o8[2] = (short)f2b(va.z); o8[3] = (short)f2b(va.w);
    o8[4] = (short)f2b(vb.x); o8[5] = (short)f2b(vb.y);
    o8[6] = (short)f2b(vb.z); o8[7] = (short)f2b(vb.w);
    int byte = ((row << 10) | (col8 << 4)) ^ ((row & 7) << 4);
    *(bf16x8*)((char*)Ws + byte) = o8;
  }
  __syncthreads();

  f32x4 acc[2][6];
  #pragma unroll
  for (int mt = 0; mt < 2; ++mt)
    #pragma unroll
    for (int nt = 0; nt < 6; ++nt) acc[mt][nt] = (f32x4){0.f, 0.f, 0.f, 0.f};

  #pragma unroll
  for (int kk = 0; kk < 4; ++kk) {
    int kfrag = wv * 4 + kk;     // k = kfrag*32 + kq*8
    bf16x8 afr[2];
    #pragma unroll
    for (int mt = 0; mt < 2; ++mt) {
      int row = mt * 16 + r16;
      int byte = ((row << 10) | (kfrag << 6) | (kq << 4)) ^ ((row & 7) << 4);
      afr[mt] = *(const bf16x8*)((const char*)Hs + byte);
    }
    #pragma unroll
    for (int nt = 0; nt < 6; ++nt) {
      int row = nt * 16 + r16;
      int byte = ((row << 10) | (kfrag << 6) | (kq << 4)) ^ ((row & 7) << 4);
      bf16x8 bfr = *(const bf16x8*)((const char*)Ws + byte);
      #pragma unroll
      for (int mt = 0; mt < 2; ++mt)
        acc[mt][nt] = __builtin_amdgcn_mfma_f32_16x16x32_bf16(afr[mt], bfr, acc[mt][nt], 0, 0, 0);
    }
  }
  size_t prow = (size_t)(blk * 4 + wv) * 2688;
  #pragma unroll
  for (int mt = 0; mt < 2; ++mt)
    #pragma unroll
    for (int nt = 0; nt < 6; ++nt)
      #pragma unroll
      for (int r = 0; r < 4; ++r) {
        int m = mt * 16 + kq * 4 + r;
        int n = nt * 16 + r16;
        if (m < 28) partial[prow + m * 96 + n] = acc[mt][nt][r];
      }
}

__global__ __launch_bounds__(256) void head_reduce(const float* __restrict__ partial,
                                                   const float* __restrict__ bh_,
                                                   float* __restrict__ out) {
  int o = blockIdx.x;              // 0..2687 = m*96+p
  int tid = threadIdx.x;
  float s = 0.f;
  for (int b = tid; b < 2048; b += 256) s += partial[(size_t)b * 2688 + o];
  __shared__ float red[256];
  red[tid] = s;
  __syncthreads();
  for (int st = 128; st > 0; st >>= 1) {
    if (tid < st) red[tid] += red[tid + st];
    __syncthreads();
  }
  if (tid == 0) {
    int m = o / 96, p = o % 96;
    int b = m / NVARS, v = m % NVARS;
    out[(size_t)b * (NPRED * NVARS) + (size_t)p * NVARS + v] = red[0] + bh_[p];
  }
}

extern "C" void kernel_launch(void* const* d_in, const int* in_sizes, int n_in,
                              void* d_out, int out_size, void* d_ws, size_t ws_size,
                              hipStream_t stream) {
  const float* x_enc = (const float*)d_in[0];
  const float* w_emb = (const float*)d_in[1];
  const float* b_emb = (const float*)d_in[2];
  const float* w_pos = (const float*)d_in[3];
  const float* Wq = (const float*)d_in[4];
  const float* bq = (const float*)d_in[5];
  const float* Wk = (const float*)d_in[6];
  const float* bk = (const float*)d_in[7];
  const float* Wv = (const float*)d_in[8];
  const float* bv_ = (const float*)d_in[9];
  const float* Wo = (const float*)d_in[10];
  const float* bo = (const float*)d_in[11];
  const float* W1 = (const float*)d_in[12];
  const float* b1 = (const float*)d_in[13];
  const float* W2 = (const float*)d_in[14];
  const float* b2 = (const float*)d_in[15];
  const float* g1 = (const float*)d_in[16];
  const float* be1 = (const float*)d_in[17];
  const float* g2 = (const float*)d_in[18];
  const float* be2 = (const float*)d_in[19];
  const float* gF = (const float*)d_in[20];
  const float* bF = (const float*)d_in[21];
  const float* Wh = (const float*)d_in[22];
  const float* bh_ = (const float*)d_in[23];
  float* out = (float*)d_out;

  const size_t S = (size_t)SBIG;
  const size_t SB = S * 4;                    // 29,360,128 B
  char* ws = (char*)d_ws;
  float* h    = (float*)(ws);                 // [0, SB)
  float* QKb  = (float*)(ws + SB);            // [SB, 3SB): [14336][1024] fp32
  unsigned short* Vb   = (unsigned short*)(ws + 3 * SB);            // 14.7 MB
  unsigned short* Ob_b = (unsigned short*)(ws + 3 * SB + SB / 2);   // 14.7 MB
  // weight scratch region [4SB, 5SB)
  unsigned short* Wqk_hi = (unsigned short*)(ws + 4 * SB);                  // 1 MB
  unsigned short* Wqk_lo = (unsigned short*)(ws + 4 * SB + 0x100000);       // 1 MB
  unsigned short* Wv_b = (unsigned short*)(ws + 4 * SB + 0x200000);         // 0.5 MB
  unsigned short* Wo_b = (unsigned short*)(ws + 4 * SB + 0x280000);         // 0.5 MB
  unsigned short* W1_b = (unsigned short*)(ws + 4 * SB + 0x300000);         // 2 MB
  unsigned short* W2_b = (unsigned short*)(ws + 4 * SB + 0x500000);         // 2 MB
  unsigned short* h_hi = (unsigned short*)(ws + 5 * SB);           // SB/2
  unsigned short* h_lo = (unsigned short*)(ws + 5 * SB + SB / 2);  // SB/2
  // phase aliases:
  unsigned short* CTXb = h_hi;                 // after QK+V gemms consumed h_hi
  unsigned short* h_bf = h_lo;                 // after QK gemm consumed h_lo
  unsigned short* FFNb = (unsigned short*)QKb; // after attn consumed QK
  float* partial = QKb;                        // head phase (22 MB <= 2SB)
  int*   idx = (int*)(ws + 6 * SB);                        // 70KB
  float* Mv  = (float*)(ws + 6 * SB + 0x20000);            // 448KB
  int*   top = (int*)(ws + 6 * SB + 0xA0000);              // 31KB
  float* vmean = (float*)(ws + 6 * SB + 0xB0000);          // 56KB
  if (ws_size < 6 * SB + 0xC0000) return;

  dim3 b256(256);
  int gVec = (int)(S / 4 / 256);   // 7168

  embed_kernel<<<gVec, b256, 0, stream>>>(x_enc, w_emb, b_emb, w_pos, h, h_hi, h_lo);

  for (int l = 0; l < 2; ++l) {
    const float* Wql = Wq + (size_t)l * DMOD * DMOD;
    const float* Wkl = Wk + (size_t)l * DMOD * DMOD;
    const float* Wvl = Wv + (size_t)l * DMOD * DMOD;
    const float* Wol = Wo + (size_t)l * DMOD * DMOD;
    const float* W1l = W1 + (size_t)l * DFFN * DMOD;
    const float* W2l = W2 + (size_t)l * DMOD * DFFN;

    prep_weights<<<3072, b256, 0, stream>>>(Wql, Wkl, Wvl, Wol, W1l, W2l,
                                            Wqk_hi, Wqk_lo, Wv_b, Wo_b, W1_b, W2_b);

    dim3 gqk(QKS / 128, NROWS / 128);
    gemm_mfma3<<<gqk, b256, 0, stream>>>(h_hi, h_lo, Wqk_hi, Wqk_lo,
                                         bq + l * DMOD, bk + l * DMOD,
                                         QKb, NROWS, QKS, DMOD, QKS);
    dim3 gv(DMOD / 128, NROWS / 128);
    gemm_mfma<0, 1><<<gv, b256, 0, stream>>>(h_hi, Wv_b, bv_ + l * DMOD,
                                             (float*)0, Vb, NROWS, DMOD, DMOD);

    make_idx_kernel<<<(SEQL * NSAMP + 255) / 256, b256, 0, stream>>>(l, idx);
    m2_kernel<<<NBH, dim3(512), 0, stream>>>(QKb, idx, Mv);
    topk_kernel<<<NBH, b256, 0, stream>>>(Mv, top);
    vmean_kernel<<<NBH, dim3(64), 0, stream>>>(Vb, vmean);
    ctx_fill_kernel<<<gVec, b256, 0, stream>>>(vmean, CTXb);
    attn2_kernel<<<NBH, b256, 0, stream>>>(QKb, Vb, top, CTXb);

    dim3 go(DMOD / 128, NROWS / 128);
    gemm_mfma<0, 1><<<go, b256, 0, stream>>>(CTXb, Wo_b, bo + l * DMOD,
                                             (float*)0, Ob_b, NROWS, DMOD, DMOD);
    add_ln<2, 1><<<NROWS / 2, b256, 0, stream>>>(h, Ob_b, g1 + l * DMOD, be1 + l * DMOD,
                                                 h, h_bf, (unsigned short*)0, (unsigned short*)0);

    dim3 gf1(DFFN / 128, NROWS / 128);
    gemm_mfma<1, 1><<<gf1, b256, 0, stream>>>(h_bf, W1_b, b1 + l * DFFN,
                                              (float*)0, FFNb, NROWS, DFFN, DMOD);
    dim3 gf2(DMOD / 128, NROWS / 128);
    gemm_mfma<0, 1><<<gf2, b256, 0, stream>>>(FFNb, W2_b, b2 + l * DMOD,
                                              (float*)0, Ob_b, NROWS, DMOD, DFFN);
    if (l == 0) {
      add_ln<2, 2><<<NROWS / 2, b256, 0, stream>>>(h, Ob_b, g2 + l * DMOD, be2 + l * DMOD,
                                                   h, (unsigned short*)0, h_hi, h_lo);
    } else {
      add_ln<2, 0><<<NROWS / 2, b256, 0, stream>>>(h, Ob_b, g2 + l * DMOD, be2 + l * DMOD,
                                                   h, (unsigned short*)0, (unsigned short*)0, (unsigned short*)0);
    }
  }

  add_ln<0, 1><<<NROWS / 2, b256, 0, stream>>>(h, (const unsigned short*)0, gF, bF,
                                               h, h_bf, (unsigned short*)0, (unsigned short*)0);
  head_partial_mfma<<<512, b256, 0, stream>>>(h_bf, Wh, partial);
  head_reduce<<<NBV * NPRED, b256, 0, stream>>>(partial, bh_, out);
}

// Round 7
// 806.880 us; speedup vs baseline: 7.0452x; 1.0191x over previous
//
#include <hip/hip_runtime.h>
#include <math.h>

#define SEQL 512
#define DMOD 512
#define NHEAD 8
#define DHEAD 64
#define DFFN 2048
#define NBATCH 4
#define NVARS 7
#define NBV 28          // NBATCH*NVARS
#define NBH 224         // NBV*NHEAD
#define NROWS 14336     // NBV*SEQL
#define NSAMP 35        // U_part = u = 35
#define NPRED 96
#define SBIG 7340032    // NBV*SEQL*DMOD floats
#define QKS 1024        // fused QK row stride

typedef short bf16x8 __attribute__((ext_vector_type(8)));
typedef float f32x4 __attribute__((ext_vector_type(4)));

__device__ inline unsigned short f2b(float f) {
  unsigned u = __builtin_bit_cast(unsigned, f);
  unsigned r = (u + 0x7FFFu + ((u >> 16) & 1u)) >> 16;
  return (unsigned short)r;
}
__device__ inline float b2f(unsigned short h) {
  return __builtin_bit_cast(float, (unsigned)h << 16);
}

// ---------------- threefry2x32 (matches jax._src.prng) ----------------
__device__ inline void threefry2x32(unsigned k0, unsigned k1,
                                    unsigned x0, unsigned x1,
                                    unsigned &o0, unsigned &o1) {
  unsigned ks2 = k0 ^ k1 ^ 0x1BD11BDAu;
  unsigned ks[3] = {k0, k1, ks2};
  x0 += k0; x1 += k1;
  const unsigned rot[2][4] = {{13u,15u,26u,6u},{17u,29u,16u,24u}};
  #pragma unroll
  for (int i = 0; i < 5; ++i) {
    #pragma unroll
    for (int j = 0; j < 4; ++j) {
      unsigned r = rot[i & 1][j];
      x0 += x1;
      x1 = (x1 << r) | (x1 >> (32u - r));
      x1 ^= x0;
    }
    x0 += ks[(i + 1) % 3];
    x1 += ks[(i + 2) % 3] + (unsigned)(i + 1);
  }
  o0 = x0; o1 = x1;
}

__global__ void make_idx_kernel(int layer, int* idx) {
  int i = blockIdx.x * 256 + threadIdx.x;
  if (i >= SEQL * NSAMP) return;
  unsigned kl0, kl1, o0, o1;
  threefry2x32(0u, 42u, 0u, (unsigned)layer, kl0, kl1);
  threefry2x32(kl0, kl1, (unsigned)i, (unsigned)(SEQL * NSAMP + i), o0, o1);
  idx[i] = (int)(o1 & 511u);
}

// ---------------- embedding (vectorized, fused hi/lo split) ----------------
__global__ void embed_kernel(const float* __restrict__ x_enc,
                             const float* __restrict__ w_emb,
                             const float* __restrict__ b_emb,
                             const float* __restrict__ w_pos,
                             float* __restrict__ h,
                             unsigned short* __restrict__ h_hi,
                             unsigned short* __restrict__ h_lo) {
  size_t i = (size_t)blockIdx.x * 256 + threadIdx.x;
  if (i >= (size_t)(SBIG / 4)) return;
  size_t e = i * 4;
  int dm = (int)(e & 511);
  int l  = (int)((e >> 9) & 511);
  int bv = (int)(e >> 18);
  int b = bv / NVARS, v = bv % NVARS;
  float xs = x_enc[((size_t)b * SEQL + l) * NVARS + v];
  float4 we = *(const float4*)(w_emb + dm);
  float4 bb = *(const float4*)(b_emb + dm);
  float4 wp = *(const float4*)(w_pos + (size_t)l * DMOD + dm);
  float4 val;
  val.x = xs * we.x + bb.x + wp.x;
  val.y = xs * we.y + bb.y + wp.y;
  val.z = xs * we.z + bb.z + wp.z;
  val.w = xs * we.w + bb.w + wp.w;
  *(float4*)(h + e) = val;
  ushort4 hi4, lo4;
  hi4.x = f2b(val.x); lo4.x = f2b(val.x - b2f(hi4.x));
  hi4.y = f2b(val.y); lo4.y = f2b(val.y - b2f(hi4.y));
  hi4.z = f2b(val.z); lo4.z = f2b(val.z - b2f(hi4.z));
  hi4.w = f2b(val.w); lo4.w = f2b(val.w - b2f(hi4.w));
  *(ushort4*)(h_hi + e) = hi4;
  *(ushort4*)(h_lo + e) = lo4;
}

// ---------------- fused per-layer weight prep (one dispatch) ----------------
__global__ void prep_weights(const float* __restrict__ Wq, const float* __restrict__ Wk,
                             const float* __restrict__ Wv, const float* __restrict__ Wo,
                             const float* __restrict__ W1, const float* __restrict__ W2,
                             unsigned short* __restrict__ Wqk_hi, unsigned short* __restrict__ Wqk_lo,
                             unsigned short* __restrict__ Wv_b, unsigned short* __restrict__ Wo_b,
                             unsigned short* __restrict__ W1_b, unsigned short* __restrict__ W2_b) {
  const int Q4 = 65536;   // 262144/4
  int g = blockIdx.x * 256 + threadIdx.x;
  if (g < 2 * Q4) {
    const float* src = g < Q4 ? Wq : Wk;
    unsigned short* hi = Wqk_hi + (g < Q4 ? 0 : DMOD * DMOD);
    unsigned short* lo = Wqk_lo + (g < Q4 ? 0 : DMOD * DMOD);
    int off = (g < Q4 ? g : g - Q4) * 4;
    float4 v = *(const float4*)(src + off);
    ushort4 h4, l4;
    h4.x = f2b(v.x); l4.x = f2b(v.x - b2f(h4.x));
    h4.y = f2b(v.y); l4.y = f2b(v.y - b2f(h4.y));
    h4.z = f2b(v.z); l4.z = f2b(v.z - b2f(h4.z));
    h4.w = f2b(v.w); l4.w = f2b(v.w - b2f(h4.w));
    *(ushort4*)(hi + off) = h4;
    *(ushort4*)(lo + off) = l4;
    return;
  }
  const float* src;
  unsigned short* dst;
  int off;
  if (g < 3 * Q4)      { src = Wv; dst = Wv_b; off = (g - 2 * Q4) * 4; }
  else if (g < 4 * Q4) { src = Wo; dst = Wo_b; off = (g - 3 * Q4) * 4; }
  else if (g < 4 * Q4 + 262144) { src = W1; dst = W1_b; off = (g - 4 * Q4) * 4; }
  else                 { src = W2; dst = W2_b; off = (g - 4 * Q4 - 262144) * 4; }
  float4 v = *(const float4*)(src + off);
  ushort4 o;
  o.x = f2b(v.x); o.y = f2b(v.y); o.z = f2b(v.z); o.w = f2b(v.w);
  *(ushort4*)(dst + off) = o;
}

// ---------------- split-bf16 MFMA GEMM (3-pass hi/lo): C = A@W^T + [bq|bk] ----------------
__global__ __launch_bounds__(256) void gemm_mfma3(const unsigned short* __restrict__ Ah,
                                                  const unsigned short* __restrict__ Al,
                                                  const unsigned short* __restrict__ Bh,
                                                  const unsigned short* __restrict__ Bl,
                                                  const float* __restrict__ bq,
                                                  const float* __restrict__ bk,
                                                  float* __restrict__ C,
                                                  int M, int N, int K, int ldc) {
  __shared__ __align__(16) unsigned short AsH[128 * 64];
  __shared__ __align__(16) unsigned short AsL[128 * 64];
  __shared__ __align__(16) unsigned short BsH[128 * 64];
  __shared__ __align__(16) unsigned short BsL[128 * 64];
  int nwg = gridDim.x * gridDim.y;
  int flat = blockIdx.y * gridDim.x + blockIdx.x;
  int swz = (flat & 7) * (nwg >> 3) + (flat >> 3);
  int bxs = swz % gridDim.x, bys = swz / gridDim.x;
  int bm = bys * 128, bn = bxs * 128;
  int tid = threadIdx.x;
  int wave = tid >> 6, lane = tid & 63;
  int wr = wave >> 1, wc = wave & 1;
  int r16 = lane & 15, kq = lane >> 4;

  f32x4 acc[4][4];
  #pragma unroll
  for (int i = 0; i < 4; ++i)
    #pragma unroll
    for (int j = 0; j < 4; ++j) acc[i][j] = (f32x4){0.f, 0.f, 0.f, 0.f};

  for (int kt = 0; kt < K; kt += 64) {
    __syncthreads();
    #pragma unroll
    for (int i = 0; i < 4; ++i) {
      int c = i * 256 + tid;
      int row = c >> 3, kb = c & 7;
      size_t offA = (size_t)(bm + row) * K + kt + kb * 8;
      size_t offB = (size_t)(bn + row) * K + kt + kb * 8;
      uint4 vah = *(const uint4*)(Ah + offA);
      uint4 val = *(const uint4*)(Al + offA);
      uint4 vbh = *(const uint4*)(Bh + offB);
      uint4 vbl = *(const uint4*)(Bl + offB);
      int sw = ((row << 7) | (kb << 4)) ^ ((row & 7) << 4);
      *(uint4*)((char*)AsH + sw) = vah;
      *(uint4*)((char*)AsL + sw) = val;
      *(uint4*)((char*)BsH + sw) = vbh;
      *(uint4*)((char*)BsL + sw) = vbl;
    }
    __syncthreads();
    #pragma unroll
    for (int ks = 0; ks < 2; ++ks) {
      bf16x8 ah[4], al[4], bh[4], bl[4];
      #pragma unroll
      for (int mi = 0; mi < 4; ++mi) {
        int row = wr * 64 + mi * 16 + r16;
        int addr = ((row << 7) | (ks << 6) | (kq << 4)) ^ ((row & 7) << 4);
        ah[mi] = *(const bf16x8*)((const char*)AsH + addr);
        al[mi] = *(const bf16x8*)((const char*)AsL + addr);
      }
      #pragma unroll
      for (int ni = 0; ni < 4; ++ni) {
        int row = wc * 64 + ni * 16 + r16;
        int addr = ((row << 7) | (ks << 6) | (kq << 4)) ^ ((row & 7) << 4);
        bh[ni] = *(const bf16x8*)((const char*)BsH + addr);
        bl[ni] = *(const bf16x8*)((const char*)BsL + addr);
      }
      #pragma unroll
      for (int mi = 0; mi < 4; ++mi)
        #pragma unroll
        for (int ni = 0; ni < 4; ++ni) {
          acc[mi][ni] = __builtin_amdgcn_mfma_f32_16x16x32_bf16(ah[mi], bh[ni], acc[mi][ni], 0, 0, 0);
          acc[mi][ni] = __builtin_amdgcn_mfma_f32_16x16x32_bf16(ah[mi], bl[ni], acc[mi][ni], 0, 0, 0);
          acc[mi][ni] = __builtin_amdgcn_mfma_f32_16x16x32_bf16(al[mi], bh[ni], acc[mi][ni], 0, 0, 0);
        }
    }
  }
  int crow0 = bm + wr * 64 + (lane >> 4) * 4;
  int ccol0 = bn + wc * 64 + (lane & 15);
  #pragma unroll
  for (int mi = 0; mi < 4; ++mi) {
    #pragma unroll
    for (int ni = 0; ni < 4; ++ni) {
      int col = ccol0 + ni * 16;
      float bvv = col < 512 ? bq[col] : bk[col - 512];
      #pragma unroll
      for (int r = 0; r < 4; ++r) {
        int row = crow0 + mi * 16 + r;
        C[(size_t)row * ldc + col] = acc[mi][ni][r] + bvv;
      }
    }
  }
}

// ---------------- bf16 MFMA GEMM (single): C = A@W^T + bias, opt gelu ----------------
template<int ACT, int OUTBF>
__global__ __launch_bounds__(256) void gemm_mfma(const unsigned short* __restrict__ A,
                                                 const unsigned short* __restrict__ W,
                                                 const float* __restrict__ bias,
                                                 float* __restrict__ Cf,
                                                 unsigned short* __restrict__ Cb,
                                                 int M, int N, int K) {
  __shared__ __align__(16) unsigned short As[128 * 64];
  __shared__ __align__(16) unsigned short Bs[128 * 64];
  int nwg = gridDim.x * gridDim.y;
  int flat = blockIdx.y * gridDim.x + blockIdx.x;
  int swz = (flat & 7) * (nwg >> 3) + (flat >> 3);
  int bxs = swz % gridDim.x, bys = swz / gridDim.x;
  int bm = bys * 128, bn = bxs * 128;
  int tid = threadIdx.x;
  int wave = tid >> 6, lane = tid & 63;
  int wr = wave >> 1, wc = wave & 1;
  int r16 = lane & 15, kq = lane >> 4;

  f32x4 acc[4][4];
  #pragma unroll
  for (int i = 0; i < 4; ++i)
    #pragma unroll
    for (int j = 0; j < 4; ++j) acc[i][j] = (f32x4){0.f, 0.f, 0.f, 0.f};

  for (int kt = 0; kt < K; kt += 64) {
    __syncthreads();
    #pragma unroll
    for (int i = 0; i < 4; ++i) {
      int c = i * 256 + tid;
      int row = c >> 3, kb = c & 7;
      uint4 va = *(const uint4*)(A + (size_t)(bm + row) * K + kt + kb * 8);
      uint4 vb = *(const uint4*)(W + (size_t)(bn + row) * K + kt + kb * 8);
      int sw = ((row << 7) | (kb << 4)) ^ ((row & 7) << 4);
      *(uint4*)((char*)As + sw) = va;
      *(uint4*)((char*)Bs + sw) = vb;
    }
    __syncthreads();
    #pragma unroll
    for (int ks = 0; ks < 2; ++ks) {
      bf16x8 afr[4], bfr[4];
      #pragma unroll
      for (int mi = 0; mi < 4; ++mi) {
        int row = wr * 64 + mi * 16 + r16;
        int addr = ((row << 7) | (ks << 6) | (kq << 4)) ^ ((row & 7) << 4);
        afr[mi] = *(const bf16x8*)((const char*)As + addr);
      }
      #pragma unroll
      for (int ni = 0; ni < 4; ++ni) {
        int row = wc * 64 + ni * 16 + r16;
        int addr = ((row << 7) | (ks << 6) | (kq << 4)) ^ ((row & 7) << 4);
        bfr[ni] = *(const bf16x8*)((const char*)Bs + addr);
      }
      #pragma unroll
      for (int mi = 0; mi < 4; ++mi)
        #pragma unroll
        for (int ni = 0; ni < 4; ++ni)
          acc[mi][ni] = __builtin_amdgcn_mfma_f32_16x16x32_bf16(afr[mi], bfr[ni], acc[mi][ni], 0, 0, 0);
    }
  }
  int crow0 = bm + wr * 64 + (lane >> 4) * 4;
  int ccol0 = bn + wc * 64 + (lane & 15);
  #pragma unroll
  for (int mi = 0; mi < 4; ++mi) {
    #pragma unroll
    for (int ni = 0; ni < 4; ++ni) {
      int col = ccol0 + ni * 16;
      float bvv = bias[col];
      #pragma unroll
      for (int r = 0; r < 4; ++r) {
        int row = crow0 + mi * 16 + r;
        float v = acc[mi][ni][r] + bvv;
        if (ACT) {
          // gelu(tanh approx) = x * sigmoid(2y), y = 0.79788456(x + 0.044715 x^3)
          float x = v;
          float y2 = 1.5957691216057308f * (x + 0.044715f * x * x * x);
          v = x / (1.0f + __expf(-y2));
        }
        if (OUTBF) Cb[(size_t)row * N + col] = f2b(v);
        else       Cf[(size_t)row * N + col] = v;
      }
    }
  }
}

// ---------------- M measure: block per (bh), XOR-swizzled float4 K in LDS ----------------
__global__ __launch_bounds__(512) void m2_kernel(const float* __restrict__ QK,
                                                 const int* __restrict__ idx,
                                                 float* __restrict__ Mout) {
  int bh = blockIdx.x;
  int bv = bh >> 3, head = bh & 7;
  int tid = threadIdx.x;                 // 0..511, one q-row each
  __shared__ float Ks[512 * 64];         // 128 KB, word(l,db) = l*64 + ((db^(l&15))<<2)
  const float* base = QK + (size_t)bv * (SEQL * QKS);
  for (int c = tid; c < 512 * 16; c += 512) {
    int l = c >> 4, db = c & 15;
    float4 v = *(const float4*)(base + (size_t)l * QKS + 512 + head * 64 + db * 4);
    *(float4*)(Ks + l * 64 + ((db ^ (l & 15)) << 2)) = v;
  }
  float q[64];
  const float* qp = base + (size_t)tid * QKS + head * 64;
  #pragma unroll
  for (int d4 = 0; d4 < 64; d4 += 4) {
    float4 qv = *(const float4*)(qp + d4);
    q[d4 + 0] = qv.x; q[d4 + 1] = qv.y; q[d4 + 2] = qv.z; q[d4 + 3] = qv.w;
  }
  __syncthreads();
  const int* ip = idx + tid * NSAMP;
  float mx = -INFINITY, sm = 0.f;
  for (int u = 0; u < NSAMP; ++u) {
    int kidx = ip[u];
    const float* kr = Ks + kidx * 64;
    int x = kidx & 15;
    float s = 0.f;
    #pragma unroll
    for (int db = 0; db < 16; ++db) {
      float4 kv = *(const float4*)(kr + ((db ^ x) << 2));
      s += q[db * 4 + 0] * kv.x + q[db * 4 + 1] * kv.y
         + q[db * 4 + 2] * kv.z + q[db * 4 + 3] * kv.w;
    }
    mx = fmaxf(mx, s);
    sm += s;
  }
  Mout[(size_t)bh * SEQL + tid] = mx - sm * (1.0f / 512.0f);
}

// ---------------- top-k (k=35) ----------------
__global__ __launch_bounds__(256) void topk_kernel(const float* __restrict__ Mv,
                                                   int* __restrict__ top) {
  int bh = blockIdx.x;
  int tid = threadIdx.x;
  __shared__ float vals[512];
  __shared__ float rv[256];
  __shared__ int ri[256];
  vals[tid]       = Mv[(size_t)bh * SEQL + tid];
  vals[tid + 256] = Mv[(size_t)bh * SEQL + tid + 256];
  __syncthreads();
  for (int t = 0; t < NSAMP; ++t) {
    float v0 = vals[tid], v1 = vals[tid + 256];
    float bvv; int bii;
    if (v0 >= v1) { bvv = v0; bii = tid; } else { bvv = v1; bii = tid + 256; }
    rv[tid] = bvv; ri[tid] = bii;
    __syncthreads();
    for (int s = 128; s > 0; s >>= 1) {
      if (tid < s) {
        float ov = rv[tid + s]; int oi = ri[tid + s];
        if (ov > rv[tid] || (ov == rv[tid] && oi < ri[tid])) { rv[tid] = ov; ri[tid] = oi; }
      }
      __syncthreads();
    }
    if (tid == 0) { top[bh * NSAMP + t] = ri[0]; vals[ri[0]] = -INFINITY; }
    __syncthreads();
  }
}

// ---------------- mean of V (bf16 V, coalesced: block per bv) ----------------
__global__ __launch_bounds__(256) void vmean_kernel(const unsigned short* __restrict__ Vb,
                                                    float* __restrict__ vmean) {
  int bv = blockIdx.x;                 // 0..27
  int t = threadIdx.x;                 // cols 2t, 2t+1
  const unsigned short* vb = Vb + (size_t)bv * (SEQL * DMOD) + t * 2;
  float s0 = 0.f, s1 = 0.f;
  #pragma unroll 4
  for (int l = 0; l < SEQL; ++l) {
    unsigned u = *(const unsigned*)(vb + (size_t)l * DMOD);
    s0 += b2f((unsigned short)(u & 0xffffu));
    s1 += b2f((unsigned short)(u >> 16));
  }
  vmean[bv * DMOD + t * 2]     = s0 * (1.0f / 512.0f);
  vmean[bv * DMOD + t * 2 + 1] = s1 * (1.0f / 512.0f);
}

// ---------------- ctx = broadcast vmean (bf16 out, vectorized) ----------------
__global__ void ctx_fill_kernel(const float* __restrict__ vmean,
                                unsigned short* __restrict__ ctxb) {
  size_t i = (size_t)blockIdx.x * 256 + threadIdx.x;
  if (i >= (size_t)(SBIG / 4)) return;
  size_t e = i * 4;
  int dm = (int)(e & 511);
  int bv = (int)(e >> 18);
  float4 vm = *(const float4*)(vmean + bv * DMOD + dm);
  ushort4 o;
  o.x = f2b(vm.x); o.y = f2b(vm.y); o.z = f2b(vm.z); o.w = f2b(vm.w);
  *(ushort4*)(ctxb + e) = o;
}

// ---------------- MFMA attention for selected queries: block per (bh) ----------------
__global__ __launch_bounds__(256) void attn2_kernel(const float* __restrict__ QK,
                                                    const unsigned short* __restrict__ Vb,
                                                    const int* __restrict__ top,
                                                    unsigned short* __restrict__ ctxb) {
  __shared__ __align__(16) unsigned short KV[512 * 64];
  __shared__ __align__(16) unsigned short P[48 * 512];
  __shared__ __align__(16) unsigned short Qs[48 * 64];
  __shared__ int topi[NSAMP];
  int bh = blockIdx.x;
  int bv = bh >> 3, head = bh & 7;
  int tid = threadIdx.x;
  int wv = tid >> 6, lane = tid & 63;
  int r16 = lane & 15, kq = lane >> 4;
  const float* base = QK + (size_t)bv * (SEQL * QKS);
  const unsigned short* vbase = Vb + (size_t)bv * (SEQL * DMOD) + head * 64;

  if (tid < NSAMP) topi[tid] = top[bh * NSAMP + tid];
  __syncthreads();

  for (int c = tid; c < NSAMP * 16; c += 256) {
    int u = c >> 4, dq = c & 15;
    float4 q4 = *(const float4*)(base + (size_t)topi[u] * QKS + head * 64 + dq * 4);
    ushort4 o;
    o.x = f2b(q4.x * 0.125f); o.y = f2b(q4.y * 0.125f);
    o.z = f2b(q4.z * 0.125f); o.w = f2b(q4.w * 0.125f);
    int byte = ((u << 7) | (dq << 3)) ^ ((u & 7) << 4);
    *(ushort4*)((char*)Qs + byte) = o;
  }
  for (int c = tid; c < 512 * 16; c += 256) {
    int l = c >> 4, dq = c & 15;
    float4 k4 = *(const float4*)(base + (size_t)l * QKS + 512 + head * 64 + dq * 4);
    ushort4 o;
    o.x = f2b(k4.x); o.y = f2b(k4.y); o.z = f2b(k4.z); o.w = f2b(k4.w);
    int byte = ((l << 7) | (dq << 3)) ^ ((l & 7) << 4);
    *(ushort4*)((char*)KV + byte) = o;
  }
  __syncthreads();

  // QK^T: scores[48][512]
  {
    f32x4 acc[3][8];
    #pragma unroll
    for (int m = 0; m < 3; ++m)
      #pragma unroll
      for (int j = 0; j < 8; ++j) acc[m][j] = (f32x4){0.f, 0.f, 0.f, 0.f};
    bf16x8 afr[3][2];
    #pragma unroll
    for (int m = 0; m < 3; ++m)
      #pragma unroll
      for (int ks = 0; ks < 2; ++ks) {
        int row = m * 16 + r16;
        int addr = ((row << 7) | (ks << 6) | (kq << 4)) ^ ((row & 7) << 4);
        afr[m][ks] = *(const bf16x8*)((const char*)Qs + addr);
      }
    #pragma unroll
    for (int j = 0; j < 8; ++j) {
      int nrow = (wv * 8 + j) * 16 + r16;
      #pragma unroll
      for (int ks = 0; ks < 2; ++ks) {
        int addr = ((nrow << 7) | (ks << 6) | (kq << 4)) ^ ((nrow & 7) << 4);
        bf16x8 bfr = *(const bf16x8*)((const char*)KV + addr);
        #pragma unroll
        for (int m = 0; m < 3; ++m)
          acc[m][j] = __builtin_amdgcn_mfma_f32_16x16x32_bf16(afr[m][ks], bfr, acc[m][j], 0, 0, 0);
      }
    }
    #pragma unroll
    for (int m = 0; m < 3; ++m)
      #pragma unroll
      for (int j = 0; j < 8; ++j) {
        int l = (wv * 8 + j) * 16 + r16;
        #pragma unroll
        for (int r = 0; r < 4; ++r) {
          int u = m * 16 + kq * 4 + r;
          int byte = ((u << 10) | (l << 1)) ^ ((u & 7) << 4);
          *(unsigned short*)((char*)P + byte) = f2b(acc[m][j][r]);
        }
      }
  }
  __syncthreads();

  // stage V^T into KV region (K dead) from bf16 V
  for (int c = tid; c < 512 * 8; c += 256) {
    int l = c >> 3, dq = c & 7;
    bf16x8 v8 = *(const bf16x8*)(vbase + (size_t)l * DMOD + dq * 8);
    #pragma unroll
    for (int j = 0; j < 8; ++j) {
      int d = dq * 8 + j;
      int byte = ((d << 10) | (l << 1)) ^ ((d & 7) << 4);
      *(unsigned short*)((char*)KV + byte) = (unsigned short)v8[j];
    }
  }
  // softmax on P rows
  for (int u = wv; u < NSAMP; u += 4) {
    int byte = ((u << 10) | (lane << 4)) ^ ((u & 7) << 4);
    bf16x8 sv = *(const bf16x8*)((const char*)P + byte);
    float s[8];
    #pragma unroll
    for (int j = 0; j < 8; ++j) s[j] = b2f((unsigned short)sv[j]);
    float mx = s[0];
    #pragma unroll
    for (int j = 1; j < 8; ++j) mx = fmaxf(mx, s[j]);
    #pragma unroll
    for (int off = 32; off > 0; off >>= 1) mx = fmaxf(mx, __shfl_xor(mx, off));
    float e[8], sm = 0.f;
    #pragma unroll
    for (int j = 0; j < 8; ++j) { e[j] = __expf(s[j] - mx); sm += e[j]; }
    #pragma unroll
    for (int off = 32; off > 0; off >>= 1) sm += __shfl_xor(sm, off);
    float inv = 1.0f / sm;
    bf16x8 pv;
    #pragma unroll
    for (int j = 0; j < 8; ++j) pv[j] = (short)f2b(e[j] * inv);
    *(bf16x8*)((char*)P + byte) = pv;
  }
  __syncthreads();

  // PV: ctx[48][64] = P @ V
  {
    f32x4 acc2[3];
    #pragma unroll
    for (int m = 0; m < 3; ++m) acc2[m] = (f32x4){0.f, 0.f, 0.f, 0.f};
    for (int kst = 0; kst < 16; ++kst) {
      int vrow = wv * 16 + r16;
      int baddr = ((vrow << 10) | (kst << 6) | (kq << 4)) ^ ((vrow & 7) << 4);
      bf16x8 bfr = *(const bf16x8*)((const char*)KV + baddr);
      #pragma unroll
      for (int m = 0; m < 3; ++m) {
        int prow = m * 16 + r16;
        int aaddr = ((prow << 10) | (kst << 6) | (kq << 4)) ^ ((prow & 7) << 4);
        bf16x8 afr2 = *(const bf16x8*)((const char*)P + aaddr);
        acc2[m] = __builtin_amdgcn_mfma_f32_16x16x32_bf16(afr2, bfr, acc2[m], 0, 0, 0);
      }
    }
    int d = wv * 16 + r16;
    #pragma unroll
    for (int m = 0; m < 3; ++m)
      #pragma unroll
      for (int r = 0; r < 4; ++r) {
        int u = m * 16 + kq * 4 + r;
        if (u < NSAMP) {
          size_t off = (size_t)bv * (SEQL * DMOD) + (size_t)topi[u] * DMOD + head * 64 + d;
          ctxb[off] = f2b(acc2[m][r]);
        }
      }
  }
}

// ---------------- residual add + layernorm (vectorized: 2 rows/block) ----------------
template<int BMODE, int OUT>
__global__ __launch_bounds__(256) void add_ln(const float* __restrict__ a,
                                              const unsigned short* __restrict__ b,
                                              const float* __restrict__ g,
                                              const float* __restrict__ be,
                                              float* __restrict__ out,
                                              unsigned short* __restrict__ outb,
                                              unsigned short* __restrict__ outh,
                                              unsigned short* __restrict__ outl) {
  int row = blockIdx.x * 2 + (threadIdx.x >> 7);
  int t = threadIdx.x & 127;
  int wave = threadIdx.x >> 6;
  int lane = threadIdx.x & 63;
  size_t base = (size_t)row * DMOD + t * 4;
  float4 x = *(const float4*)(a + base);
  if (BMODE == 2) {
    ushort4 r4 = *(const ushort4*)(b + base);
    x.x += b2f(r4.x); x.y += b2f(r4.y); x.z += b2f(r4.z); x.w += b2f(r4.w);
  }
  float s1 = x.x + x.y + x.z + x.w;
  float s2 = x.x * x.x + x.y * x.y + x.z * x.z + x.w * x.w;
  #pragma unroll
  for (int off = 32; off > 0; off >>= 1) {
    s1 += __shfl_xor(s1, off);
    s2 += __shfl_xor(s2, off);
  }
  __shared__ float sh[8];
  if (lane == 0) { sh[wave * 2] = s1; sh[wave * 2 + 1] = s2; }
  __syncthreads();
  int mate = wave ^ 1;
  s1 += sh[mate * 2];
  s2 += sh[mate * 2 + 1];
  float mu = s1 * (1.0f / 512.0f);
  float var = s2 * (1.0f / 512.0f) - mu * mu;
  float rstd = rsqrtf(var + 1e-5f);
  float4 gg = *(const float4*)(g + t * 4);
  float4 bb = *(const float4*)(be + t * 4);
  float4 o;
  o.x = (x.x - mu) * rstd * gg.x + bb.x;
  o.y = (x.y - mu) * rstd * gg.y + bb.y;
  o.z = (x.z - mu) * rstd * gg.z + bb.z;
  o.w = (x.w - mu) * rstd * gg.w + bb.w;
  *(float4*)(out + base) = o;
  if (OUT == 1) {
    ushort4 ob;
    ob.x = f2b(o.x); ob.y = f2b(o.y); ob.z = f2b(o.z); ob.w = f2b(o.w);
    *(ushort4*)(outb + base) = ob;
  }
  if (OUT == 2) {
    ushort4 hi4, lo4;
    hi4.x = f2b(o.x); lo4.x = f2b(o.x - b2f(hi4.x));
    hi4.y = f2b(o.y); lo4.y = f2b(o.y - b2f(hi4.y));
    hi4.z = f2b(o.z); lo4.z = f2b(o.z - b2f(hi4.z));
    hi4.w = f2b(o.w); lo4.w = f2b(o.w - b2f(hi4.w));
    *(ushort4*)(outh + base) = hi4;
    *(ushort4*)(outl + base) = lo4;
  }
}

// ---------------- head via MFMA: partial[blk*4+w][2688], K-chunk 512/block ----------------
__global__ __launch_bounds__(256) void head_partial_mfma(const unsigned short* __restrict__ hbf,
                                                         const float* __restrict__ Wh,
                                                         float* __restrict__ partial) {
  __shared__ __align__(16) unsigned short Hs[32 * 512];   // 32 KB
  __shared__ __align__(16) unsigned short Ws[96 * 512];   // 96 KB
  int blk = blockIdx.x;            // 0..511
  int k0 = blk * 512;
  int tid = threadIdx.x;
  int wv = tid >> 6, lane = tid & 63;
  int r16 = lane & 15, kq = lane >> 4;

  for (int c = tid; c < 32 * 64; c += 256) {
    int row = c >> 6, col8 = c & 63;
    int src = row < 28 ? row : 0;
    bf16x8 v = *(const bf16x8*)(hbf + (size_t)src * 262144 + k0 + col8 * 8);
    int byte = ((row << 10) | (col8 << 4)) ^ ((row & 7) << 4);
    *(bf16x8*)((char*)Hs + byte) = v;
  }
  for (int c = tid; c < 96 * 64; c += 256) {
    int row = c >> 6, col8 = c & 63;
    const float* src = Wh + (size_t)row * 262144 + k0 + col8 * 8;
    float4 va = *(const float4*)(src);
    float4 vb = *(const float4*)(src + 4);
    bf16x8 o8;
    o8[0] = (short)f2b(va.x); o8[1] = (short)f2b(va.y);
    o8[2] = (short)f2b(va.z); o8[3] = (short)f2b(va.w);
    o8[4] = (short)f2b(vb.x); o8[5] = (short)f2b(vb.y);
    o8[6] = (short)f2b(vb.z); o8[7] = (short)f2b(vb.w);
    int byte = ((row << 10) | (col8 << 4)) ^ ((row & 7) << 4);
    *(bf16x8*)((char*)Ws + byte) = o8;
  }
  __syncthreads();

  f32x4 acc[2][6];
  #pragma unroll
  for (int mt = 0; mt < 2; ++mt)
    #pragma unroll
    for (int nt = 0; nt < 6; ++nt) acc[mt][nt] = (f32x4){0.f, 0.f, 0.f, 0.f};

  #pragma unroll
  for (int kk = 0; kk < 4; ++kk) {
    int kfrag = wv * 4 + kk;     // k = kfrag*32 + kq*8
    bf16x8 afr[2];
    #pragma unroll
    for (int mt = 0; mt < 2; ++mt) {
      int row = mt * 16 + r16;
      int byte = ((row << 10) | (kfrag << 6) | (kq << 4)) ^ ((row & 7) << 4);
      afr[mt] = *(const bf16x8*)((const char*)Hs + byte);
    }
    #pragma unroll
    for (int nt = 0; nt < 6; ++nt) {
      int row = nt * 16 + r16;
      int byte = ((row << 10) | (kfrag << 6) | (kq << 4)) ^ ((row & 7) << 4);
      bf16x8 bfr = *(const bf16x8*)((const char*)Ws + byte);
      #pragma unroll
      for (int mt = 0; mt < 2; ++mt)
        acc[mt][nt] = __builtin_amdgcn_mfma_f32_16x16x32_bf16(afr[mt], bfr, acc[mt][nt], 0, 0, 0);
    }
  }
  size_t prow = (size_t)(blk * 4 + wv) * 2688;
  #pragma unroll
  for (int mt = 0; mt < 2; ++mt)
    #pragma unroll
    for (int nt = 0; nt < 6; ++nt)
      #pragma unroll
      for (int r = 0; r < 4; ++r) {
        int m = mt * 16 + kq * 4 + r;
        int n = nt * 16 + r16;
        if (m < 28) partial[prow + m * 96 + n] = acc[mt][nt][r];
      }
}

__global__ __launch_bounds__(256) void head_reduce(const float* __restrict__ partial,
                                                   const float* __restrict__ bh_,
                                                   float* __restrict__ out) {
  int o = blockIdx.x;              // 0..2687 = m*96+p
  int tid = threadIdx.x;
  float s = 0.f;
  for (int b = tid; b < 2048; b += 256) s += partial[(size_t)b * 2688 + o];
  __shared__ float red[256];
  red[tid] = s;
  __syncthreads();
  for (int st = 128; st > 0; st >>= 1) {
    if (tid < st) red[tid] += red[tid + st];
    __syncthreads();
  }
  if (tid == 0) {
    int m = o / 96, p = o % 96;
    int b = m / NVARS, v = m % NVARS;
    out[(size_t)b * (NPRED * NVARS) + (size_t)p * NVARS + v] = red[0] + bh_[p];
  }
}

extern "C" void kernel_launch(void* const* d_in, const int* in_sizes, int n_in,
                              void* d_out, int out_size, void* d_ws, size_t ws_size,
                              hipStream_t stream) {
  const float* x_enc = (const float*)d_in[0];
  const float* w_emb = (const float*)d_in[1];
  const float* b_emb = (const float*)d_in[2];
  const float* w_pos = (const float*)d_in[3];
  const float* Wq = (const float*)d_in[4];
  const float* bq = (const float*)d_in[5];
  const float* Wk = (const float*)d_in[6];
  const float* bk = (const float*)d_in[7];
  const float* Wv = (const float*)d_in[8];
  const float* bv_ = (const float*)d_in[9];
  const float* Wo = (const float*)d_in[10];
  const float* bo = (const float*)d_in[11];
  const float* W1 = (const float*)d_in[12];
  const float* b1 = (const float*)d_in[13];
  const float* W2 = (const float*)d_in[14];
  const float* b2 = (const float*)d_in[15];
  const float* g1 = (const float*)d_in[16];
  const float* be1 = (const float*)d_in[17];
  const float* g2 = (const float*)d_in[18];
  const float* be2 = (const float*)d_in[19];
  const float* gF = (const float*)d_in[20];
  const float* bF = (const float*)d_in[21];
  const float* Wh = (const float*)d_in[22];
  const float* bh_ = (const float*)d_in[23];
  float* out = (float*)d_out;

  const size_t S = (size_t)SBIG;
  const size_t SB = S * 4;                    // 29,360,128 B
  char* ws = (char*)d_ws;
  float* h    = (float*)(ws);                 // [0, SB)
  float* QKb  = (float*)(ws + SB);            // [SB, 3SB): [14336][1024] fp32
  unsigned short* Vb   = (unsigned short*)(ws + 3 * SB);            // 14.7 MB
  unsigned short* Ob_b = (unsigned short*)(ws + 3 * SB + SB / 2);   // 14.7 MB
  // weight scratch region [4SB, 5SB)
  unsigned short* Wqk_hi = (unsigned short*)(ws + 4 * SB);                  // 1 MB
  unsigned short* Wqk_lo = (unsigned short*)(ws + 4 * SB + 0x100000);       // 1 MB
  unsigned short* Wv_b = (unsigned short*)(ws + 4 * SB + 0x200000);         // 0.5 MB
  unsigned short* Wo_b = (unsigned short*)(ws + 4 * SB + 0x280000);         // 0.5 MB
  unsigned short* W1_b = (unsigned short*)(ws + 4 * SB + 0x300000);         // 2 MB
  unsigned short* W2_b = (unsigned short*)(ws + 4 * SB + 0x500000);         // 2 MB
  unsigned short* h_hi = (unsigned short*)(ws + 5 * SB);           // SB/2
  unsigned short* h_lo = (unsigned short*)(ws + 5 * SB + SB / 2);  // SB/2
  // phase aliases:
  unsigned short* CTXb = h_hi;                 // after QK+V gemms consumed h_hi
  unsigned short* h_bf = h_lo;                 // after QK gemm consumed h_lo
  unsigned short* FFNb = (unsigned short*)QKb; // after attn consumed QK
  float* partial = QKb;                        // head phase (22 MB <= 2SB)
  int*   idx = (int*)(ws + 6 * SB);                        // 70KB
  float* Mv  = (float*)(ws + 6 * SB + 0x20000);            // 448KB
  int*   top = (int*)(ws + 6 * SB + 0xA0000);              // 31KB
  float* vmean = (float*)(ws + 6 * SB + 0xB0000);          // 56KB
  if (ws_size < 6 * SB + 0xC0000) return;

  dim3 b256(256);
  int gVec = (int)(S / 4 / 256);   // 7168

  embed_kernel<<<gVec, b256, 0, stream>>>(x_enc, w_emb, b_emb, w_pos, h, h_hi, h_lo);

  for (int l = 0; l < 2; ++l) {
    const float* Wql = Wq + (size_t)l * DMOD * DMOD;
    const float* Wkl = Wk + (size_t)l * DMOD * DMOD;
    const float* Wvl = Wv + (size_t)l * DMOD * DMOD;
    const float* Wol = Wo + (size_t)l * DMOD * DMOD;
    const float* W1l = W1 + (size_t)l * DFFN * DMOD;
    const float* W2l = W2 + (size_t)l * DMOD * DFFN;

    prep_weights<<<3072, b256, 0, stream>>>(Wql, Wkl, Wvl, Wol, W1l, W2l,
                                            Wqk_hi, Wqk_lo, Wv_b, Wo_b, W1_b, W2_b);

    dim3 gqk(QKS / 128, NROWS / 128);
    gemm_mfma3<<<gqk, b256, 0, stream>>>(h_hi, h_lo, Wqk_hi, Wqk_lo,
                                         bq + l * DMOD, bk + l * DMOD,
                                         QKb, NROWS, QKS, DMOD, QKS);
    dim3 gv(DMOD / 128, NROWS / 128);
    gemm_mfma<0, 1><<<gv, b256, 0, stream>>>(h_hi, Wv_b, bv_ + l * DMOD,
                                             (float*)0, Vb, NROWS, DMOD, DMOD);

    make_idx_kernel<<<(SEQL * NSAMP + 255) / 256, b256, 0, stream>>>(l, idx);
    m2_kernel<<<NBH, dim3(512), 0, stream>>>(QKb, idx, Mv);
    topk_kernel<<<NBH, b256, 0, stream>>>(Mv, top);
    vmean_kernel<<<NBV, b256, 0, stream>>>(Vb, vmean);
    ctx_fill_kernel<<<gVec, b256, 0, stream>>>(vmean, CTXb);
    attn2_kernel<<<NBH, b256, 0, stream>>>(QKb, Vb, top, CTXb);

    dim3 go(DMOD / 128, NROWS / 128);
    gemm_mfma<0, 1><<<go, b256, 0, stream>>>(CTXb, Wo_b, bo + l * DMOD,
                                             (float*)0, Ob_b, NROWS, DMOD, DMOD);
    add_ln<2, 1><<<NROWS / 2, b256, 0, stream>>>(h, Ob_b, g1 + l * DMOD, be1 + l * DMOD,
                                                 h, h_bf, (unsigned short*)0, (unsigned short*)0);

    dim3 gf1(DFFN / 128, NROWS / 128);
    gemm_mfma<1, 1><<<gf1, b256, 0, stream>>>(h_bf, W1_b, b1 + l * DFFN,
                                              (float*)0, FFNb, NROWS, DFFN, DMOD);
    dim3 gf2(DMOD / 128, NROWS / 128);
    gemm_mfma<0, 1><<<gf2, b256, 0, stream>>>(FFNb, W2_b, b2 + l * DMOD,
                                              (float*)0, Ob_b, NROWS, DMOD, DFFN);
    if (l == 0) {
      add_ln<2, 2><<<NROWS / 2, b256, 0, stream>>>(h, Ob_b, g2 + l * DMOD, be2 + l * DMOD,
                                                   h, (unsigned short*)0, h_hi, h_lo);
    } else {
      add_ln<2, 0><<<NROWS / 2, b256, 0, stream>>>(h, Ob_b, g2 + l * DMOD, be2 + l * DMOD,
                                                   h, (unsigned short*)0, (unsigned short*)0, (unsigned short*)0);
    }
  }

  add_ln<0, 1><<<NROWS / 2, b256, 0, stream>>>(h, (const unsigned short*)0, gF, bF,
                                               h, h_bf, (unsigned short*)0, (unsigned short*)0);
  head_partial_mfma<<<512, b256, 0, stream>>>(h_bf, Wh, partial);
  head_reduce<<<NBV * NPRED, b256, 0, stream>>>(partial, bh_, out);
}

// Round 8
// 779.652 us; speedup vs baseline: 7.2913x; 1.0349x over previous
//
#include <hip/hip_runtime.h>
#include <math.h>

#define SEQL 512
#define DMOD 512
#define NHEAD 8
#define DHEAD 64
#define DFFN 2048
#define NBATCH 4
#define NVARS 7
#define NBV 28          // NBATCH*NVARS
#define NBH 224         // NBV*NHEAD
#define NROWS 14336     // NBV*SEQL
#define NSAMP 35        // U_part = u = 35
#define NPRED 96
#define SBIG 7340032    // NBV*SEQL*DMOD floats
#define QKS 1024        // fused QK row stride

typedef short bf16x8 __attribute__((ext_vector_type(8)));
typedef float f32x4 __attribute__((ext_vector_type(4)));

#define GLDS(gptr, lptr) \
  __builtin_amdgcn_global_load_lds((const __attribute__((address_space(1))) void*)(gptr), \
                                   (__attribute__((address_space(3))) void*)(lptr), 16, 0, 0)

__device__ inline unsigned short f2b(float f) {
  unsigned u = __builtin_bit_cast(unsigned, f);
  unsigned r = (u + 0x7FFFu + ((u >> 16) & 1u)) >> 16;
  return (unsigned short)r;
}
__device__ inline float b2f(unsigned short h) {
  return __builtin_bit_cast(float, (unsigned)h << 16);
}

// ---------------- threefry2x32 (matches jax._src.prng) ----------------
__device__ inline void threefry2x32(unsigned k0, unsigned k1,
                                    unsigned x0, unsigned x1,
                                    unsigned &o0, unsigned &o1) {
  unsigned ks2 = k0 ^ k1 ^ 0x1BD11BDAu;
  unsigned ks[3] = {k0, k1, ks2};
  x0 += k0; x1 += k1;
  const unsigned rot[2][4] = {{13u,15u,26u,6u},{17u,29u,16u,24u}};
  #pragma unroll
  for (int i = 0; i < 5; ++i) {
    #pragma unroll
    for (int j = 0; j < 4; ++j) {
      unsigned r = rot[i & 1][j];
      x0 += x1;
      x1 = (x1 << r) | (x1 >> (32u - r));
      x1 ^= x0;
    }
    x0 += ks[(i + 1) % 3];
    x1 += ks[(i + 2) % 3] + (unsigned)(i + 1);
  }
  o0 = x0; o1 = x1;
}

__global__ void make_idx_kernel(int layer, int* idx) {
  int i = blockIdx.x * 256 + threadIdx.x;
  if (i >= SEQL * NSAMP) return;
  unsigned kl0, kl1, o0, o1;
  threefry2x32(0u, 42u, 0u, (unsigned)layer, kl0, kl1);
  threefry2x32(kl0, kl1, (unsigned)i, (unsigned)(SEQL * NSAMP + i), o0, o1);
  idx[i] = (int)(o1 & 511u);
}

// ---------------- embedding (vectorized, fused hi/lo split) ----------------
__global__ void embed_kernel(const float* __restrict__ x_enc,
                             const float* __restrict__ w_emb,
                             const float* __restrict__ b_emb,
                             const float* __restrict__ w_pos,
                             float* __restrict__ h,
                             unsigned short* __restrict__ h_hi,
                             unsigned short* __restrict__ h_lo) {
  size_t i = (size_t)blockIdx.x * 256 + threadIdx.x;
  if (i >= (size_t)(SBIG / 4)) return;
  size_t e = i * 4;
  int dm = (int)(e & 511);
  int l  = (int)((e >> 9) & 511);
  int bv = (int)(e >> 18);
  int b = bv / NVARS, v = bv % NVARS;
  float xs = x_enc[((size_t)b * SEQL + l) * NVARS + v];
  float4 we = *(const float4*)(w_emb + dm);
  float4 bb = *(const float4*)(b_emb + dm);
  float4 wp = *(const float4*)(w_pos + (size_t)l * DMOD + dm);
  float4 val;
  val.x = xs * we.x + bb.x + wp.x;
  val.y = xs * we.y + bb.y + wp.y;
  val.z = xs * we.z + bb.z + wp.z;
  val.w = xs * we.w + bb.w + wp.w;
  *(float4*)(h + e) = val;
  ushort4 hi4, lo4;
  hi4.x = f2b(val.x); lo4.x = f2b(val.x - b2f(hi4.x));
  hi4.y = f2b(val.y); lo4.y = f2b(val.y - b2f(hi4.y));
  hi4.z = f2b(val.z); lo4.z = f2b(val.z - b2f(hi4.z));
  hi4.w = f2b(val.w); lo4.w = f2b(val.w - b2f(hi4.w));
  *(ushort4*)(h_hi + e) = hi4;
  *(ushort4*)(h_lo + e) = lo4;
}

// ---------------- fused per-layer weight prep (one dispatch) ----------------
__global__ void prep_weights(const float* __restrict__ Wq, const float* __restrict__ Wk,
                             const float* __restrict__ Wv, const float* __restrict__ Wo,
                             const float* __restrict__ W1, const float* __restrict__ W2,
                             unsigned short* __restrict__ Wqk_hi, unsigned short* __restrict__ Wqk_lo,
                             unsigned short* __restrict__ Wv_b, unsigned short* __restrict__ Wo_b,
                             unsigned short* __restrict__ W1_b, unsigned short* __restrict__ W2_b) {
  const int Q4 = 65536;   // 262144/4
  int g = blockIdx.x * 256 + threadIdx.x;
  if (g < 2 * Q4) {
    const float* src = g < Q4 ? Wq : Wk;
    unsigned short* hi = Wqk_hi + (g < Q4 ? 0 : DMOD * DMOD);
    unsigned short* lo = Wqk_lo + (g < Q4 ? 0 : DMOD * DMOD);
    int off = (g < Q4 ? g : g - Q4) * 4;
    float4 v = *(const float4*)(src + off);
    ushort4 h4, l4;
    h4.x = f2b(v.x); l4.x = f2b(v.x - b2f(h4.x));
    h4.y = f2b(v.y); l4.y = f2b(v.y - b2f(h4.y));
    h4.z = f2b(v.z); l4.z = f2b(v.z - b2f(h4.z));
    h4.w = f2b(v.w); l4.w = f2b(v.w - b2f(h4.w));
    *(ushort4*)(hi + off) = h4;
    *(ushort4*)(lo + off) = l4;
    return;
  }
  const float* src;
  unsigned short* dst;
  int off;
  if (g < 3 * Q4)      { src = Wv; dst = Wv_b; off = (g - 2 * Q4) * 4; }
  else if (g < 4 * Q4) { src = Wo; dst = Wo_b; off = (g - 3 * Q4) * 4; }
  else if (g < 4 * Q4 + 262144) { src = W1; dst = W1_b; off = (g - 4 * Q4) * 4; }
  else                 { src = W2; dst = W2_b; off = (g - 4 * Q4 - 262144) * 4; }
  float4 v = *(const float4*)(src + off);
  ushort4 o;
  o.x = f2b(v.x); o.y = f2b(v.y); o.z = f2b(v.z); o.w = f2b(v.w);
  *(ushort4*)(dst + off) = o;
}

// ---------------- split-bf16 MFMA GEMM (3-pass hi/lo): C = A@W^T + [bq|bk] ----------------
// staging via global_load_lds w=16, linear LDS dest + pre-swizzled global source
__global__ __launch_bounds__(256) void gemm_mfma3(const unsigned short* __restrict__ Ah,
                                                  const unsigned short* __restrict__ Al,
                                                  const unsigned short* __restrict__ Bh,
                                                  const unsigned short* __restrict__ Bl,
                                                  const float* __restrict__ bq,
                                                  const float* __restrict__ bk,
                                                  float* __restrict__ C,
                                                  int M, int N, int K, int ldc) {
  __shared__ __align__(16) unsigned short AsH[128 * 64];
  __shared__ __align__(16) unsigned short AsL[128 * 64];
  __shared__ __align__(16) unsigned short BsH[128 * 64];
  __shared__ __align__(16) unsigned short BsL[128 * 64];
  int nwg = gridDim.x * gridDim.y;
  int flat = blockIdx.y * gridDim.x + blockIdx.x;
  int swz = (flat & 7) * (nwg >> 3) + (flat >> 3);
  int bxs = swz % gridDim.x, bys = swz / gridDim.x;
  int bm = bys * 128, bn = bxs * 128;
  int tid = threadIdx.x;
  int wave = tid >> 6, lane = tid & 63;
  int wr = wave >> 1, wc = wave & 1;
  int r16 = lane & 15, kq = lane >> 4;

  f32x4 acc[4][4];
  #pragma unroll
  for (int i = 0; i < 4; ++i)
    #pragma unroll
    for (int j = 0; j < 4; ++j) acc[i][j] = (f32x4){0.f, 0.f, 0.f, 0.f};

  for (int kt = 0; kt < K; kt += 64) {
    __syncthreads();
    #pragma unroll
    for (int i = 0; i < 4; ++i) {
      int c = i * 256 + tid;
      int row = c >> 3, kb = c & 7;
      int kbs = kb ^ (row & 7);             // pre-swizzled source
      size_t offA = (size_t)(bm + row) * K + kt + kbs * 8;
      size_t offB = (size_t)(bn + row) * K + kt + kbs * 8;
      int ldst = (i * 256 + (tid & 192)) << 4;   // wave-uniform linear dest
      GLDS(Ah + offA, (char*)AsH + ldst);
      GLDS(Al + offA, (char*)AsL + ldst);
      GLDS(Bh + offB, (char*)BsH + ldst);
      GLDS(Bl + offB, (char*)BsL + ldst);
    }
    __syncthreads();
    #pragma unroll
    for (int ks = 0; ks < 2; ++ks) {
      bf16x8 ah[4], al[4], bh[4], bl[4];
      #pragma unroll
      for (int mi = 0; mi < 4; ++mi) {
        int row = wr * 64 + mi * 16 + r16;
        int addr = ((row << 7) | (ks << 6) | (kq << 4)) ^ ((row & 7) << 4);
        ah[mi] = *(const bf16x8*)((const char*)AsH + addr);
        al[mi] = *(const bf16x8*)((const char*)AsL + addr);
      }
      #pragma unroll
      for (int ni = 0; ni < 4; ++ni) {
        int row = wc * 64 + ni * 16 + r16;
        int addr = ((row << 7) | (ks << 6) | (kq << 4)) ^ ((row & 7) << 4);
        bh[ni] = *(const bf16x8*)((const char*)BsH + addr);
        bl[ni] = *(const bf16x8*)((const char*)BsL + addr);
      }
      #pragma unroll
      for (int mi = 0; mi < 4; ++mi)
        #pragma unroll
        for (int ni = 0; ni < 4; ++ni) {
          acc[mi][ni] = __builtin_amdgcn_mfma_f32_16x16x32_bf16(ah[mi], bh[ni], acc[mi][ni], 0, 0, 0);
          acc[mi][ni] = __builtin_amdgcn_mfma_f32_16x16x32_bf16(ah[mi], bl[ni], acc[mi][ni], 0, 0, 0);
          acc[mi][ni] = __builtin_amdgcn_mfma_f32_16x16x32_bf16(al[mi], bh[ni], acc[mi][ni], 0, 0, 0);
        }
    }
  }
  int crow0 = bm + wr * 64 + (lane >> 4) * 4;
  int ccol0 = bn + wc * 64 + (lane & 15);
  #pragma unroll
  for (int mi = 0; mi < 4; ++mi) {
    #pragma unroll
    for (int ni = 0; ni < 4; ++ni) {
      int col = ccol0 + ni * 16;
      float bvv = col < 512 ? bq[col] : bk[col - 512];
      #pragma unroll
      for (int r = 0; r < 4; ++r) {
        int row = crow0 + mi * 16 + r;
        C[(size_t)row * ldc + col] = acc[mi][ni][r] + bvv;
      }
    }
  }
}

// ---------------- bf16 MFMA GEMM (single): C = A@W^T + bias, opt gelu ----------------
template<int ACT, int OUTBF>
__global__ __launch_bounds__(256) void gemm_mfma(const unsigned short* __restrict__ A,
                                                 const unsigned short* __restrict__ W,
                                                 const float* __restrict__ bias,
                                                 float* __restrict__ Cf,
                                                 unsigned short* __restrict__ Cb,
                                                 int M, int N, int K) {
  __shared__ __align__(16) unsigned short As[128 * 64];
  __shared__ __align__(16) unsigned short Bs[128 * 64];
  int nwg = gridDim.x * gridDim.y;
  int flat = blockIdx.y * gridDim.x + blockIdx.x;
  int swz = (flat & 7) * (nwg >> 3) + (flat >> 3);
  int bxs = swz % gridDim.x, bys = swz / gridDim.x;
  int bm = bys * 128, bn = bxs * 128;
  int tid = threadIdx.x;
  int wave = tid >> 6, lane = tid & 63;
  int wr = wave >> 1, wc = wave & 1;
  int r16 = lane & 15, kq = lane >> 4;

  f32x4 acc[4][4];
  #pragma unroll
  for (int i = 0; i < 4; ++i)
    #pragma unroll
    for (int j = 0; j < 4; ++j) acc[i][j] = (f32x4){0.f, 0.f, 0.f, 0.f};

  for (int kt = 0; kt < K; kt += 64) {
    __syncthreads();
    #pragma unroll
    for (int i = 0; i < 4; ++i) {
      int c = i * 256 + tid;
      int row = c >> 3, kb = c & 7;
      int kbs = kb ^ (row & 7);
      size_t offA = (size_t)(bm + row) * K + kt + kbs * 8;
      size_t offB = (size_t)(bn + row) * K + kt + kbs * 8;
      int ldst = (i * 256 + (tid & 192)) << 4;
      GLDS(A + offA, (char*)As + ldst);
      GLDS(W + offB, (char*)Bs + ldst);
    }
    __syncthreads();
    #pragma unroll
    for (int ks = 0; ks < 2; ++ks) {
      bf16x8 afr[4], bfr[4];
      #pragma unroll
      for (int mi = 0; mi < 4; ++mi) {
        int row = wr * 64 + mi * 16 + r16;
        int addr = ((row << 7) | (ks << 6) | (kq << 4)) ^ ((row & 7) << 4);
        afr[mi] = *(const bf16x8*)((const char*)As + addr);
      }
      #pragma unroll
      for (int ni = 0; ni < 4; ++ni) {
        int row = wc * 64 + ni * 16 + r16;
        int addr = ((row << 7) | (ks << 6) | (kq << 4)) ^ ((row & 7) << 4);
        bfr[ni] = *(const bf16x8*)((const char*)Bs + addr);
      }
      #pragma unroll
      for (int mi = 0; mi < 4; ++mi)
        #pragma unroll
        for (int ni = 0; ni < 4; ++ni)
          acc[mi][ni] = __builtin_amdgcn_mfma_f32_16x16x32_bf16(afr[mi], bfr[ni], acc[mi][ni], 0, 0, 0);
    }
  }
  int crow0 = bm + wr * 64 + (lane >> 4) * 4;
  int ccol0 = bn + wc * 64 + (lane & 15);
  #pragma unroll
  for (int mi = 0; mi < 4; ++mi) {
    #pragma unroll
    for (int ni = 0; ni < 4; ++ni) {
      int col = ccol0 + ni * 16;
      float bvv = bias[col];
      #pragma unroll
      for (int r = 0; r < 4; ++r) {
        int row = crow0 + mi * 16 + r;
        float v = acc[mi][ni][r] + bvv;
        if (ACT) {
          // gelu(tanh approx) = x * sigmoid(2y), y = 0.79788456(x + 0.044715 x^3)
          float x = v;
          float y2 = 1.5957691216057308f * (x + 0.044715f * x * x * x);
          v = x / (1.0f + __expf(-y2));
        }
        if (OUTBF) Cb[(size_t)row * N + col] = f2b(v);
        else       Cf[(size_t)row * N + col] = v;
      }
    }
  }
}

// ---------------- M measure: block per (bh), XOR-swizzled float4 K in LDS ----------------
__global__ __launch_bounds__(512) void m2_kernel(const float* __restrict__ QK,
                                                 const int* __restrict__ idx,
                                                 float* __restrict__ Mout) {
  int bh = blockIdx.x;
  int bv = bh >> 3, head = bh & 7;
  int tid = threadIdx.x;                 // 0..511, one q-row each
  __shared__ float Ks[512 * 64];         // 128 KB, word(l,db) = l*64 + ((db^(l&15))<<2)
  const float* base = QK + (size_t)bv * (SEQL * QKS);
  for (int c = tid; c < 512 * 16; c += 512) {
    int l = c >> 4, db = c & 15;
    float4 v = *(const float4*)(base + (size_t)l * QKS + 512 + head * 64 + db * 4);
    *(float4*)(Ks + l * 64 + ((db ^ (l & 15)) << 2)) = v;
  }
  float q[64];
  const float* qp = base + (size_t)tid * QKS + head * 64;
  #pragma unroll
  for (int d4 = 0; d4 < 64; d4 += 4) {
    float4 qv = *(const float4*)(qp + d4);
    q[d4 + 0] = qv.x; q[d4 + 1] = qv.y; q[d4 + 2] = qv.z; q[d4 + 3] = qv.w;
  }
  __syncthreads();
  const int* ip = idx + tid * NSAMP;
  float mx = -INFINITY, sm = 0.f;
  for (int u = 0; u < NSAMP; ++u) {
    int kidx = ip[u];
    const float* kr = Ks + kidx * 64;
    int x = kidx & 15;
    float s = 0.f;
    #pragma unroll
    for (int db = 0; db < 16; ++db) {
      float4 kv = *(const float4*)(kr + ((db ^ x) << 2));
      s += q[db * 4 + 0] * kv.x + q[db * 4 + 1] * kv.y
         + q[db * 4 + 2] * kv.z + q[db * 4 + 3] * kv.w;
    }
    mx = fmaxf(mx, s);
    sm += s;
  }
  Mout[(size_t)bh * SEQL + tid] = mx - sm * (1.0f / 512.0f);
}

// ---------------- top-k (k=35) ----------------
__global__ __launch_bounds__(256) void topk_kernel(const float* __restrict__ Mv,
                                                   int* __restrict__ top) {
  int bh = blockIdx.x;
  int tid = threadIdx.x;
  __shared__ float vals[512];
  __shared__ float rv[256];
  __shared__ int ri[256];
  vals[tid]       = Mv[(size_t)bh * SEQL + tid];
  vals[tid + 256] = Mv[(size_t)bh * SEQL + tid + 256];
  __syncthreads();
  for (int t = 0; t < NSAMP; ++t) {
    float v0 = vals[tid], v1 = vals[tid + 256];
    float bvv; int bii;
    if (v0 >= v1) { bvv = v0; bii = tid; } else { bvv = v1; bii = tid + 256; }
    rv[tid] = bvv; ri[tid] = bii;
    __syncthreads();
    for (int s = 128; s > 0; s >>= 1) {
      if (tid < s) {
        float ov = rv[tid + s]; int oi = ri[tid + s];
        if (ov > rv[tid] || (ov == rv[tid] && oi < ri[tid])) { rv[tid] = ov; ri[tid] = oi; }
      }
      __syncthreads();
    }
    if (tid == 0) { top[bh * NSAMP + t] = ri[0]; vals[ri[0]] = -INFINITY; }
    __syncthreads();
  }
}

// ---------------- mean of V (bf16 V, coalesced: block per bv) ----------------
__global__ __launch_bounds__(256) void vmean_kernel(const unsigned short* __restrict__ Vb,
                                                    float* __restrict__ vmean) {
  int bv = blockIdx.x;                 // 0..27
  int t = threadIdx.x;                 // cols 2t, 2t+1
  const unsigned short* vb = Vb + (size_t)bv * (SEQL * DMOD) + t * 2;
  float s0 = 0.f, s1 = 0.f;
  #pragma unroll 4
  for (int l = 0; l < SEQL; ++l) {
    unsigned u = *(const unsigned*)(vb + (size_t)l * DMOD);
    s0 += b2f((unsigned short)(u & 0xffffu));
    s1 += b2f((unsigned short)(u >> 16));
  }
  vmean[bv * DMOD + t * 2]     = s0 * (1.0f / 512.0f);
  vmean[bv * DMOD + t * 2 + 1] = s1 * (1.0f / 512.0f);
}

// ---------------- ctx = broadcast vmean (bf16 out, vectorized) ----------------
__global__ void ctx_fill_kernel(const float* __restrict__ vmean,
                                unsigned short* __restrict__ ctxb) {
  size_t i = (size_t)blockIdx.x * 256 + threadIdx.x;
  if (i >= (size_t)(SBIG / 4)) return;
  size_t e = i * 4;
  int dm = (int)(e & 511);
  int bv = (int)(e >> 18);
  float4 vm = *(const float4*)(vmean + bv * DMOD + dm);
  ushort4 o;
  o.x = f2b(vm.x); o.y = f2b(vm.y); o.z = f2b(vm.z); o.w = f2b(vm.w);
  *(ushort4*)(ctxb + e) = o;
}

// ---------------- MFMA attention for selected queries: block per (bh) ----------------
__global__ __launch_bounds__(256) void attn2_kernel(const float* __restrict__ QK,
                                                    const unsigned short* __restrict__ Vb,
                                                    const int* __restrict__ top,
                                                    unsigned short* __restrict__ ctxb) {
  __shared__ __align__(16) unsigned short KV[512 * 64];
  __shared__ __align__(16) unsigned short P[48 * 512];
  __shared__ __align__(16) unsigned short Qs[48 * 64];
  __shared__ int topi[NSAMP];
  int bh = blockIdx.x;
  int bv = bh >> 3, head = bh & 7;
  int tid = threadIdx.x;
  int wv = tid >> 6, lane = tid & 63;
  int r16 = lane & 15, kq = lane >> 4;
  const float* base = QK + (size_t)bv * (SEQL * QKS);
  const unsigned short* vbase = Vb + (size_t)bv * (SEQL * DMOD) + head * 64;

  if (tid < NSAMP) topi[tid] = top[bh * NSAMP + tid];
  __syncthreads();

  for (int c = tid; c < NSAMP * 16; c += 256) {
    int u = c >> 4, dq = c & 15;
    float4 q4 = *(const float4*)(base + (size_t)topi[u] * QKS + head * 64 + dq * 4);
    ushort4 o;
    o.x = f2b(q4.x * 0.125f); o.y = f2b(q4.y * 0.125f);
    o.z = f2b(q4.z * 0.125f); o.w = f2b(q4.w * 0.125f);
    int byte = ((u << 7) | (dq << 3)) ^ ((u & 7) << 4);
    *(ushort4*)((char*)Qs + byte) = o;
  }
  for (int c = tid; c < 512 * 16; c += 256) {
    int l = c >> 4, dq = c & 15;
    float4 k4 = *(const float4*)(base + (size_t)l * QKS + 512 + head * 64 + dq * 4);
    ushort4 o;
    o.x = f2b(k4.x); o.y = f2b(k4.y); o.z = f2b(k4.z); o.w = f2b(k4.w);
    int byte = ((l << 7) | (dq << 3)) ^ ((l & 7) << 4);
    *(ushort4*)((char*)KV + byte) = o;
  }
  __syncthreads();

  // QK^T: scores[48][512]
  {
    f32x4 acc[3][8];
    #pragma unroll
    for (int m = 0; m < 3; ++m)
      #pragma unroll
      for (int j = 0; j < 8; ++j) acc[m][j] = (f32x4){0.f, 0.f, 0.f, 0.f};
    bf16x8 afr[3][2];
    #pragma unroll
    for (int m = 0; m < 3; ++m)
      #pragma unroll
      for (int ks = 0; ks < 2; ++ks) {
        int row = m * 16 + r16;
        int addr = ((row << 7) | (ks << 6) | (kq << 4)) ^ ((row & 7) << 4);
        afr[m][ks] = *(const bf16x8*)((const char*)Qs + addr);
      }
    #pragma unroll
    for (int j = 0; j < 8; ++j) {
      int nrow = (wv * 8 + j) * 16 + r16;
      #pragma unroll
      for (int ks = 0; ks < 2; ++ks) {
        int addr = ((nrow << 7) | (ks << 6) | (kq << 4)) ^ ((nrow & 7) << 4);
        bf16x8 bfr = *(const bf16x8*)((const char*)KV + addr);
        #pragma unroll
        for (int m = 0; m < 3; ++m)
          acc[m][j] = __builtin_amdgcn_mfma_f32_16x16x32_bf16(afr[m][ks], bfr, acc[m][j], 0, 0, 0);
      }
    }
    #pragma unroll
    for (int m = 0; m < 3; ++m)
      #pragma unroll
      for (int j = 0; j < 8; ++j) {
        int l = (wv * 8 + j) * 16 + r16;
        #pragma unroll
        for (int r = 0; r < 4; ++r) {
          int u = m * 16 + kq * 4 + r;
          int byte = ((u << 10) | (l << 1)) ^ ((u & 7) << 4);
          *(unsigned short*)((char*)P + byte) = f2b(acc[m][j][r]);
        }
      }
  }
  __syncthreads();

  // stage V^T into KV region (K dead) from bf16 V
  for (int c = tid; c < 512 * 8; c += 256) {
    int l = c >> 3, dq = c & 7;
    bf16x8 v8 = *(const bf16x8*)(vbase + (size_t)l * DMOD + dq * 8);
    #pragma unroll
    for (int j = 0; j < 8; ++j) {
      int d = dq * 8 + j;
      int byte = ((d << 10) | (l << 1)) ^ ((d & 7) << 4);
      *(unsigned short*)((char*)KV + byte) = (unsigned short)v8[j];
    }
  }
  // softmax on P rows
  for (int u = wv; u < NSAMP; u += 4) {
    int byte = ((u << 10) | (lane << 4)) ^ ((u & 7) << 4);
    bf16x8 sv = *(const bf16x8*)((const char*)P + byte);
    float s[8];
    #pragma unroll
    for (int j = 0; j < 8; ++j) s[j] = b2f((unsigned short)sv[j]);
    float mx = s[0];
    #pragma unroll
    for (int j = 1; j < 8; ++j) mx = fmaxf(mx, s[j]);
    #pragma unroll
    for (int off = 32; off > 0; off >>= 1) mx = fmaxf(mx, __shfl_xor(mx, off));
    float e[8], sm = 0.f;
    #pragma unroll
    for (int j = 0; j < 8; ++j) { e[j] = __expf(s[j] - mx); sm += e[j]; }
    #pragma unroll
    for (int off = 32; off > 0; off >>= 1) sm += __shfl_xor(sm, off);
    float inv = 1.0f / sm;
    bf16x8 pv;
    #pragma unroll
    for (int j = 0; j < 8; ++j) pv[j] = (short)f2b(e[j] * inv);
    *(bf16x8*)((char*)P + byte) = pv;
  }
  __syncthreads();

  // PV: ctx[48][64] = P @ V
  {
    f32x4 acc2[3];
    #pragma unroll
    for (int m = 0; m < 3; ++m) acc2[m] = (f32x4){0.f, 0.f, 0.f, 0.f};
    for (int kst = 0; kst < 16; ++kst) {
      int vrow = wv * 16 + r16;
      int baddr = ((vrow << 10) | (kst << 6) | (kq << 4)) ^ ((vrow & 7) << 4);
      bf16x8 bfr = *(const bf16x8*)((const char*)KV + baddr);
      #pragma unroll
      for (int m = 0; m < 3; ++m) {
        int prow = m * 16 + r16;
        int aaddr = ((prow << 10) | (kst << 6) | (kq << 4)) ^ ((prow & 7) << 4);
        bf16x8 afr2 = *(const bf16x8*)((const char*)P + aaddr);
        acc2[m] = __builtin_amdgcn_mfma_f32_16x16x32_bf16(afr2, bfr, acc2[m], 0, 0, 0);
      }
    }
    int d = wv * 16 + r16;
    #pragma unroll
    for (int m = 0; m < 3; ++m)
      #pragma unroll
      for (int r = 0; r < 4; ++r) {
        int u = m * 16 + kq * 4 + r;
        if (u < NSAMP) {
          size_t off = (size_t)bv * (SEQL * DMOD) + (size_t)topi[u] * DMOD + head * 64 + d;
          ctxb[off] = f2b(acc2[m][r]);
        }
      }
  }
}

// ---------------- residual add + layernorm (vectorized: 2 rows/block) ----------------
template<int BMODE, int OUT>
__global__ __launch_bounds__(256) void add_ln(const float* __restrict__ a,
                                              const unsigned short* __restrict__ b,
                                              const float* __restrict__ g,
                                              const float* __restrict__ be,
                                              float* __restrict__ out,
                                              unsigned short* __restrict__ outb,
                                              unsigned short* __restrict__ outh,
                                              unsigned short* __restrict__ outl) {
  int row = blockIdx.x * 2 + (threadIdx.x >> 7);
  int t = threadIdx.x & 127;
  int wave = threadIdx.x >> 6;
  int lane = threadIdx.x & 63;
  size_t base = (size_t)row * DMOD + t * 4;
  float4 x = *(const float4*)(a + base);
  if (BMODE == 2) {
    ushort4 r4 = *(const ushort4*)(b + base);
    x.x += b2f(r4.x); x.y += b2f(r4.y); x.z += b2f(r4.z); x.w += b2f(r4.w);
  }
  float s1 = x.x + x.y + x.z + x.w;
  float s2 = x.x * x.x + x.y * x.y + x.z * x.z + x.w * x.w;
  #pragma unroll
  for (int off = 32; off > 0; off >>= 1) {
    s1 += __shfl_xor(s1, off);
    s2 += __shfl_xor(s2, off);
  }
  __shared__ float sh[8];
  if (lane == 0) { sh[wave * 2] = s1; sh[wave * 2 + 1] = s2; }
  __syncthreads();
  int mate = wave ^ 1;
  s1 += sh[mate * 2];
  s2 += sh[mate * 2 + 1];
  float mu = s1 * (1.0f / 512.0f);
  float var = s2 * (1.0f / 512.0f) - mu * mu;
  float rstd = rsqrtf(var + 1e-5f);
  float4 gg = *(const float4*)(g + t * 4);
  float4 bb = *(const float4*)(be + t * 4);
  float4 o;
  o.x = (x.x - mu) * rstd * gg.x + bb.x;
  o.y = (x.y - mu) * rstd * gg.y + bb.y;
  o.z = (x.z - mu) * rstd * gg.z + bb.z;
  o.w = (x.w - mu) * rstd * gg.w + bb.w;
  *(float4*)(out + base) = o;
  if (OUT == 1) {
    ushort4 ob;
    ob.x = f2b(o.x); ob.y = f2b(o.y); ob.z = f2b(o.z); ob.w = f2b(o.w);
    *(ushort4*)(outb + base) = ob;
  }
  if (OUT == 2) {
    ushort4 hi4, lo4;
    hi4.x = f2b(o.x); lo4.x = f2b(o.x - b2f(hi4.x));
    hi4.y = f2b(o.y); lo4.y = f2b(o.y - b2f(hi4.y));
    hi4.z = f2b(o.z); lo4.z = f2b(o.z - b2f(hi4.z));
    hi4.w = f2b(o.w); lo4.w = f2b(o.w - b2f(hi4.w));
    *(ushort4*)(outh + base) = hi4;
    *(ushort4*)(outl + base) = lo4;
  }
}

// ---------------- head via MFMA: partial[blk*4+w][2688], K-chunk 512/block ----------------
__global__ __launch_bounds__(256) void head_partial_mfma(const unsigned short* __restrict__ hbf,
                                                         const float* __restrict__ Wh,
                                                         float* __restrict__ partial) {
  __shared__ __align__(16) unsigned short Hs[32 * 512];   // 32 KB
  __shared__ __align__(16) unsigned short Ws[96 * 512];   // 96 KB
  int blk = blockIdx.x;            // 0..511
  int k0 = blk * 512;
  int tid = threadIdx.x;
  int wv = tid >> 6, lane = tid & 63;
  int r16 = lane & 15, kq = lane >> 4;

  for (int c = tid; c < 32 * 64; c += 256) {
    int row = c >> 6, col8 = c & 63;
    int src = row < 28 ? row : 0;
    bf16x8 v = *(const bf16x8*)(hbf + (size_t)src * 262144 + k0 + col8 * 8);
    int byte = ((row << 10) | (col8 << 4)) ^ ((row & 7) << 4);
    *(bf16x8*)((char*)Hs + byte) = v;
  }
  for (int c = tid; c < 96 * 64; c += 256) {
    int row = c >> 6, col8 = c & 63;
    const float* src = Wh + (size_t)row * 262144 + k0 + col8 * 8;
    float4 va = *(const float4*)(src);
    float4 vb = *(const float4*)(src + 4);
    bf16x8 o8;
    o8[0] = (short)f2b(va.x); o8[1] = (short)f2b(va.y);
    o8[2] = (short)f2b(va.z); o8[3] = (short)f2b(va.w);
    o8[4] = (short)f2b(vb.x); o8[5] = (short)f2b(vb.y);
    o8[6] = (short)f2b(vb.z); o8[7] = (short)f2b(vb.w);
    int byte = ((row << 10) | (col8 << 4)) ^ ((row & 7) << 4);
    *(bf16x8*)((char*)Ws + byte) = o8;
  }
  __syncthreads();

  f32x4 acc[2][6];
  #pragma unroll
  for (int mt = 0; mt < 2; ++mt)
    #pragma unroll
    for (int nt = 0; nt < 6; ++nt) acc[mt][nt] = (f32x4){0.f, 0.f, 0.f, 0.f};

  #pragma unroll
  for (int kk = 0; kk < 4; ++kk) {
    int kfrag = wv * 4 + kk;     // k = kfrag*32 + kq*8
    bf16x8 afr[2];
    #pragma unroll
    for (int mt = 0; mt < 2; ++mt) {
      int row = mt * 16 + r16;
      int byte = ((row << 10) | (kfrag << 6) | (kq << 4)) ^ ((row & 7) << 4);
      afr[mt] = *(const bf16x8*)((const char*)Hs + byte);
    }
    #pragma unroll
    for (int nt = 0; nt < 6; ++nt) {
      int row = nt * 16 + r16;
      int byte = ((row << 10) | (kfrag << 6) | (kq << 4)) ^ ((row & 7) << 4);
      bf16x8 bfr = *(const bf16x8*)((const char*)Ws + byte);
      #pragma unroll
      for (int mt = 0; mt < 2; ++mt)
        acc[mt][nt] = __builtin_amdgcn_mfma_f32_16x16x32_bf16(afr[mt], bfr, acc[mt][nt], 0, 0, 0);
    }
  }
  size_t prow = (size_t)(blk * 4 + wv) * 2688;
  #pragma unroll
  for (int mt = 0; mt < 2; ++mt)
    #pragma unroll
    for (int nt = 0; nt < 6; ++nt)
      #pragma unroll
      for (int r = 0; r < 4; ++r) {
        int m = mt * 16 + kq * 4 + r;
        int n = nt * 16 + r16;
        if (m < 28) partial[prow + m * 96 + n] = acc[mt][nt][r];
      }
}

__global__ __launch_bounds__(256) void head_reduce(const float* __restrict__ partial,
                                                   const float* __restrict__ bh_,
                                                   float* __restrict__ out) {
  int o = blockIdx.x;              // 0..2687 = m*96+p
  int tid = threadIdx.x;
  float s = 0.f;
  for (int b = tid; b < 2048; b += 256) s += partial[(size_t)b * 2688 + o];
  __shared__ float red[256];
  red[tid] = s;
  __syncthreads();
  for (int st = 128; st > 0; st >>= 1) {
    if (tid < st) red[tid] += red[tid + st];
    __syncthreads();
  }
  if (tid == 0) {
    int m = o / 96, p = o % 96;
    int b = m / NVARS, v = m % NVARS;
    out[(size_t)b * (NPRED * NVARS) + (size_t)p * NVARS + v] = red[0] + bh_[p];
  }
}

extern "C" void kernel_launch(void* const* d_in, const int* in_sizes, int n_in,
                              void* d_out, int out_size, void* d_ws, size_t ws_size,
                              hipStream_t stream) {
  const float* x_enc = (const float*)d_in[0];
  const float* w_emb = (const float*)d_in[1];
  const float* b_emb = (const float*)d_in[2];
  const float* w_pos = (const float*)d_in[3];
  const float* Wq = (const float*)d_in[4];
  const float* bq = (const float*)d_in[5];
  const float* Wk = (const float*)d_in[6];
  const float* bk = (const float*)d_in[7];
  const float* Wv = (const float*)d_in[8];
  const float* bv_ = (const float*)d_in[9];
  const float* Wo = (const float*)d_in[10];
  const float* bo = (const float*)d_in[11];
  const float* W1 = (const float*)d_in[12];
  const float* b1 = (const float*)d_in[13];
  const float* W2 = (const float*)d_in[14];
  const float* b2 = (const float*)d_in[15];
  const float* g1 = (const float*)d_in[16];
  const float* be1 = (const float*)d_in[17];
  const float* g2 = (const float*)d_in[18];
  const float* be2 = (const float*)d_in[19];
  const float* gF = (const float*)d_in[20];
  const float* bF = (const float*)d_in[21];
  const float* Wh = (const float*)d_in[22];
  const float* bh_ = (const float*)d_in[23];
  float* out = (float*)d_out;

  const size_t S = (size_t)SBIG;
  const size_t SB = S * 4;                    // 29,360,128 B
  char* ws = (char*)d_ws;
  float* h    = (float*)(ws);                 // [0, SB)
  float* QKb  = (float*)(ws + SB);            // [SB, 3SB): [14336][1024] fp32
  unsigned short* Vb   = (unsigned short*)(ws + 3 * SB);            // 14.7 MB
  unsigned short* Ob_b = (unsigned short*)(ws + 3 * SB + SB / 2);   // 14.7 MB
  // weight scratch region [4SB, 5SB)
  unsigned short* Wqk_hi = (unsigned short*)(ws + 4 * SB);                  // 1 MB
  unsigned short* Wqk_lo = (unsigned short*)(ws + 4 * SB + 0x100000);       // 1 MB
  unsigned short* Wv_b = (unsigned short*)(ws + 4 * SB + 0x200000);         // 0.5 MB
  unsigned short* Wo_b = (unsigned short*)(ws + 4 * SB + 0x280000);         // 0.5 MB
  unsigned short* W1_b = (unsigned short*)(ws + 4 * SB + 0x300000);         // 2 MB
  unsigned short* W2_b = (unsigned short*)(ws + 4 * SB + 0x500000);         // 2 MB
  unsigned short* h_hi = (unsigned short*)(ws + 5 * SB);           // SB/2
  unsigned short* h_lo = (unsigned short*)(ws + 5 * SB + SB / 2);  // SB/2
  // phase aliases:
  unsigned short* CTXb = h_hi;                 // after QK+V gemms consumed h_hi
  unsigned short* h_bf = h_lo;                 // after QK gemm consumed h_lo
  unsigned short* FFNb = (unsigned short*)QKb; // after attn consumed QK
  float* partial = QKb;                        // head phase (22 MB <= 2SB)
  int*   idx = (int*)(ws + 6 * SB);                        // 70KB
  float* Mv  = (float*)(ws + 6 * SB + 0x20000);            // 448KB
  int*   top = (int*)(ws + 6 * SB + 0xA0000);              // 31KB
  float* vmean = (float*)(ws + 6 * SB + 0xB0000);          // 56KB
  if (ws_size < 6 * SB + 0xC0000) return;

  dim3 b256(256);
  int gVec = (int)(S / 4 / 256);   // 7168

  embed_kernel<<<gVec, b256, 0, stream>>>(x_enc, w_emb, b_emb, w_pos, h, h_hi, h_lo);

  for (int l = 0; l < 2; ++l) {
    const float* Wql = Wq + (size_t)l * DMOD * DMOD;
    const float* Wkl = Wk + (size_t)l * DMOD * DMOD;
    const float* Wvl = Wv + (size_t)l * DMOD * DMOD;
    const float* Wol = Wo + (size_t)l * DMOD * DMOD;
    const float* W1l = W1 + (size_t)l * DFFN * DMOD;
    const float* W2l = W2 + (size_t)l * DMOD * DFFN;

    prep_weights<<<3072, b256, 0, stream>>>(Wql, Wkl, Wvl, Wol, W1l, W2l,
                                            Wqk_hi, Wqk_lo, Wv_b, Wo_b, W1_b, W2_b);

    dim3 gqk(QKS / 128, NROWS / 128);
    gemm_mfma3<<<gqk, b256, 0, stream>>>(h_hi, h_lo, Wqk_hi, Wqk_lo,
                                         bq + l * DMOD, bk + l * DMOD,
                                         QKb, NROWS, QKS, DMOD, QKS);
    dim3 gv(DMOD / 128, NROWS / 128);
    gemm_mfma<0, 1><<<gv, b256, 0, stream>>>(h_hi, Wv_b, bv_ + l * DMOD,
                                             (float*)0, Vb, NROWS, DMOD, DMOD);

    make_idx_kernel<<<(SEQL * NSAMP + 255) / 256, b256, 0, stream>>>(l, idx);
    m2_kernel<<<NBH, dim3(512), 0, stream>>>(QKb, idx, Mv);
    topk_kernel<<<NBH, b256, 0, stream>>>(Mv, top);
    vmean_kernel<<<NBV, b256, 0, stream>>>(Vb, vmean);
    ctx_fill_kernel<<<gVec, b256, 0, stream>>>(vmean, CTXb);
    attn2_kernel<<<NBH, b256, 0, stream>>>(QKb, Vb, top, CTXb);

    dim3 go(DMOD / 128, NROWS / 128);
    gemm_mfma<0, 1><<<go, b256, 0, stream>>>(CTXb, Wo_b, bo + l * DMOD,
                                             (float*)0, Ob_b, NROWS, DMOD, DMOD);
    add_ln<2, 1><<<NROWS / 2, b256, 0, stream>>>(h, Ob_b, g1 + l * DMOD, be1 + l * DMOD,
                                                 h, h_bf, (unsigned short*)0, (unsigned short*)0);

    dim3 gf1(DFFN / 128, NROWS / 128);
    gemm_mfma<1, 1><<<gf1, b256, 0, stream>>>(h_bf, W1_b, b1 + l * DFFN,
                                              (float*)0, FFNb, NROWS, DFFN, DMOD);
    dim3 gf2(DMOD / 128, NROWS / 128);
    gemm_mfma<0, 1><<<gf2, b256, 0, stream>>>(FFNb, W2_b, b2 + l * DMOD,
                                              (float*)0, Ob_b, NROWS, DMOD, DFFN);
    if (l == 0) {
      add_ln<2, 2><<<NROWS / 2, b256, 0, stream>>>(h, Ob_b, g2 + l * DMOD, be2 + l * DMOD,
                                                   h, (unsigned short*)0, h_hi, h_lo);
    } else {
      add_ln<2, 0><<<NROWS / 2, b256, 0, stream>>>(h, Ob_b, g2 + l * DMOD, be2 + l * DMOD,
                                                   h, (unsigned short*)0, (unsigned short*)0, (unsigned short*)0);
    }
  }

  add_ln<0, 1><<<NROWS / 2, b256, 0, stream>>>(h, (const unsigned short*)0, gF, bF,
                                               h, h_bf, (unsigned short*)0, (unsigned short*)0);
  head_partial_mfma<<<512, b256, 0, stream>>>(h_bf, Wh, partial);
  head_reduce<<<NBV * NPRED, b256, 0, stream>>>(partial, bh_, out);
}

// Round 9
// 752.643 us; speedup vs baseline: 7.5529x; 1.0359x over previous
//
#include <hip/hip_runtime.h>
#include <math.h>

#define SEQL 512
#define DMOD 512
#define NHEAD 8
#define DHEAD 64
#define DFFN 2048
#define NBATCH 4
#define NVARS 7
#define NBV 28          // NBATCH*NVARS
#define NBH 224         // NBV*NHEAD
#define NROWS 14336     // NBV*SEQL
#define NSAMP 35        // U_part = u = 35
#define NPRED 96
#define SBIG 7340032    // NBV*SEQL*DMOD floats
#define QKS 1024        // fused QK row stride

typedef short bf16x8 __attribute__((ext_vector_type(8)));
typedef float f32x4 __attribute__((ext_vector_type(4)));

#define GLDS(gptr, lptr) \
  __builtin_amdgcn_global_load_lds((const __attribute__((address_space(1))) void*)(gptr), \
                                   (__attribute__((address_space(3))) void*)(lptr), 16, 0, 0)

__device__ inline unsigned short f2b(float f) {
  unsigned u = __builtin_bit_cast(unsigned, f);
  unsigned r = (u + 0x7FFFu + ((u >> 16) & 1u)) >> 16;
  return (unsigned short)r;
}
__device__ inline float b2f(unsigned short h) {
  return __builtin_bit_cast(float, (unsigned)h << 16);
}

// ---------------- threefry2x32 (matches jax._src.prng) ----------------
__device__ inline void threefry2x32(unsigned k0, unsigned k1,
                                    unsigned x0, unsigned x1,
                                    unsigned &o0, unsigned &o1) {
  unsigned ks2 = k0 ^ k1 ^ 0x1BD11BDAu;
  unsigned ks[3] = {k0, k1, ks2};
  x0 += k0; x1 += k1;
  const unsigned rot[2][4] = {{13u,15u,26u,6u},{17u,29u,16u,24u}};
  #pragma unroll
  for (int i = 0; i < 5; ++i) {
    #pragma unroll
    for (int j = 0; j < 4; ++j) {
      unsigned r = rot[i & 1][j];
      x0 += x1;
      x1 = (x1 << r) | (x1 >> (32u - r));
      x1 ^= x0;
    }
    x0 += ks[(i + 1) % 3];
    x1 += ks[(i + 2) % 3] + (unsigned)(i + 1);
  }
  o0 = x0; o1 = x1;
}

__global__ void make_idx_kernel(int layer, int* idx) {
  int i = blockIdx.x * 256 + threadIdx.x;
  if (i >= SEQL * NSAMP) return;
  unsigned kl0, kl1, o0, o1;
  threefry2x32(0u, 42u, 0u, (unsigned)layer, kl0, kl1);
  threefry2x32(kl0, kl1, (unsigned)i, (unsigned)(SEQL * NSAMP + i), o0, o1);
  idx[i] = (int)(o1 & 511u);
}

// ---------------- embedding (vectorized, fused hi/lo split) ----------------
__global__ void embed_kernel(const float* __restrict__ x_enc,
                             const float* __restrict__ w_emb,
                             const float* __restrict__ b_emb,
                             const float* __restrict__ w_pos,
                             float* __restrict__ h,
                             unsigned short* __restrict__ h_hi,
                             unsigned short* __restrict__ h_lo) {
  size_t i = (size_t)blockIdx.x * 256 + threadIdx.x;
  if (i >= (size_t)(SBIG / 4)) return;
  size_t e = i * 4;
  int dm = (int)(e & 511);
  int l  = (int)((e >> 9) & 511);
  int bv = (int)(e >> 18);
  int b = bv / NVARS, v = bv % NVARS;
  float xs = x_enc[((size_t)b * SEQL + l) * NVARS + v];
  float4 we = *(const float4*)(w_emb + dm);
  float4 bb = *(const float4*)(b_emb + dm);
  float4 wp = *(const float4*)(w_pos + (size_t)l * DMOD + dm);
  float4 val;
  val.x = xs * we.x + bb.x + wp.x;
  val.y = xs * we.y + bb.y + wp.y;
  val.z = xs * we.z + bb.z + wp.z;
  val.w = xs * we.w + bb.w + wp.w;
  *(float4*)(h + e) = val;
  ushort4 hi4, lo4;
  hi4.x = f2b(val.x); lo4.x = f2b(val.x - b2f(hi4.x));
  hi4.y = f2b(val.y); lo4.y = f2b(val.y - b2f(hi4.y));
  hi4.z = f2b(val.z); lo4.z = f2b(val.z - b2f(hi4.z));
  hi4.w = f2b(val.w); lo4.w = f2b(val.w - b2f(hi4.w));
  *(ushort4*)(h_hi + e) = hi4;
  *(ushort4*)(h_lo + e) = lo4;
}

// ---------------- fused per-layer weight prep (one dispatch) ----------------
__global__ void prep_weights(const float* __restrict__ Wq, const float* __restrict__ Wk,
                             const float* __restrict__ Wv, const float* __restrict__ Wo,
                             const float* __restrict__ W1, const float* __restrict__ W2,
                             unsigned short* __restrict__ Wqk_hi, unsigned short* __restrict__ Wqk_lo,
                             unsigned short* __restrict__ Wv_b, unsigned short* __restrict__ Wo_b,
                             unsigned short* __restrict__ W1_b, unsigned short* __restrict__ W2_b) {
  const int Q4 = 65536;   // 262144/4
  int g = blockIdx.x * 256 + threadIdx.x;
  if (g < 2 * Q4) {
    const float* src = g < Q4 ? Wq : Wk;
    unsigned short* hi = Wqk_hi + (g < Q4 ? 0 : DMOD * DMOD);
    unsigned short* lo = Wqk_lo + (g < Q4 ? 0 : DMOD * DMOD);
    int off = (g < Q4 ? g : g - Q4) * 4;
    float4 v = *(const float4*)(src + off);
    ushort4 h4, l4;
    h4.x = f2b(v.x); l4.x = f2b(v.x - b2f(h4.x));
    h4.y = f2b(v.y); l4.y = f2b(v.y - b2f(h4.y));
    h4.z = f2b(v.z); l4.z = f2b(v.z - b2f(h4.z));
    h4.w = f2b(v.w); l4.w = f2b(v.w - b2f(h4.w));
    *(ushort4*)(hi + off) = h4;
    *(ushort4*)(lo + off) = l4;
    return;
  }
  const float* src;
  unsigned short* dst;
  int off;
  if (g < 3 * Q4)      { src = Wv; dst = Wv_b; off = (g - 2 * Q4) * 4; }
  else if (g < 4 * Q4) { src = Wo; dst = Wo_b; off = (g - 3 * Q4) * 4; }
  else if (g < 4 * Q4 + 262144) { src = W1; dst = W1_b; off = (g - 4 * Q4) * 4; }
  else                 { src = W2; dst = W2_b; off = (g - 4 * Q4 - 262144) * 4; }
  float4 v = *(const float4*)(src + off);
  ushort4 o;
  o.x = f2b(v.x); o.y = f2b(v.y); o.z = f2b(v.z); o.w = f2b(v.w);
  *(ushort4*)(dst + off) = o;
}

// ---------------- split-bf16 MFMA GEMM (3-pass hi/lo): C = A@W^T + [bq|bk] ----------------
__global__ __launch_bounds__(256) void gemm_mfma3(const unsigned short* __restrict__ Ah,
                                                  const unsigned short* __restrict__ Al,
                                                  const unsigned short* __restrict__ Bh,
                                                  const unsigned short* __restrict__ Bl,
                                                  const float* __restrict__ bq,
                                                  const float* __restrict__ bk,
                                                  float* __restrict__ C,
                                                  int M, int N, int K, int ldc) {
  __shared__ __align__(16) unsigned short AsH[128 * 64];
  __shared__ __align__(16) unsigned short AsL[128 * 64];
  __shared__ __align__(16) unsigned short BsH[128 * 64];
  __shared__ __align__(16) unsigned short BsL[128 * 64];
  int nwg = gridDim.x * gridDim.y;
  int flat = blockIdx.y * gridDim.x + blockIdx.x;
  int swz = (flat & 7) * (nwg >> 3) + (flat >> 3);
  int bxs = swz % gridDim.x, bys = swz / gridDim.x;
  int bm = bys * 128, bn = bxs * 128;
  int tid = threadIdx.x;
  int wave = tid >> 6, lane = tid & 63;
  int wr = wave >> 1, wc = wave & 1;
  int r16 = lane & 15, kq = lane >> 4;

  f32x4 acc[4][4];
  #pragma unroll
  for (int i = 0; i < 4; ++i)
    #pragma unroll
    for (int j = 0; j < 4; ++j) acc[i][j] = (f32x4){0.f, 0.f, 0.f, 0.f};

  for (int kt = 0; kt < K; kt += 64) {
    __syncthreads();
    #pragma unroll
    for (int i = 0; i < 4; ++i) {
      int c = i * 256 + tid;
      int row = c >> 3, kb = c & 7;
      int kbs = kb ^ (row & 7);             // pre-swizzled source
      size_t offA = (size_t)(bm + row) * K + kt + kbs * 8;
      size_t offB = (size_t)(bn + row) * K + kt + kbs * 8;
      int ldst = (i * 256 + (tid & 192)) << 4;   // wave-uniform linear dest
      GLDS(Ah + offA, (char*)AsH + ldst);
      GLDS(Al + offA, (char*)AsL + ldst);
      GLDS(Bh + offB, (char*)BsH + ldst);
      GLDS(Bl + offB, (char*)BsL + ldst);
    }
    __syncthreads();
    #pragma unroll
    for (int ks = 0; ks < 2; ++ks) {
      bf16x8 ah[4], al[4], bh[4], bl[4];
      #pragma unroll
      for (int mi = 0; mi < 4; ++mi) {
        int row = wr * 64 + mi * 16 + r16;
        int addr = ((row << 7) | (ks << 6) | (kq << 4)) ^ ((row & 7) << 4);
        ah[mi] = *(const bf16x8*)((const char*)AsH + addr);
        al[mi] = *(const bf16x8*)((const char*)AsL + addr);
      }
      #pragma unroll
      for (int ni = 0; ni < 4; ++ni) {
        int row = wc * 64 + ni * 16 + r16;
        int addr = ((row << 7) | (ks << 6) | (kq << 4)) ^ ((row & 7) << 4);
        bh[ni] = *(const bf16x8*)((const char*)BsH + addr);
        bl[ni] = *(const bf16x8*)((const char*)BsL + addr);
      }
      #pragma unroll
      for (int mi = 0; mi < 4; ++mi)
        #pragma unroll
        for (int ni = 0; ni < 4; ++ni) {
          acc[mi][ni] = __builtin_amdgcn_mfma_f32_16x16x32_bf16(ah[mi], bh[ni], acc[mi][ni], 0, 0, 0);
          acc[mi][ni] = __builtin_amdgcn_mfma_f32_16x16x32_bf16(ah[mi], bl[ni], acc[mi][ni], 0, 0, 0);
          acc[mi][ni] = __builtin_amdgcn_mfma_f32_16x16x32_bf16(al[mi], bh[ni], acc[mi][ni], 0, 0, 0);
        }
    }
  }
  int crow0 = bm + wr * 64 + (lane >> 4) * 4;
  int ccol0 = bn + wc * 64 + (lane & 15);
  #pragma unroll
  for (int mi = 0; mi < 4; ++mi) {
    #pragma unroll
    for (int ni = 0; ni < 4; ++ni) {
      int col = ccol0 + ni * 16;
      float bvv = col < 512 ? bq[col] : bk[col - 512];
      #pragma unroll
      for (int r = 0; r < 4; ++r) {
        int row = crow0 + mi * 16 + r;
        C[(size_t)row * ldc + col] = acc[mi][ni][r] + bvv;
      }
    }
  }
}

// ---------------- bf16 MFMA GEMM, 2-phase double-buffered LDS ----------------
template<int ACT, int OUTBF>
__global__ __launch_bounds__(256) void gemm_mfma(const unsigned short* __restrict__ A,
                                                 const unsigned short* __restrict__ W,
                                                 const float* __restrict__ bias,
                                                 float* __restrict__ Cf,
                                                 unsigned short* __restrict__ Cb,
                                                 int M, int N, int K) {
  __shared__ __align__(16) unsigned short As[2][128 * 64];   // 32 KB x2
  __shared__ __align__(16) unsigned short Bs[2][128 * 64];   // 32 KB x2
  int nwg = gridDim.x * gridDim.y;
  int flat = blockIdx.y * gridDim.x + blockIdx.x;
  int swz = (flat & 7) * (nwg >> 3) + (flat >> 3);
  int bxs = swz % gridDim.x, bys = swz / gridDim.x;
  int bm = bys * 128, bn = bxs * 128;
  int tid = threadIdx.x;
  int wave = tid >> 6, lane = tid & 63;
  int wr = wave >> 1, wc = wave & 1;
  int r16 = lane & 15, kq = lane >> 4;

  f32x4 acc[4][4];
  #pragma unroll
  for (int i = 0; i < 4; ++i)
    #pragma unroll
    for (int j = 0; j < 4; ++j) acc[i][j] = (f32x4){0.f, 0.f, 0.f, 0.f};

#define STAGE_MM(buf, ktv) \
  { \
    for (int i_ = 0; i_ < 4; ++i_) { \
      int c_ = i_ * 256 + tid; \
      int row_ = c_ >> 3, kb_ = c_ & 7; \
      int kbs_ = kb_ ^ (row_ & 7); \
      size_t offA_ = (size_t)(bm + row_) * K + (ktv) + kbs_ * 8; \
      size_t offB_ = (size_t)(bn + row_) * K + (ktv) + kbs_ * 8; \
      int ldst_ = (i_ * 256 + (tid & 192)) << 4; \
      GLDS(A + offA_, (char*)As[buf] + ldst_); \
      GLDS(W + offB_, (char*)Bs[buf] + ldst_); \
    } \
  }

  int nkt = K >> 6;
  STAGE_MM(0, 0);
  __syncthreads();                 // compiler drains vmcnt before barrier
  for (int t = 0; t < nkt; ++t) {
    int cur = t & 1;
    if (t + 1 < nkt) STAGE_MM(cur ^ 1, (t + 1) << 6);
    const char* Ab = (const char*)As[cur];
    const char* Bb = (const char*)Bs[cur];
    #pragma unroll
    for (int ks = 0; ks < 2; ++ks) {
      bf16x8 afr[4], bfr[4];
      #pragma unroll
      for (int mi = 0; mi < 4; ++mi) {
        int row = wr * 64 + mi * 16 + r16;
        int addr = ((row << 7) | (ks << 6) | (kq << 4)) ^ ((row & 7) << 4);
        afr[mi] = *(const bf16x8*)(Ab + addr);
      }
      #pragma unroll
      for (int ni = 0; ni < 4; ++ni) {
        int row = wc * 64 + ni * 16 + r16;
        int addr = ((row << 7) | (ks << 6) | (kq << 4)) ^ ((row & 7) << 4);
        bfr[ni] = *(const bf16x8*)(Bb + addr);
      }
      #pragma unroll
      for (int mi = 0; mi < 4; ++mi)
        #pragma unroll
        for (int ni = 0; ni < 4; ++ni)
          acc[mi][ni] = __builtin_amdgcn_mfma_f32_16x16x32_bf16(afr[mi], bfr[ni], acc[mi][ni], 0, 0, 0);
    }
    __syncthreads();               // drains the in-flight next-buf GLDS too
  }
#undef STAGE_MM

  int crow0 = bm + wr * 64 + (lane >> 4) * 4;
  int ccol0 = bn + wc * 64 + (lane & 15);
  #pragma unroll
  for (int mi = 0; mi < 4; ++mi) {
    #pragma unroll
    for (int ni = 0; ni < 4; ++ni) {
      int col = ccol0 + ni * 16;
      float bvv = bias[col];
      #pragma unroll
      for (int r = 0; r < 4; ++r) {
        int row = crow0 + mi * 16 + r;
        float v = acc[mi][ni][r] + bvv;
        if (ACT) {
          // gelu(tanh approx) = x * sigmoid(2*0.79788456(x+0.044715x^3))
          float x = v;
          float u = x * __builtin_fmaf(0.044715f * x, x, 1.0f);
          float tme = __expf(-1.5957691216057308f * u);
          v = x * __builtin_amdgcn_rcpf(1.0f + tme);
        }
        if (OUTBF) Cb[(size_t)row * N + col] = f2b(v);
        else       Cf[(size_t)row * N + col] = v;
      }
    }
  }
}

// ---------------- M measure: block per (bh), XOR-swizzled float4 K in LDS ----------------
__global__ __launch_bounds__(512) void m2_kernel(const float* __restrict__ QK,
                                                 const int* __restrict__ idx,
                                                 float* __restrict__ Mout) {
  int bh = blockIdx.x;
  int bv = bh >> 3, head = bh & 7;
  int tid = threadIdx.x;                 // 0..511, one q-row each
  __shared__ float Ks[512 * 64];         // 128 KB, word(l,db) = l*64 + ((db^(l&15))<<2)
  const float* base = QK + (size_t)bv * (SEQL * QKS);
  for (int c = tid; c < 512 * 16; c += 512) {
    int l = c >> 4, db = c & 15;
    float4 v = *(const float4*)(base + (size_t)l * QKS + 512 + head * 64 + db * 4);
    *(float4*)(Ks + l * 64 + ((db ^ (l & 15)) << 2)) = v;
  }
  float q[64];
  const float* qp = base + (size_t)tid * QKS + head * 64;
  #pragma unroll
  for (int d4 = 0; d4 < 64; d4 += 4) {
    float4 qv = *(const float4*)(qp + d4);
    q[d4 + 0] = qv.x; q[d4 + 1] = qv.y; q[d4 + 2] = qv.z; q[d4 + 3] = qv.w;
  }
  __syncthreads();
  const int* ip = idx + tid * NSAMP;
  float mx = -INFINITY, sm = 0.f;
  for (int u = 0; u < NSAMP; ++u) {
    int kidx = ip[u];
    const float* kr = Ks + kidx * 64;
    int x = kidx & 15;
    float s = 0.f;
    #pragma unroll
    for (int db = 0; db < 16; ++db) {
      float4 kv = *(const float4*)(kr + ((db ^ x) << 2));
      s += q[db * 4 + 0] * kv.x + q[db * 4 + 1] * kv.y
         + q[db * 4 + 2] * kv.z + q[db * 4 + 3] * kv.w;
    }
    mx = fmaxf(mx, s);
    sm += s;
  }
  Mout[(size_t)bh * SEQL + tid] = mx - sm * (1.0f / 512.0f);
}

// ---------------- top-k (k=35) ----------------
__global__ __launch_bounds__(256) void topk_kernel(const float* __restrict__ Mv,
                                                   int* __restrict__ top) {
  int bh = blockIdx.x;
  int tid = threadIdx.x;
  __shared__ float vals[512];
  __shared__ float rv[256];
  __shared__ int ri[256];
  vals[tid]       = Mv[(size_t)bh * SEQL + tid];
  vals[tid + 256] = Mv[(size_t)bh * SEQL + tid + 256];
  __syncthreads();
  for (int t = 0; t < NSAMP; ++t) {
    float v0 = vals[tid], v1 = vals[tid + 256];
    float bvv; int bii;
    if (v0 >= v1) { bvv = v0; bii = tid; } else { bvv = v1; bii = tid + 256; }
    rv[tid] = bvv; ri[tid] = bii;
    __syncthreads();
    for (int s = 128; s > 0; s >>= 1) {
      if (tid < s) {
        float ov = rv[tid + s]; int oi = ri[tid + s];
        if (ov > rv[tid] || (ov == rv[tid] && oi < ri[tid])) { rv[tid] = ov; ri[tid] = oi; }
      }
      __syncthreads();
    }
    if (tid == 0) { top[bh * NSAMP + t] = ri[0]; vals[ri[0]] = -INFINITY; }
    __syncthreads();
  }
}

// ---------------- mean of V (bf16 V, coalesced: block per bv) ----------------
__global__ __launch_bounds__(256) void vmean_kernel(const unsigned short* __restrict__ Vb,
                                                    float* __restrict__ vmean) {
  int bv = blockIdx.x;                 // 0..27
  int t = threadIdx.x;                 // cols 2t, 2t+1
  const unsigned short* vb = Vb + (size_t)bv * (SEQL * DMOD) + t * 2;
  float s0 = 0.f, s1 = 0.f;
  #pragma unroll 4
  for (int l = 0; l < SEQL; ++l) {
    unsigned u = *(const unsigned*)(vb + (size_t)l * DMOD);
    s0 += b2f((unsigned short)(u & 0xffffu));
    s1 += b2f((unsigned short)(u >> 16));
  }
  vmean[bv * DMOD + t * 2]     = s0 * (1.0f / 512.0f);
  vmean[bv * DMOD + t * 2 + 1] = s1 * (1.0f / 512.0f);
}

// ---------------- ctx = broadcast vmean (bf16 out, vectorized) ----------------
__global__ void ctx_fill_kernel(const float* __restrict__ vmean,
                                unsigned short* __restrict__ ctxb) {
  size_t i = (size_t)blockIdx.x * 256 + threadIdx.x;
  if (i >= (size_t)(SBIG / 4)) return;
  size_t e = i * 4;
  int dm = (int)(e & 511);
  int bv = (int)(e >> 18);
  float4 vm = *(const float4*)(vmean + bv * DMOD + dm);
  ushort4 o;
  o.x = f2b(vm.x); o.y = f2b(vm.y); o.z = f2b(vm.z); o.w = f2b(vm.w);
  *(ushort4*)(ctxb + e) = o;
}

// ---------------- MFMA attention for selected queries: block per (bh) ----------------
__global__ __launch_bounds__(256) void attn2_kernel(const float* __restrict__ QK,
                                                    const unsigned short* __restrict__ Vb,
                                                    const int* __restrict__ top,
                                                    unsigned short* __restrict__ ctxb) {
  __shared__ __align__(16) unsigned short KV[512 * 64];
  __shared__ __align__(16) unsigned short P[48 * 512];
  __shared__ __align__(16) unsigned short Qs[48 * 64];
  __shared__ int topi[NSAMP];
  int bh = blockIdx.x;
  int bv = bh >> 3, head = bh & 7;
  int tid = threadIdx.x;
  int wv = tid >> 6, lane = tid & 63;
  int r16 = lane & 15, kq = lane >> 4;
  const float* base = QK + (size_t)bv * (SEQL * QKS);
  const unsigned short* vbase = Vb + (size_t)bv * (SEQL * DMOD) + head * 64;

  if (tid < NSAMP) topi[tid] = top[bh * NSAMP + tid];
  __syncthreads();

  for (int c = tid; c < NSAMP * 16; c += 256) {
    int u = c >> 4, dq = c & 15;
    float4 q4 = *(const float4*)(base + (size_t)topi[u] * QKS + head * 64 + dq * 4);
    ushort4 o;
    o.x = f2b(q4.x * 0.125f); o.y = f2b(q4.y * 0.125f);
    o.z = f2b(q4.z * 0.125f); o.w = f2b(q4.w * 0.125f);
    int byte = ((u << 7) | (dq << 3)) ^ ((u & 7) << 4);
    *(ushort4*)((char*)Qs + byte) = o;
  }
  for (int c = tid; c < 512 * 16; c += 256) {
    int l = c >> 4, dq = c & 15;
    float4 k4 = *(const float4*)(base + (size_t)l * QKS + 512 + head * 64 + dq * 4);
    ushort4 o;
    o.x = f2b(k4.x); o.y = f2b(k4.y); o.z = f2b(k4.z); o.w = f2b(k4.w);
    int byte = ((l << 7) | (dq << 3)) ^ ((l & 7) << 4);
    *(ushort4*)((char*)KV + byte) = o;
  }
  __syncthreads();

  // QK^T: scores[48][512]
  {
    f32x4 acc[3][8];
    #pragma unroll
    for (int m = 0; m < 3; ++m)
      #pragma unroll
      for (int j = 0; j < 8; ++j) acc[m][j] = (f32x4){0.f, 0.f, 0.f, 0.f};
    bf16x8 afr[3][2];
    #pragma unroll
    for (int m = 0; m < 3; ++m)
      #pragma unroll
      for (int ks = 0; ks < 2; ++ks) {
        int row = m * 16 + r16;
        int addr = ((row << 7) | (ks << 6) | (kq << 4)) ^ ((row & 7) << 4);
        afr[m][ks] = *(const bf16x8*)((const char*)Qs + addr);
      }
    #pragma unroll
    for (int j = 0; j < 8; ++j) {
      int nrow = (wv * 8 + j) * 16 + r16;
      #pragma unroll
      for (int ks = 0; ks < 2; ++ks) {
        int addr = ((nrow << 7) | (ks << 6) | (kq << 4)) ^ ((nrow & 7) << 4);
        bf16x8 bfr = *(const bf16x8*)((const char*)KV + addr);
        #pragma unroll
        for (int m = 0; m < 3; ++m)
          acc[m][j] = __builtin_amdgcn_mfma_f32_16x16x32_bf16(afr[m][ks], bfr, acc[m][j], 0, 0, 0);
      }
    }
    #pragma unroll
    for (int m = 0; m < 3; ++m)
      #pragma unroll
      for (int j = 0; j < 8; ++j) {
        int l = (wv * 8 + j) * 16 + r16;
        #pragma unroll
        for (int r = 0; r < 4; ++r) {
          int u = m * 16 + kq * 4 + r;
          int byte = ((u << 10) | (l << 1)) ^ ((u & 7) << 4);
          *(unsigned short*)((char*)P + byte) = f2b(acc[m][j][r]);
        }
      }
  }
  __syncthreads();

  // stage V^T into KV region (K dead) from bf16 V
  for (int c = tid; c < 512 * 8; c += 256) {
    int l = c >> 3, dq = c & 7;
    bf16x8 v8 = *(const bf16x8*)(vbase + (size_t)l * DMOD + dq * 8);
    #pragma unroll
    for (int j = 0; j < 8; ++j) {
      int d = dq * 8 + j;
      int byte = ((d << 10) | (l << 1)) ^ ((d & 7) << 4);
      *(unsigned short*)((char*)KV + byte) = (unsigned short)v8[j];
    }
  }
  // softmax on P rows
  for (int u = wv; u < NSAMP; u += 4) {
    int byte = ((u << 10) | (lane << 4)) ^ ((u & 7) << 4);
    bf16x8 sv = *(const bf16x8*)((const char*)P + byte);
    float s[8];
    #pragma unroll
    for (int j = 0; j < 8; ++j) s[j] = b2f((unsigned short)sv[j]);
    float mx = s[0];
    #pragma unroll
    for (int j = 1; j < 8; ++j) mx = fmaxf(mx, s[j]);
    #pragma unroll
    for (int off = 32; off > 0; off >>= 1) mx = fmaxf(mx, __shfl_xor(mx, off));
    float e[8], sm = 0.f;
    #pragma unroll
    for (int j = 0; j < 8; ++j) { e[j] = __expf(s[j] - mx); sm += e[j]; }
    #pragma unroll
    for (int off = 32; off > 0; off >>= 1) sm += __shfl_xor(sm, off);
    float inv = 1.0f / sm;
    bf16x8 pv;
    #pragma unroll
    for (int j = 0; j < 8; ++j) pv[j] = (short)f2b(e[j] * inv);
    *(bf16x8*)((char*)P + byte) = pv;
  }
  __syncthreads();

  // PV: ctx[48][64] = P @ V
  {
    f32x4 acc2[3];
    #pragma unroll
    for (int m = 0; m < 3; ++m) acc2[m] = (f32x4){0.f, 0.f, 0.f, 0.f};
    for (int kst = 0; kst < 16; ++kst) {
      int vrow = wv * 16 + r16;
      int baddr = ((vrow << 10) | (kst << 6) | (kq << 4)) ^ ((vrow & 7) << 4);
      bf16x8 bfr = *(const bf16x8*)((const char*)KV + baddr);
      #pragma unroll
      for (int m = 0; m < 3; ++m) {
        int prow = m * 16 + r16;
        int aaddr = ((prow << 10) | (kst << 6) | (kq << 4)) ^ ((prow & 7) << 4);
        bf16x8 afr2 = *(const bf16x8*)((const char*)P + aaddr);
        acc2[m] = __builtin_amdgcn_mfma_f32_16x16x32_bf16(afr2, bfr, acc2[m], 0, 0, 0);
      }
    }
    int d = wv * 16 + r16;
    #pragma unroll
    for (int m = 0; m < 3; ++m)
      #pragma unroll
      for (int r = 0; r < 4; ++r) {
        int u = m * 16 + kq * 4 + r;
        if (u < NSAMP) {
          size_t off = (size_t)bv * (SEQL * DMOD) + (size_t)topi[u] * DMOD + head * 64 + d;
          ctxb[off] = f2b(acc2[m][r]);
        }
      }
  }
}

// ---------------- residual add + layernorm (vectorized: 2 rows/block) ----------------
template<int BMODE, int OUT>
__global__ __launch_bounds__(256) void add_ln(const float* __restrict__ a,
                                              const unsigned short* __restrict__ b,
                                              const float* __restrict__ g,
                                              const float* __restrict__ be,
                                              float* __restrict__ out,
                                              unsigned short* __restrict__ outb,
                                              unsigned short* __restrict__ outh,
                                              unsigned short* __restrict__ outl) {
  int row = blockIdx.x * 2 + (threadIdx.x >> 7);
  int t = threadIdx.x & 127;
  int wave = threadIdx.x >> 6;
  int lane = threadIdx.x & 63;
  size_t base = (size_t)row * DMOD + t * 4;
  float4 x = *(const float4*)(a + base);
  if (BMODE == 2) {
    ushort4 r4 = *(const ushort4*)(b + base);
    x.x += b2f(r4.x); x.y += b2f(r4.y); x.z += b2f(r4.z); x.w += b2f(r4.w);
  }
  float s1 = x.x + x.y + x.z + x.w;
  float s2 = x.x * x.x + x.y * x.y + x.z * x.z + x.w * x.w;
  #pragma unroll
  for (int off = 32; off > 0; off >>= 1) {
    s1 += __shfl_xor(s1, off);
    s2 += __shfl_xor(s2, off);
  }
  __shared__ float sh[8];
  if (lane == 0) { sh[wave * 2] = s1; sh[wave * 2 + 1] = s2; }
  __syncthreads();
  int mate = wave ^ 1;
  s1 += sh[mate * 2];
  s2 += sh[mate * 2 + 1];
  float mu = s1 * (1.0f / 512.0f);
  float var = s2 * (1.0f / 512.0f) - mu * mu;
  float rstd = rsqrtf(var + 1e-5f);
  float4 gg = *(const float4*)(g + t * 4);
  float4 bb = *(const float4*)(be + t * 4);
  float4 o;
  o.x = (x.x - mu) * rstd * gg.x + bb.x;
  o.y = (x.y - mu) * rstd * gg.y + bb.y;
  o.z = (x.z - mu) * rstd * gg.z + bb.z;
  o.w = (x.w - mu) * rstd * gg.w + bb.w;
  *(float4*)(out + base) = o;
  if (OUT == 1) {
    ushort4 ob;
    ob.x = f2b(o.x); ob.y = f2b(o.y); ob.z = f2b(o.z); ob.w = f2b(o.w);
    *(ushort4*)(outb + base) = ob;
  }
  if (OUT == 2) {
    ushort4 hi4, lo4;
    hi4.x = f2b(o.x); lo4.x = f2b(o.x - b2f(hi4.x));
    hi4.y = f2b(o.y); lo4.y = f2b(o.y - b2f(hi4.y));
    hi4.z = f2b(o.z); lo4.z = f2b(o.z - b2f(hi4.z));
    hi4.w = f2b(o.w); lo4.w = f2b(o.w - b2f(hi4.w));
    *(ushort4*)(outh + base) = hi4;
    *(ushort4*)(outl + base) = lo4;
  }
}

// ---------------- head via MFMA: partial[blk*4+w][2688], K-chunk 512/block ----------------
__global__ __launch_bounds__(256) void head_partial_mfma(const unsigned short* __restrict__ hbf,
                                                         const float* __restrict__ Wh,
                                                         float* __restrict__ partial) {
  __shared__ __align__(16) unsigned short Hs[32 * 512];   // 32 KB
  __shared__ __align__(16) unsigned short Ws[96 * 512];   // 96 KB
  int blk = blockIdx.x;            // 0..511
  int k0 = blk * 512;
  int tid = threadIdx.x;
  int wv = tid >> 6, lane = tid & 63;
  int r16 = lane & 15, kq = lane >> 4;

  for (int c = tid; c < 32 * 64; c += 256) {
    int row = c >> 6, col8 = c & 63;
    int src = row < 28 ? row : 0;
    bf16x8 v = *(const bf16x8*)(hbf + (size_t)src * 262144 + k0 + col8 * 8);
    int byte = ((row << 10) | (col8 << 4)) ^ ((row & 7) << 4);
    *(bf16x8*)((char*)Hs + byte) = v;
  }
  for (int c = tid; c < 96 * 64; c += 256) {
    int row = c >> 6, col8 = c & 63;
    const float* src = Wh + (size_t)row * 262144 + k0 + col8 * 8;
    float4 va = *(const float4*)(src);
    float4 vb = *(const float4*)(src + 4);
    bf16x8 o8;
    o8[0] = (short)f2b(va.x); o8[1] = (short)f2b(va.y);
    o8[2] = (short)f2b(va.z); o8[3] = (short)f2b(va.w);
    o8[4] = (short)f2b(vb.x); o8[5] = (short)f2b(vb.y);
    o8[6] = (short)f2b(vb.z); o8[7] = (short)f2b(vb.w);
    int byte = ((row << 10) | (col8 << 4)) ^ ((row & 7) << 4);
    *(bf16x8*)((char*)Ws + byte) = o8;
  }
  __syncthreads();

  f32x4 acc[2][6];
  #pragma unroll
  for (int mt = 0; mt < 2; ++mt)
    #pragma unroll
    for (int nt = 0; nt < 6; ++nt) acc[mt][nt] = (f32x4){0.f, 0.f, 0.f, 0.f};

  #pragma unroll
  for (int kk = 0; kk < 4; ++kk) {
    int kfrag = wv * 4 + kk;     // k = kfrag*32 + kq*8
    bf16x8 afr[2];
    #pragma unroll
    for (int mt = 0; mt < 2; ++mt) {
      int row = mt * 16 + r16;
      int byte = ((row << 10) | (kfrag << 6) | (kq << 4)) ^ ((row & 7) << 4);
      afr[mt] = *(const bf16x8*)((const char*)Hs + byte);
    }
    #pragma unroll
    for (int nt = 0; nt < 6; ++nt) {
      int row = nt * 16 + r16;
      int byte = ((row << 10) | (kfrag << 6) | (kq << 4)) ^ ((row & 7) << 4);
      bf16x8 bfr = *(const bf16x8*)((const char*)Ws + byte);
      #pragma unroll
      for (int mt = 0; mt < 2; ++mt)
        acc[mt][nt] = __builtin_amdgcn_mfma_f32_16x16x32_bf16(afr[mt], bfr, acc[mt][nt], 0, 0, 0);
    }
  }
  size_t prow = (size_t)(blk * 4 + wv) * 2688;
  #pragma unroll
  for (int mt = 0; mt < 2; ++mt)
    #pragma unroll
    for (int nt = 0; nt < 6; ++nt)
      #pragma unroll
      for (int r = 0; r < 4; ++r) {
        int m = mt * 16 + kq * 4 + r;
        int n = nt * 16 + r16;
        if (m < 28) partial[prow + m * 96 + n] = acc[mt][nt][r];
      }
}

__global__ __launch_bounds__(256) void head_reduce(const float* __restrict__ partial,
                                                   const float* __restrict__ bh_,
                                                   float* __restrict__ out) {
  int o = blockIdx.x;              // 0..2687 = m*96+p
  int tid = threadIdx.x;
  float s = 0.f;
  for (int b = tid; b < 2048; b += 256) s += partial[(size_t)b * 2688 + o];
  __shared__ float red[256];
  red[tid] = s;
  __syncthreads();
  for (int st = 128; st > 0; st >>= 1) {
    if (tid < st) red[tid] += red[tid + st];
    __syncthreads();
  }
  if (tid == 0) {
    int m = o / 96, p = o % 96;
    int b = m / NVARS, v = m % NVARS;
    out[(size_t)b * (NPRED * NVARS) + (size_t)p * NVARS + v] = red[0] + bh_[p];
  }
}

extern "C" void kernel_launch(void* const* d_in, const int* in_sizes, int n_in,
                              void* d_out, int out_size, void* d_ws, size_t ws_size,
                              hipStream_t stream) {
  const float* x_enc = (const float*)d_in[0];
  const float* w_emb = (const float*)d_in[1];
  const float* b_emb = (const float*)d_in[2];
  const float* w_pos = (const float*)d_in[3];
  const float* Wq = (const float*)d_in[4];
  const float* bq = (const float*)d_in[5];
  const float* Wk = (const float*)d_in[6];
  const float* bk = (const float*)d_in[7];
  const float* Wv = (const float*)d_in[8];
  const float* bv_ = (const float*)d_in[9];
  const float* Wo = (const float*)d_in[10];
  const float* bo = (const float*)d_in[11];
  const float* W1 = (const float*)d_in[12];
  const float* b1 = (const float*)d_in[13];
  const float* W2 = (const float*)d_in[14];
  const float* b2 = (const float*)d_in[15];
  const float* g1 = (const float*)d_in[16];
  const float* be1 = (const float*)d_in[17];
  const float* g2 = (const float*)d_in[18];
  const float* be2 = (const float*)d_in[19];
  const float* gF = (const float*)d_in[20];
  const float* bF = (const float*)d_in[21];
  const float* Wh = (const float*)d_in[22];
  const float* bh_ = (const float*)d_in[23];
  float* out = (float*)d_out;

  const size_t S = (size_t)SBIG;
  const size_t SB = S * 4;                    // 29,360,128 B
  char* ws = (char*)d_ws;
  float* h    = (float*)(ws);                 // [0, SB)
  float* QKb  = (float*)(ws + SB);            // [SB, 3SB): [14336][1024] fp32
  unsigned short* Vb   = (unsigned short*)(ws + 3 * SB);            // 14.7 MB
  unsigned short* Ob_b = (unsigned short*)(ws + 3 * SB + SB / 2);   // 14.7 MB
  // weight scratch region [4SB, 5SB)
  unsigned short* Wqk_hi = (unsigned short*)(ws + 4 * SB);                  // 1 MB
  unsigned short* Wqk_lo = (unsigned short*)(ws + 4 * SB + 0x100000);       // 1 MB
  unsigned short* Wv_b = (unsigned short*)(ws + 4 * SB + 0x200000);         // 0.5 MB
  unsigned short* Wo_b = (unsigned short*)(ws + 4 * SB + 0x280000);         // 0.5 MB
  unsigned short* W1_b = (unsigned short*)(ws + 4 * SB + 0x300000);         // 2 MB
  unsigned short* W2_b = (unsigned short*)(ws + 4 * SB + 0x500000);         // 2 MB
  unsigned short* h_hi = (unsigned short*)(ws + 5 * SB);           // SB/2
  unsigned short* h_lo = (unsigned short*)(ws + 5 * SB + SB / 2);  // SB/2
  // phase aliases:
  unsigned short* CTXb = h_hi;                 // after QK+V gemms consumed h_hi
  unsigned short* h_bf = h_lo;                 // after QK gemm consumed h_lo
  unsigned short* FFNb = (unsigned short*)QKb; // after attn consumed QK
  float* partial = QKb;                        // head phase (22 MB <= 2SB)
  int*   idx = (int*)(ws + 6 * SB);                        // 70KB
  float* Mv  = (float*)(ws + 6 * SB + 0x20000);            // 448KB
  int*   top = (int*)(ws + 6 * SB + 0xA0000);              // 31KB
  float* vmean = (float*)(ws + 6 * SB + 0xB0000);          // 56KB
  if (ws_size < 6 * SB + 0xC0000) return;

  dim3 b256(256);
  int gVec = (int)(S / 4 / 256);   // 7168

  embed_kernel<<<gVec, b256, 0, stream>>>(x_enc, w_emb, b_emb, w_pos, h, h_hi, h_lo);

  for (int l = 0; l < 2; ++l) {
    const float* Wql = Wq + (size_t)l * DMOD * DMOD;
    const float* Wkl = Wk + (size_t)l * DMOD * DMOD;
    const float* Wvl = Wv + (size_t)l * DMOD * DMOD;
    const float* Wol = Wo + (size_t)l * DMOD * DMOD;
    const float* W1l = W1 + (size_t)l * DFFN * DMOD;
    const float* W2l = W2 + (size_t)l * DMOD * DFFN;

    prep_weights<<<3072, b256, 0, stream>>>(Wql, Wkl, Wvl, Wol, W1l, W2l,
                                            Wqk_hi, Wqk_lo, Wv_b, Wo_b, W1_b, W2_b);

    dim3 gqk(QKS / 128, NROWS / 128);
    gemm_mfma3<<<gqk, b256, 0, stream>>>(h_hi, h_lo, Wqk_hi, Wqk_lo,
                                         bq + l * DMOD, bk + l * DMOD,
                                         QKb, NROWS, QKS, DMOD, QKS);
    dim3 gv(DMOD / 128, NROWS / 128);
    gemm_mfma<0, 1><<<gv, b256, 0, stream>>>(h_hi, Wv_b, bv_ + l * DMOD,
                                             (float*)0, Vb, NROWS, DMOD, DMOD);

    make_idx_kernel<<<(SEQL * NSAMP + 255) / 256, b256, 0, stream>>>(l, idx);
    m2_kernel<<<NBH, dim3(512), 0, stream>>>(QKb, idx, Mv);
    topk_kernel<<<NBH, b256, 0, stream>>>(Mv, top);
    vmean_kernel<<<NBV, b256, 0, stream>>>(Vb, vmean);
    ctx_fill_kernel<<<gVec, b256, 0, stream>>>(vmean, CTXb);
    attn2_kernel<<<NBH, b256, 0, stream>>>(QKb, Vb, top, CTXb);

    dim3 go(DMOD / 128, NROWS / 128);
    gemm_mfma<0, 1><<<go, b256, 0, stream>>>(CTXb, Wo_b, bo + l * DMOD,
                                             (float*)0, Ob_b, NROWS, DMOD, DMOD);
    add_ln<2, 1><<<NROWS / 2, b256, 0, stream>>>(h, Ob_b, g1 + l * DMOD, be1 + l * DMOD,
                                                 h, h_bf, (unsigned short*)0, (unsigned short*)0);

    dim3 gf1(DFFN / 128, NROWS / 128);
    gemm_mfma<1, 1><<<gf1, b256, 0, stream>>>(h_bf, W1_b, b1 + l * DFFN,
                                              (float*)0, FFNb, NROWS, DFFN, DMOD);
    dim3 gf2(DMOD / 128, NROWS / 128);
    gemm_mfma<0, 1><<<gf2, b256, 0, stream>>>(FFNb, W2_b, b2 + l * DMOD,
                                              (float*)0, Ob_b, NROWS, DMOD, DFFN);
    if (l == 0) {
      add_ln<2, 2><<<NROWS / 2, b256, 0, stream>>>(h, Ob_b, g2 + l * DMOD, be2 + l * DMOD,
                                                   h, (unsigned short*)0, h_hi, h_lo);
    } else {
      add_ln<2, 0><<<NROWS / 2, b256, 0, stream>>>(h, Ob_b, g2 + l * DMOD, be2 + l * DMOD,
                                                   h, (unsigned short*)0, (unsigned short*)0, (unsigned short*)0);
    }
  }

  add_ln<0, 1><<<NROWS / 2, b256, 0, stream>>>(h, (const unsigned short*)0, gF, bF,
                                               h, h_bf, (unsigned short*)0, (unsigned short*)0);
  head_partial_mfma<<<512, b256, 0, stream>>>(h_bf, Wh, partial);
  head_reduce<<<NBV * NPRED, b256, 0, stream>>>(partial, bh_, out);
}